// Round 1
// baseline (1212.284 us; speedup 1.0000x reference)
//
#include <hip/hip_runtime.h>
#include <hip/hip_bf16.h>
#include <cstdint>

// ---------------------------------------------------------------------------
// SPDE GCN: 4x GCNConv (transform -> symmetric-normalized aggregate w/ self
// loops -> bias -> relu) + linear head.  All fp32.
// Pipeline per call (d_ws is poisoned before every timed launch):
//   1. zero counts/cursor
//   2. histogram in-degree by dst (atomicAdd)
//   3. block-wise exclusive scan (+ dinv = rsqrt(deg+1) fused)
//   4. scan of block sums (single block)
//   5. scatter edges into CSR buckets (col, wgt = dinv[s]*dinv[d])
//   6. per layer: register-cached-W GEMM, then wave-per-node CSR gather
//   7. linear head 32->3
// ---------------------------------------------------------------------------

__global__ __launch_bounds__(256) void init_k(int* __restrict__ counts,
                                              int* __restrict__ cursor, int n) {
    int i = blockIdx.x * blockDim.x + threadIdx.x;
    if (i < n) { counts[i] = 0; cursor[i] = 0; }
}

__global__ __launch_bounds__(256) void count_k(const int* __restrict__ ei,
                                               int* __restrict__ counts, int E) {
    int e = blockIdx.x * blockDim.x + threadIdx.x;
    if (e < E) atomicAdd(&counts[ei[E + e]], 1);
}

// Inclusive LDS scan of 1024 elements per block; writes per-element exclusive
// prefix (within block) and the block total.  Also computes dinv.
__global__ __launch_bounds__(1024) void scan1_k(const int* __restrict__ counts,
                                                int* __restrict__ part,
                                                int* __restrict__ bsums,
                                                float* __restrict__ dinv, int n) {
    __shared__ int s[1024];
    int t = threadIdx.x;
    int g = blockIdx.x * 1024 + t;
    int v = (g < n) ? counts[g] : 0;
    if (g < n) dinv[g] = rsqrtf((float)(v + 1));  // +1 self loop; deg>=1 always
    s[t] = v;
    __syncthreads();
    for (int off = 1; off < 1024; off <<= 1) {
        int x = (t >= off) ? s[t - off] : 0;
        __syncthreads();
        s[t] += x;
        __syncthreads();
    }
    if (g < n) part[g] = s[t] - v;  // exclusive within block
    if (t == 1023) bsums[blockIdx.x] = s[1023];
}

// Exclusive scan of <=1024 block sums, in place.
__global__ __launch_bounds__(1024) void scan2_k(int* __restrict__ bsums, int nb) {
    __shared__ int s[1024];
    int t = threadIdx.x;
    int v = (t < nb) ? bsums[t] : 0;
    s[t] = v;
    __syncthreads();
    for (int off = 1; off < 1024; off <<= 1) {
        int x = (t >= off) ? s[t - off] : 0;
        __syncthreads();
        s[t] += x;
        __syncthreads();
    }
    if (t < nb) bsums[t] = s[t] - v;
}

__global__ __launch_bounds__(256) void fill_k(const int* __restrict__ ei,
                                              const int* __restrict__ part,
                                              const int* __restrict__ boffs,
                                              int* __restrict__ cursor,
                                              const float* __restrict__ dinv,
                                              int* __restrict__ col,
                                              float* __restrict__ wgt, int E) {
    int e = blockIdx.x * blockDim.x + threadIdx.x;
    if (e >= E) return;
    int s = ei[e];
    int d = ei[E + e];
    int pos  = atomicAdd(&cursor[d], 1);
    int base = part[d] + boffs[d >> 10];
    col[base + pos] = s;
    wgt[base + pos] = dinv[s] * dinv[d];
}

// T[n x OUT] = H[n x IN] @ W[IN x OUT].  Each lane register-caches one column
// of W (IN VGPRs), rows grid-strided so the W load amortizes.  H row loads are
// float4 broadcasts -> VALU-bound.
template <int IN, int OUT>
__global__ __launch_bounds__(256) void gemm_rc_k(const float* __restrict__ H,
                                                 const float* __restrict__ W,
                                                 float* __restrict__ T, int n) {
    constexpr int SUB = 64 / OUT;  // 1 (OUT=64) or 2 (OUT=32)
    const int lane = threadIdx.x & 63;
    const int o    = lane % OUT;
    const int sub  = lane / OUT;
    const int gwid   = (blockIdx.x * blockDim.x + threadIdx.x) >> 6;
    const int nwaves = (gridDim.x * blockDim.x) >> 6;

    float Wc[IN];
#pragma unroll
    for (int k = 0; k < IN; ++k) Wc[k] = W[k * OUT + o];

    for (int r = gwid * SUB + sub; r < n; r += nwaves * SUB) {
        const float4* h4 = reinterpret_cast<const float4*>(H + (size_t)r * IN);
        float acc = 0.f;
#pragma unroll
        for (int k4 = 0; k4 < IN / 4; ++k4) {
            float4 v = h4[k4];
            acc = fmaf(v.x, Wc[4 * k4 + 0], acc);
            acc = fmaf(v.y, Wc[4 * k4 + 1], acc);
            acc = fmaf(v.z, Wc[4 * k4 + 2], acc);
            acc = fmaf(v.w, Wc[4 * k4 + 3], acc);
        }
        T[(size_t)r * OUT + o] = acc;
    }
}

// One wave per node; lane -> feature channel.  Each neighbor = one coalesced
// WIDTH*4B row read.  Self loop folded in as dinv[i]^2 * T[i].
template <int WIDTH>
__global__ __launch_bounds__(256) void agg_k(const float* __restrict__ T,
                                             const int* __restrict__ part,
                                             const int* __restrict__ boffs,
                                             const int* __restrict__ counts,
                                             const int* __restrict__ col,
                                             const float* __restrict__ wgt,
                                             const float* __restrict__ dinv,
                                             const float* __restrict__ bias,
                                             float* __restrict__ O, int n) {
    constexpr int NSUB = 64 / WIDTH;
    const int lane = threadIdx.x & 63;
    const int ch   = lane % WIDTH;
    const int sub  = lane / WIDTH;
    const int i = (blockIdx.x * blockDim.x + threadIdx.x) >> 6;
    if (i >= n) return;

    const int start = part[i] + boffs[i >> 10];
    const int cnt   = counts[i];

    float acc = 0.f;
    for (int e = sub; e < cnt; e += NSUB) {
        int   j = col[start + e];
        float w = wgt[start + e];
        acc = fmaf(w, T[(size_t)j * WIDTH + ch], acc);
    }
    if (sub == 0) {
        float di = dinv[i];
        acc = fmaf(di * di, T[(size_t)i * WIDTH + ch], acc);
    }
    if constexpr (NSUB == 2) acc += __shfl_xor(acc, 32, 64);
    if (sub == 0) {
        float v = acc + bias[ch];
        O[(size_t)i * WIDTH + ch] = fmaxf(v, 0.f);
    }
}

__global__ __launch_bounds__(256) void head_k(const float* __restrict__ H,
                                              const float* __restrict__ Wh,
                                              const float* __restrict__ bh,
                                              float* __restrict__ O, int n) {
    int i = blockIdx.x * blockDim.x + threadIdx.x;
    if (i >= n) return;
    const float4* h4 = reinterpret_cast<const float4*>(H + (size_t)i * 32);
    float a0 = bh[0], a1 = bh[1], a2 = bh[2];
#pragma unroll
    for (int k4 = 0; k4 < 8; ++k4) {
        float4 v = h4[k4];
        int k = k4 * 4;
        a0 = fmaf(v.x, Wh[(k + 0) * 3 + 0], a0);
        a1 = fmaf(v.x, Wh[(k + 0) * 3 + 1], a1);
        a2 = fmaf(v.x, Wh[(k + 0) * 3 + 2], a2);
        a0 = fmaf(v.y, Wh[(k + 1) * 3 + 0], a0);
        a1 = fmaf(v.y, Wh[(k + 1) * 3 + 1], a1);
        a2 = fmaf(v.y, Wh[(k + 1) * 3 + 2], a2);
        a0 = fmaf(v.z, Wh[(k + 2) * 3 + 0], a0);
        a1 = fmaf(v.z, Wh[(k + 2) * 3 + 1], a1);
        a2 = fmaf(v.z, Wh[(k + 2) * 3 + 2], a2);
        a0 = fmaf(v.w, Wh[(k + 3) * 3 + 0], a0);
        a1 = fmaf(v.w, Wh[(k + 3) * 3 + 1], a1);
        a2 = fmaf(v.w, Wh[(k + 3) * 3 + 2], a2);
    }
    O[(size_t)i * 3 + 0] = a0;
    O[(size_t)i * 3 + 1] = a1;
    O[(size_t)i * 3 + 2] = a2;
}

extern "C" void kernel_launch(void* const* d_in, const int* in_sizes, int n_in,
                              void* d_out, int out_size, void* d_ws, size_t ws_size,
                              hipStream_t stream) {
    const float* x  = (const float*)d_in[0];
    const int*   ei = (const int*)d_in[1];
    const float* W1 = (const float*)d_in[2];
    const float* b1 = (const float*)d_in[3];
    const float* W2 = (const float*)d_in[4];
    const float* b2 = (const float*)d_in[5];
    const float* W3 = (const float*)d_in[6];
    const float* b3 = (const float*)d_in[7];
    const float* W4 = (const float*)d_in[8];
    const float* b4 = (const float*)d_in[9];
    const float* Wh = (const float*)d_in[10];
    const float* bh = (const float*)d_in[11];
    float* out = (float*)d_out;

    const int n = in_sizes[0] / 128;
    const int E = in_sizes[1] / 2;
    const int nb = (n + 1023) / 1024;

    // Workspace carve-up (256B aligned regions). ~66 MB total.
    char* ws = (char*)d_ws;
    auto alloc = [&](size_t bytes) {
        char* p = ws;
        ws += (bytes + 255) & ~(size_t)255;
        return p;
    };
    int*   counts = (int*)alloc((size_t)n * 4);
    int*   part   = (int*)alloc((size_t)n * 4);
    int*   cursor = (int*)alloc((size_t)n * 4);
    float* dinv   = (float*)alloc((size_t)n * 4);
    int*   boffs  = (int*)alloc((size_t)nb * 4);
    int*   col    = (int*)alloc((size_t)E * 4);
    float* wgt    = (float*)alloc((size_t)E * 4);
    float* bufA   = (float*)alloc((size_t)n * 64 * 4);
    float* bufB   = (float*)alloc((size_t)n * 64 * 4);

    const int TB = 256;
    dim3 blk(TB);

    // ---- CSR build ----
    init_k<<<dim3((n + TB - 1) / TB), blk, 0, stream>>>(counts, cursor, n);
    count_k<<<dim3((E + TB - 1) / TB), blk, 0, stream>>>(ei, counts, E);
    scan1_k<<<dim3(nb), dim3(1024), 0, stream>>>(counts, part, boffs, dinv, n);
    scan2_k<<<dim3(1), dim3(1024), 0, stream>>>(boffs, nb);
    fill_k<<<dim3((E + TB - 1) / TB), blk, 0, stream>>>(ei, part, boffs, cursor,
                                                        dinv, col, wgt, E);

    const int gemm_blocks = 1024;               // 4096 waves, rows grid-strided
    const int agg_blocks  = (n + 3) / 4;        // one wave per node, 4 waves/block

    // ---- Layer 1: 128 -> 64 ----
    gemm_rc_k<128, 64><<<dim3(gemm_blocks), blk, 0, stream>>>(x, W1, bufA, n);
    agg_k<64><<<dim3(agg_blocks), blk, 0, stream>>>(bufA, part, boffs, counts, col,
                                                    wgt, dinv, b1, bufB, n);
    // ---- Layer 2: 64 -> 64 ----
    gemm_rc_k<64, 64><<<dim3(gemm_blocks), blk, 0, stream>>>(bufB, W2, bufA, n);
    agg_k<64><<<dim3(agg_blocks), blk, 0, stream>>>(bufA, part, boffs, counts, col,
                                                    wgt, dinv, b2, bufB, n);
    // ---- Layer 3: 64 -> 64 ----
    gemm_rc_k<64, 64><<<dim3(gemm_blocks), blk, 0, stream>>>(bufB, W3, bufA, n);
    agg_k<64><<<dim3(agg_blocks), blk, 0, stream>>>(bufA, part, boffs, counts, col,
                                                    wgt, dinv, b3, bufB, n);
    // ---- Layer 4: 64 -> 32 ----
    gemm_rc_k<64, 32><<<dim3(gemm_blocks), blk, 0, stream>>>(bufB, W4, bufA, n);
    agg_k<32><<<dim3(agg_blocks), blk, 0, stream>>>(bufA, part, boffs, counts, col,
                                                    wgt, dinv, b4, bufB, n);
    // ---- Head: 32 -> 3 ----
    head_k<<<dim3((n + TB - 1) / TB), blk, 0, stream>>>(bufB, Wh, bh, out, n);
}

// Round 2
// 879.887 us; speedup vs baseline: 1.3778x; 1.3778x over previous
//
#include <hip/hip_runtime.h>
#include <hip/hip_bf16.h>
#include <cstdint>

// ---------------------------------------------------------------------------
// SPDE GCN: 4x GCNConv (transform -> symmetric-normalized aggregate w/ self
// loops -> bias -> relu) + linear head.  All fp32.
// R2: dense transform rewritten as LDS-tiled fp32 GEMM (old register-cached-W
// version was latency-bound: VALUBusy 11%, occupancy 10%, 300us for L1).
// ---------------------------------------------------------------------------

__global__ __launch_bounds__(256) void init_k(int* __restrict__ counts,
                                              int* __restrict__ cursor, int n) {
    int i = blockIdx.x * blockDim.x + threadIdx.x;
    if (i < n) { counts[i] = 0; cursor[i] = 0; }
}

__global__ __launch_bounds__(256) void count_k(const int* __restrict__ ei,
                                               int* __restrict__ counts, int E) {
    int e = blockIdx.x * blockDim.x + threadIdx.x;
    if (e < E) atomicAdd(&counts[ei[E + e]], 1);
}

// Inclusive LDS scan of 1024 elements per block; writes per-element exclusive
// prefix (within block) and the block total.  Also computes dinv.
__global__ __launch_bounds__(1024) void scan1_k(const int* __restrict__ counts,
                                                int* __restrict__ part,
                                                int* __restrict__ bsums,
                                                float* __restrict__ dinv, int n) {
    __shared__ int s[1024];
    int t = threadIdx.x;
    int g = blockIdx.x * 1024 + t;
    int v = (g < n) ? counts[g] : 0;
    if (g < n) dinv[g] = rsqrtf((float)(v + 1));  // +1 self loop; deg>=1 always
    s[t] = v;
    __syncthreads();
    for (int off = 1; off < 1024; off <<= 1) {
        int x = (t >= off) ? s[t - off] : 0;
        __syncthreads();
        s[t] += x;
        __syncthreads();
    }
    if (g < n) part[g] = s[t] - v;  // exclusive within block
    if (t == 1023) bsums[blockIdx.x] = s[1023];
}

// Exclusive scan of <=1024 block sums, in place.
__global__ __launch_bounds__(1024) void scan2_k(int* __restrict__ bsums, int nb) {
    __shared__ int s[1024];
    int t = threadIdx.x;
    int v = (t < nb) ? bsums[t] : 0;
    s[t] = v;
    __syncthreads();
    for (int off = 1; off < 1024; off <<= 1) {
        int x = (t >= off) ? s[t - off] : 0;
        __syncthreads();
        s[t] += x;
        __syncthreads();
    }
    if (t < nb) bsums[t] = s[t] - v;
}

__global__ __launch_bounds__(256) void fill_k(const int* __restrict__ ei,
                                              const int* __restrict__ part,
                                              const int* __restrict__ boffs,
                                              int* __restrict__ cursor,
                                              const float* __restrict__ dinv,
                                              int* __restrict__ col,
                                              float* __restrict__ wgt, int E) {
    int e = blockIdx.x * blockDim.x + threadIdx.x;
    if (e >= E) return;
    int s = ei[e];
    int d = ei[E + e];
    int pos  = atomicAdd(&cursor[d], 1);
    int base = part[d] + boffs[d >> 10];
    col[base + pos] = s;
    wgt[base + pos] = dinv[s] * dinv[d];
}

// T[n x OUT] = H[n x K] @ W[K x OUT].  LDS-tiled: BM rows x OUT cols per
// block, BK=32 k-slices.  A staged transposed (pad +4 keeps b128 alignment
// and spreads banks); each thread owns a 4x4 register tile.
// Per k: 2x ds_read_b128 (~12cyc) vs 16 FMA (32cyc) -> VALU-bound.
template <int K, int OUT>
__global__ __launch_bounds__(256) void gemm_tile_k(const float* __restrict__ H,
                                                   const float* __restrict__ W,
                                                   float* __restrict__ T, int n) {
    constexpr int TX  = OUT / 4;    // threads along cols: 16 (OUT=64) / 8 (OUT=32)
    constexpr int TY  = 256 / TX;   // 16 / 32
    constexpr int BM  = TY * 4;     // 64 / 128
    constexpr int BK  = 32;
    constexpr int PAD = 4;          // keeps (k*(BM+PAD)+4*ry) a multiple of 4 floats

    __shared__ float At[BK][BM + PAD];  // A transposed: At[k][row]
    __shared__ float Ws[BK][OUT];       // W slice: Ws[k][col]

    const int t    = threadIdx.x;
    const int cx   = t % TX;            // col-thread
    const int ry   = t / TX;            // row-thread
    const int row0 = blockIdx.x * BM;

    float acc[4][4] = {{0.f}};

    // A staging map: 8 float4 per row-slice -> 8 threads/row, 32 rows/pass
    const int arow = t >> 3;  // 0..31
    const int af4  = t & 7;   // 0..7  (k4 within slice)

    for (int k0 = 0; k0 < K; k0 += BK) {
        // ---- stage A (transposed) ----
#pragma unroll
        for (int p = 0; p < BM / 32; ++p) {
            int r  = arow + p * 32;
            int gr = row0 + r;
            int grc = gr < n ? gr : n - 1;  // clamp; values unused on tail
            float4 v = *reinterpret_cast<const float4*>(
                H + (size_t)grc * K + k0 + af4 * 4);
            At[af4 * 4 + 0][r] = v.x;
            At[af4 * 4 + 1][r] = v.y;
            At[af4 * 4 + 2][r] = v.z;
            At[af4 * 4 + 3][r] = v.w;
        }
        // ---- stage W slice ----
#pragma unroll
        for (int p = 0; p < (BK * OUT) / 1024; ++p) {
            int idx = t + p * 256;          // float4 index within slice
            int wk  = idx / (OUT / 4);
            int wf  = idx % (OUT / 4);
            float4 v = *reinterpret_cast<const float4*>(
                W + (size_t)(k0 + wk) * OUT + wf * 4);
            *reinterpret_cast<float4*>(&Ws[wk][wf * 4]) = v;
        }
        __syncthreads();
        // ---- compute ----
#pragma unroll
        for (int k = 0; k < BK; ++k) {
            float4 a = *reinterpret_cast<const float4*>(&At[k][ry * 4]);
            float4 w = *reinterpret_cast<const float4*>(&Ws[k][cx * 4]);
            acc[0][0] = fmaf(a.x, w.x, acc[0][0]);
            acc[0][1] = fmaf(a.x, w.y, acc[0][1]);
            acc[0][2] = fmaf(a.x, w.z, acc[0][2]);
            acc[0][3] = fmaf(a.x, w.w, acc[0][3]);
            acc[1][0] = fmaf(a.y, w.x, acc[1][0]);
            acc[1][1] = fmaf(a.y, w.y, acc[1][1]);
            acc[1][2] = fmaf(a.y, w.z, acc[1][2]);
            acc[1][3] = fmaf(a.y, w.w, acc[1][3]);
            acc[2][0] = fmaf(a.z, w.x, acc[2][0]);
            acc[2][1] = fmaf(a.z, w.y, acc[2][1]);
            acc[2][2] = fmaf(a.z, w.z, acc[2][2]);
            acc[2][3] = fmaf(a.z, w.w, acc[2][3]);
            acc[3][0] = fmaf(a.w, w.x, acc[3][0]);
            acc[3][1] = fmaf(a.w, w.y, acc[3][1]);
            acc[3][2] = fmaf(a.w, w.z, acc[3][2]);
            acc[3][3] = fmaf(a.w, w.w, acc[3][3]);
        }
        __syncthreads();
    }
    // ---- store 4x4 tile ----
#pragma unroll
    for (int i = 0; i < 4; ++i) {
        int gr = row0 + ry * 4 + i;
        if (gr < n) {
            float4 v = make_float4(acc[i][0], acc[i][1], acc[i][2], acc[i][3]);
            *reinterpret_cast<float4*>(T + (size_t)gr * OUT + cx * 4) = v;
        }
    }
}

// One wave per node; lane -> feature channel.  Each neighbor = one coalesced
// WIDTH*4B row read.  Self loop folded in as dinv[i]^2 * T[i].
template <int WIDTH>
__global__ __launch_bounds__(256) void agg_k(const float* __restrict__ T,
                                             const int* __restrict__ part,
                                             const int* __restrict__ boffs,
                                             const int* __restrict__ counts,
                                             const int* __restrict__ col,
                                             const float* __restrict__ wgt,
                                             const float* __restrict__ dinv,
                                             const float* __restrict__ bias,
                                             float* __restrict__ O, int n) {
    constexpr int NSUB = 64 / WIDTH;
    const int lane = threadIdx.x & 63;
    const int ch   = lane % WIDTH;
    const int sub  = lane / WIDTH;
    const int i = (blockIdx.x * blockDim.x + threadIdx.x) >> 6;
    if (i >= n) return;

    const int start = part[i] + boffs[i >> 10];
    const int cnt   = counts[i];

    float acc = 0.f;
    for (int e = sub; e < cnt; e += NSUB) {
        int   j = col[start + e];
        float w = wgt[start + e];
        acc = fmaf(w, T[(size_t)j * WIDTH + ch], acc);
    }
    if (sub == 0) {
        float di = dinv[i];
        acc = fmaf(di * di, T[(size_t)i * WIDTH + ch], acc);
    }
    if constexpr (NSUB == 2) acc += __shfl_xor(acc, 32, 64);
    if (sub == 0) {
        float v = acc + bias[ch];
        O[(size_t)i * WIDTH + ch] = fmaxf(v, 0.f);
    }
}

__global__ __launch_bounds__(256) void head_k(const float* __restrict__ H,
                                              const float* __restrict__ Wh,
                                              const float* __restrict__ bh,
                                              float* __restrict__ O, int n) {
    int i = blockIdx.x * blockDim.x + threadIdx.x;
    if (i >= n) return;
    const float4* h4 = reinterpret_cast<const float4*>(H + (size_t)i * 32);
    float a0 = bh[0], a1 = bh[1], a2 = bh[2];
#pragma unroll
    for (int k4 = 0; k4 < 8; ++k4) {
        float4 v = h4[k4];
        int k = k4 * 4;
        a0 = fmaf(v.x, Wh[(k + 0) * 3 + 0], a0);
        a1 = fmaf(v.x, Wh[(k + 0) * 3 + 1], a1);
        a2 = fmaf(v.x, Wh[(k + 0) * 3 + 2], a2);
        a0 = fmaf(v.y, Wh[(k + 1) * 3 + 0], a0);
        a1 = fmaf(v.y, Wh[(k + 1) * 3 + 1], a1);
        a2 = fmaf(v.y, Wh[(k + 1) * 3 + 2], a2);
        a0 = fmaf(v.z, Wh[(k + 2) * 3 + 0], a0);
        a1 = fmaf(v.z, Wh[(k + 2) * 3 + 1], a1);
        a2 = fmaf(v.z, Wh[(k + 2) * 3 + 2], a2);
        a0 = fmaf(v.w, Wh[(k + 3) * 3 + 0], a0);
        a1 = fmaf(v.w, Wh[(k + 3) * 3 + 1], a1);
        a2 = fmaf(v.w, Wh[(k + 3) * 3 + 2], a2);
    }
    O[(size_t)i * 3 + 0] = a0;
    O[(size_t)i * 3 + 1] = a1;
    O[(size_t)i * 3 + 2] = a2;
}

extern "C" void kernel_launch(void* const* d_in, const int* in_sizes, int n_in,
                              void* d_out, int out_size, void* d_ws, size_t ws_size,
                              hipStream_t stream) {
    const float* x  = (const float*)d_in[0];
    const int*   ei = (const int*)d_in[1];
    const float* W1 = (const float*)d_in[2];
    const float* b1 = (const float*)d_in[3];
    const float* W2 = (const float*)d_in[4];
    const float* b2 = (const float*)d_in[5];
    const float* W3 = (const float*)d_in[6];
    const float* b3 = (const float*)d_in[7];
    const float* W4 = (const float*)d_in[8];
    const float* b4 = (const float*)d_in[9];
    const float* Wh = (const float*)d_in[10];
    const float* bh = (const float*)d_in[11];
    float* out = (float*)d_out;

    const int n = in_sizes[0] / 128;
    const int E = in_sizes[1] / 2;
    const int nb = (n + 1023) / 1024;

    // Workspace carve-up (256B aligned regions). ~66 MB total.
    char* ws = (char*)d_ws;
    auto alloc = [&](size_t bytes) {
        char* p = ws;
        ws += (bytes + 255) & ~(size_t)255;
        return p;
    };
    int*   counts = (int*)alloc((size_t)n * 4);
    int*   part   = (int*)alloc((size_t)n * 4);
    int*   cursor = (int*)alloc((size_t)n * 4);
    float* dinv   = (float*)alloc((size_t)n * 4);
    int*   boffs  = (int*)alloc((size_t)nb * 4);
    int*   col    = (int*)alloc((size_t)E * 4);
    float* wgt    = (float*)alloc((size_t)E * 4);
    float* bufA   = (float*)alloc((size_t)n * 64 * 4);
    float* bufB   = (float*)alloc((size_t)n * 64 * 4);

    const int TB = 256;
    dim3 blk(TB);

    // ---- CSR build ----
    init_k<<<dim3((n + TB - 1) / TB), blk, 0, stream>>>(counts, cursor, n);
    count_k<<<dim3((E + TB - 1) / TB), blk, 0, stream>>>(ei, counts, E);
    scan1_k<<<dim3(nb), dim3(1024), 0, stream>>>(counts, part, boffs, dinv, n);
    scan2_k<<<dim3(1), dim3(1024), 0, stream>>>(boffs, nb);
    fill_k<<<dim3((E + TB - 1) / TB), blk, 0, stream>>>(ei, part, boffs, cursor,
                                                        dinv, col, wgt, E);

    const int agg_blocks = (n + 3) / 4;  // one wave per node, 4 waves/block

    // ---- Layer 1: 128 -> 64 ----
    gemm_tile_k<128, 64><<<dim3((n + 63) / 64), blk, 0, stream>>>(x, W1, bufA, n);
    agg_k<64><<<dim3(agg_blocks), blk, 0, stream>>>(bufA, part, boffs, counts, col,
                                                    wgt, dinv, b1, bufB, n);
    // ---- Layer 2: 64 -> 64 ----
    gemm_tile_k<64, 64><<<dim3((n + 63) / 64), blk, 0, stream>>>(bufB, W2, bufA, n);
    agg_k<64><<<dim3(agg_blocks), blk, 0, stream>>>(bufA, part, boffs, counts, col,
                                                    wgt, dinv, b2, bufB, n);
    // ---- Layer 3: 64 -> 64 ----
    gemm_tile_k<64, 64><<<dim3((n + 63) / 64), blk, 0, stream>>>(bufB, W3, bufA, n);
    agg_k<64><<<dim3(agg_blocks), blk, 0, stream>>>(bufA, part, boffs, counts, col,
                                                    wgt, dinv, b3, bufB, n);
    // ---- Layer 4: 64 -> 32 ----
    gemm_tile_k<64, 32><<<dim3((n + 127) / 128), blk, 0, stream>>>(bufB, W4, bufA, n);
    agg_k<32><<<dim3(agg_blocks), blk, 0, stream>>>(bufA, part, boffs, counts, col,
                                                    wgt, dinv, b4, bufB, n);
    // ---- Head: 32 -> 3 ----
    head_k<<<dim3((n + TB - 1) / TB), blk, 0, stream>>>(bufB, Wh, bh, out, n);
}

// Round 3
// 579.681 us; speedup vs baseline: 2.0913x; 1.5179x over previous
//
#include <hip/hip_runtime.h>
#include <hip/hip_bf16.h>
#include <cstdint>

// ---------------------------------------------------------------------------
// SPDE GCN: 4x GCNConv (transform -> symmetric-normalized aggregate w/ self
// loops -> bias -> relu) + linear head.  All fp32.
// R2: LDS-tiled fp32 GEMM for transforms.
// R3: agg_k restructured for memory-level parallelism.  R2 counters showed
//     the edge loop fully serialized (~1450 cyc/edge: col load -> row load
//     dependent chain, 2.7 TB/s L2 traffic vs 34.5 ceiling).  Now the wave
//     bulk-loads 64 edges' (col,wgt) coalesced, shfl-broadcasts them (VALU),
//     and issues 8 independent row loads per unrolled step.
// ---------------------------------------------------------------------------

__global__ __launch_bounds__(256) void init_k(int* __restrict__ counts,
                                              int* __restrict__ cursor, int n) {
    int i = blockIdx.x * blockDim.x + threadIdx.x;
    if (i < n) { counts[i] = 0; cursor[i] = 0; }
}

__global__ __launch_bounds__(256) void count_k(const int* __restrict__ ei,
                                               int* __restrict__ counts, int E) {
    int e = blockIdx.x * blockDim.x + threadIdx.x;
    if (e < E) atomicAdd(&counts[ei[E + e]], 1);
}

// Inclusive LDS scan of 1024 elements per block; writes per-element exclusive
// prefix (within block) and the block total.  Also computes dinv.
__global__ __launch_bounds__(1024) void scan1_k(const int* __restrict__ counts,
                                                int* __restrict__ part,
                                                int* __restrict__ bsums,
                                                float* __restrict__ dinv, int n) {
    __shared__ int s[1024];
    int t = threadIdx.x;
    int g = blockIdx.x * 1024 + t;
    int v = (g < n) ? counts[g] : 0;
    if (g < n) dinv[g] = rsqrtf((float)(v + 1));  // +1 self loop; deg>=1 always
    s[t] = v;
    __syncthreads();
    for (int off = 1; off < 1024; off <<= 1) {
        int x = (t >= off) ? s[t - off] : 0;
        __syncthreads();
        s[t] += x;
        __syncthreads();
    }
    if (g < n) part[g] = s[t] - v;  // exclusive within block
    if (t == 1023) bsums[blockIdx.x] = s[1023];
}

// Exclusive scan of <=1024 block sums, in place.
__global__ __launch_bounds__(1024) void scan2_k(int* __restrict__ bsums, int nb) {
    __shared__ int s[1024];
    int t = threadIdx.x;
    int v = (t < nb) ? bsums[t] : 0;
    s[t] = v;
    __syncthreads();
    for (int off = 1; off < 1024; off <<= 1) {
        int x = (t >= off) ? s[t - off] : 0;
        __syncthreads();
        s[t] += x;
        __syncthreads();
    }
    if (t < nb) bsums[t] = s[t] - v;
}

__global__ __launch_bounds__(256) void fill_k(const int* __restrict__ ei,
                                              const int* __restrict__ part,
                                              const int* __restrict__ boffs,
                                              int* __restrict__ cursor,
                                              const float* __restrict__ dinv,
                                              int* __restrict__ col,
                                              float* __restrict__ wgt, int E) {
    int e = blockIdx.x * blockDim.x + threadIdx.x;
    if (e >= E) return;
    int s = ei[e];
    int d = ei[E + e];
    int pos  = atomicAdd(&cursor[d], 1);
    int base = part[d] + boffs[d >> 10];
    col[base + pos] = s;
    wgt[base + pos] = dinv[s] * dinv[d];
}

// T[n x OUT] = H[n x K] @ W[K x OUT].  LDS-tiled: BM rows x OUT cols per
// block, BK=32 k-slices.  A staged transposed; 4x4 register tile per thread.
template <int K, int OUT>
__global__ __launch_bounds__(256) void gemm_tile_k(const float* __restrict__ H,
                                                   const float* __restrict__ W,
                                                   float* __restrict__ T, int n) {
    constexpr int TX  = OUT / 4;
    constexpr int TY  = 256 / TX;
    constexpr int BM  = TY * 4;
    constexpr int BK  = 32;
    constexpr int PAD = 4;

    __shared__ float At[BK][BM + PAD];
    __shared__ float Ws[BK][OUT];

    const int t    = threadIdx.x;
    const int cx   = t % TX;
    const int ry   = t / TX;
    const int row0 = blockIdx.x * BM;

    float acc[4][4] = {{0.f}};

    const int arow = t >> 3;
    const int af4  = t & 7;

    for (int k0 = 0; k0 < K; k0 += BK) {
#pragma unroll
        for (int p = 0; p < BM / 32; ++p) {
            int r  = arow + p * 32;
            int gr = row0 + r;
            int grc = gr < n ? gr : n - 1;
            float4 v = *reinterpret_cast<const float4*>(
                H + (size_t)grc * K + k0 + af4 * 4);
            At[af4 * 4 + 0][r] = v.x;
            At[af4 * 4 + 1][r] = v.y;
            At[af4 * 4 + 2][r] = v.z;
            At[af4 * 4 + 3][r] = v.w;
        }
#pragma unroll
        for (int p = 0; p < (BK * OUT) / 1024; ++p) {
            int idx = t + p * 256;
            int wk  = idx / (OUT / 4);
            int wf  = idx % (OUT / 4);
            float4 v = *reinterpret_cast<const float4*>(
                W + (size_t)(k0 + wk) * OUT + wf * 4);
            *reinterpret_cast<float4*>(&Ws[wk][wf * 4]) = v;
        }
        __syncthreads();
#pragma unroll
        for (int k = 0; k < BK; ++k) {
            float4 a = *reinterpret_cast<const float4*>(&At[k][ry * 4]);
            float4 w = *reinterpret_cast<const float4*>(&Ws[k][cx * 4]);
            acc[0][0] = fmaf(a.x, w.x, acc[0][0]);
            acc[0][1] = fmaf(a.x, w.y, acc[0][1]);
            acc[0][2] = fmaf(a.x, w.z, acc[0][2]);
            acc[0][3] = fmaf(a.x, w.w, acc[0][3]);
            acc[1][0] = fmaf(a.y, w.x, acc[1][0]);
            acc[1][1] = fmaf(a.y, w.y, acc[1][1]);
            acc[1][2] = fmaf(a.y, w.z, acc[1][2]);
            acc[1][3] = fmaf(a.y, w.w, acc[1][3]);
            acc[2][0] = fmaf(a.z, w.x, acc[2][0]);
            acc[2][1] = fmaf(a.z, w.y, acc[2][1]);
            acc[2][2] = fmaf(a.z, w.z, acc[2][2]);
            acc[2][3] = fmaf(a.z, w.w, acc[2][3]);
            acc[3][0] = fmaf(a.w, w.x, acc[3][0]);
            acc[3][1] = fmaf(a.w, w.y, acc[3][1]);
            acc[3][2] = fmaf(a.w, w.z, acc[3][2]);
            acc[3][3] = fmaf(a.w, w.w, acc[3][3]);
        }
        __syncthreads();
    }
#pragma unroll
    for (int i = 0; i < 4; ++i) {
        int gr = row0 + ry * 4 + i;
        if (gr < n) {
            float4 v = make_float4(acc[i][0], acc[i][1], acc[i][2], acc[i][3]);
            *reinterpret_cast<float4*>(T + (size_t)gr * OUT + cx * 4) = v;
        }
    }
}

// One wave per node.  Wave bulk-loads up to 64 (col,wgt) pairs coalesced
// (lane = edge), then shfl-broadcasts and issues 8 independent row loads per
// unrolled step -> high MLP, no dependent col->row load chain.
// Self loop folded in as dinv[i]^2 * T[i].
template <int WIDTH>
__global__ __launch_bounds__(256) void agg_k(const float* __restrict__ T,
                                             const int* __restrict__ part,
                                             const int* __restrict__ boffs,
                                             const int* __restrict__ counts,
                                             const int* __restrict__ col,
                                             const float* __restrict__ wgt,
                                             const float* __restrict__ dinv,
                                             const float* __restrict__ bias,
                                             float* __restrict__ O, int n) {
    constexpr int NSUB = 64 / WIDTH;  // 1 (WIDTH=64) or 2 (WIDTH=32)
    constexpr int U    = 8;           // row loads in flight per sub-wave
    const int lane = threadIdx.x & 63;
    const int ch   = lane % WIDTH;
    const int sub  = lane / WIDTH;
    const int i = (blockIdx.x * blockDim.x + threadIdx.x) >> 6;
    if (i >= n) return;

    const int start = part[i] + boffs[i >> 10];
    const int cnt   = counts[i];
    const float* __restrict__ Tc = T + ch;

    float acc = 0.f;
    for (int base = 0; base < cnt; base += 64) {
        const int m = min(64, cnt - base);
        // coalesced bulk load of this chunk's edges (lane = edge index)
        int   c_l = 0;
        float w_l = 0.f;
        if (lane < m) {
            c_l = col[start + base + lane];
            w_l = wgt[start + base + lane];
        }
        int jg = 0;
        // main: U*NSUB edges per uniform step; per-sub edges jg + u*NSUB + sub
        for (; jg + U * NSUB <= m; jg += U * NSUB) {
            int   c[U]; float w[U]; float v[U];
#pragma unroll
            for (int u = 0; u < U; ++u) {
                int j = jg + u * NSUB + sub;
                c[u] = __shfl(c_l, j, 64);
                w[u] = __shfl(w_l, j, 64);
            }
#pragma unroll
            for (int u = 0; u < U; ++u) v[u] = Tc[(size_t)c[u] * WIDTH];
#pragma unroll
            for (int u = 0; u < U; ++u) acc = fmaf(w[u], v[u], acc);
        }
        // tail: uniform trip count; out-of-range edges get weight 0
        for (; jg < m; jg += NSUB) {
            int j  = jg + sub;
            int jc = j < m ? j : 0;
            int   cc = __shfl(c_l, jc, 64);
            float ww = __shfl(w_l, jc, 64);
            if (j >= m) ww = 0.f;
            acc = fmaf(ww, Tc[(size_t)cc * WIDTH], acc);
        }
    }
    if (sub == 0) {
        float di = dinv[i];
        acc = fmaf(di * di, Tc[(size_t)i * WIDTH], acc);
    }
    if constexpr (NSUB == 2) acc += __shfl_xor(acc, 32, 64);
    if (sub == 0) {
        float v = acc + bias[ch];
        O[(size_t)i * WIDTH + ch] = fmaxf(v, 0.f);
    }
}

__global__ __launch_bounds__(256) void head_k(const float* __restrict__ H,
                                              const float* __restrict__ Wh,
                                              const float* __restrict__ bh,
                                              float* __restrict__ O, int n) {
    int i = blockIdx.x * blockDim.x + threadIdx.x;
    if (i >= n) return;
    const float4* h4 = reinterpret_cast<const float4*>(H + (size_t)i * 32);
    float a0 = bh[0], a1 = bh[1], a2 = bh[2];
#pragma unroll
    for (int k4 = 0; k4 < 8; ++k4) {
        float4 v = h4[k4];
        int k = k4 * 4;
        a0 = fmaf(v.x, Wh[(k + 0) * 3 + 0], a0);
        a1 = fmaf(v.x, Wh[(k + 0) * 3 + 1], a1);
        a2 = fmaf(v.x, Wh[(k + 0) * 3 + 2], a2);
        a0 = fmaf(v.y, Wh[(k + 1) * 3 + 0], a0);
        a1 = fmaf(v.y, Wh[(k + 1) * 3 + 1], a1);
        a2 = fmaf(v.y, Wh[(k + 1) * 3 + 2], a2);
        a0 = fmaf(v.z, Wh[(k + 2) * 3 + 0], a0);
        a1 = fmaf(v.z, Wh[(k + 2) * 3 + 1], a1);
        a2 = fmaf(v.z, Wh[(k + 2) * 3 + 2], a2);
        a0 = fmaf(v.w, Wh[(k + 3) * 3 + 0], a0);
        a1 = fmaf(v.w, Wh[(k + 3) * 3 + 1], a1);
        a2 = fmaf(v.w, Wh[(k + 3) * 3 + 2], a2);
    }
    O[(size_t)i * 3 + 0] = a0;
    O[(size_t)i * 3 + 1] = a1;
    O[(size_t)i * 3 + 2] = a2;
}

extern "C" void kernel_launch(void* const* d_in, const int* in_sizes, int n_in,
                              void* d_out, int out_size, void* d_ws, size_t ws_size,
                              hipStream_t stream) {
    const float* x  = (const float*)d_in[0];
    const int*   ei = (const int*)d_in[1];
    const float* W1 = (const float*)d_in[2];
    const float* b1 = (const float*)d_in[3];
    const float* W2 = (const float*)d_in[4];
    const float* b2 = (const float*)d_in[5];
    const float* W3 = (const float*)d_in[6];
    const float* b3 = (const float*)d_in[7];
    const float* W4 = (const float*)d_in[8];
    const float* b4 = (const float*)d_in[9];
    const float* Wh = (const float*)d_in[10];
    const float* bh = (const float*)d_in[11];
    float* out = (float*)d_out;

    const int n = in_sizes[0] / 128;
    const int E = in_sizes[1] / 2;
    const int nb = (n + 1023) / 1024;

    char* ws = (char*)d_ws;
    auto alloc = [&](size_t bytes) {
        char* p = ws;
        ws += (bytes + 255) & ~(size_t)255;
        return p;
    };
    int*   counts = (int*)alloc((size_t)n * 4);
    int*   part   = (int*)alloc((size_t)n * 4);
    int*   cursor = (int*)alloc((size_t)n * 4);
    float* dinv   = (float*)alloc((size_t)n * 4);
    int*   boffs  = (int*)alloc((size_t)nb * 4);
    int*   col    = (int*)alloc((size_t)E * 4);
    float* wgt    = (float*)alloc((size_t)E * 4);
    float* bufA   = (float*)alloc((size_t)n * 64 * 4);
    float* bufB   = (float*)alloc((size_t)n * 64 * 4);

    const int TB = 256;
    dim3 blk(TB);

    // ---- CSR build ----
    init_k<<<dim3((n + TB - 1) / TB), blk, 0, stream>>>(counts, cursor, n);
    count_k<<<dim3((E + TB - 1) / TB), blk, 0, stream>>>(ei, counts, E);
    scan1_k<<<dim3(nb), dim3(1024), 0, stream>>>(counts, part, boffs, dinv, n);
    scan2_k<<<dim3(1), dim3(1024), 0, stream>>>(boffs, nb);
    fill_k<<<dim3((E + TB - 1) / TB), blk, 0, stream>>>(ei, part, boffs, cursor,
                                                        dinv, col, wgt, E);

    const int agg_blocks = (n + 3) / 4;  // one wave per node, 4 waves/block

    // ---- Layer 1: 128 -> 64 ----
    gemm_tile_k<128, 64><<<dim3((n + 63) / 64), blk, 0, stream>>>(x, W1, bufA, n);
    agg_k<64><<<dim3(agg_blocks), blk, 0, stream>>>(bufA, part, boffs, counts, col,
                                                    wgt, dinv, b1, bufB, n);
    // ---- Layer 2: 64 -> 64 ----
    gemm_tile_k<64, 64><<<dim3((n + 63) / 64), blk, 0, stream>>>(bufB, W2, bufA, n);
    agg_k<64><<<dim3(agg_blocks), blk, 0, stream>>>(bufA, part, boffs, counts, col,
                                                    wgt, dinv, b2, bufB, n);
    // ---- Layer 3: 64 -> 64 ----
    gemm_tile_k<64, 64><<<dim3((n + 63) / 64), blk, 0, stream>>>(bufB, W3, bufA, n);
    agg_k<64><<<dim3(agg_blocks), blk, 0, stream>>>(bufA, part, boffs, counts, col,
                                                    wgt, dinv, b3, bufB, n);
    // ---- Layer 4: 64 -> 32 ----
    gemm_tile_k<64, 32><<<dim3((n + 127) / 128), blk, 0, stream>>>(bufB, W4, bufA, n);
    agg_k<32><<<dim3(agg_blocks), blk, 0, stream>>>(bufA, part, boffs, counts, col,
                                                    wgt, dinv, b4, bufB, n);
    // ---- Head: 32 -> 3 ----
    head_k<<<dim3((n + TB - 1) / TB), blk, 0, stream>>>(bufB, Wh, bh, out, n);
}

// Round 4
// 520.936 us; speedup vs baseline: 2.3271x; 1.1128x over previous
//
#include <hip/hip_runtime.h>
#include <hip/hip_bf16.h>
#include <cstdint>

// ---------------------------------------------------------------------------
// SPDE GCN: 4x GCNConv + linear head, all fp32.
// R2: LDS-tiled fp32 GEMM for transforms.
// R3: agg_k restructured for MLP (bulk edge load + shfl broadcast + 8-deep
//     independent row loads).
// R4: CSR build de-bottlenecked.  R3 counters: fill_k 80-110us, VALUBusy
//     0.8%, WRITE_SIZE 155MB for 12.8MB payload (12x write amplification,
//     two scattered 4B stores/edge).  Changes:
//       (a) wgt array eliminated: T' = dinv*(h@W) scaled in GEMM epilogue,
//           agg multiplies by dinv[i] once -> one scatter per edge.
//       (b) rank-during-count + fused rowptr -> fill has no atomic, 4 edges
//           per thread, independent gathers/scatters (MLP).
//       (c) fill fused with layer-1 GEMM (independent work, interleaved
//           blocks) so GEMM FMAs hide fill's memory latency.
//       (d) head (32->3) fused into agg_k<32> epilogue via shfl reduction.
// ---------------------------------------------------------------------------

__global__ __launch_bounds__(256) void init_k(int* __restrict__ counts, int n) {
    int i = blockIdx.x * blockDim.x + threadIdx.x;
    if (i < n) counts[i] = 0;
}

// In-degree histogram; also records each edge's arrival rank in its bucket
// (coalesced write) so fill needs no atomic.
__global__ __launch_bounds__(256) void count_k(const int* __restrict__ ei,
                                               int* __restrict__ counts,
                                               int* __restrict__ rank, int E) {
    int e = blockIdx.x * blockDim.x + threadIdx.x;
    if (e < E) rank[e] = atomicAdd(&counts[ei[E + e]], 1);
}

// Inclusive LDS scan of 1024 per block -> per-element exclusive prefix +
// block total; dinv = rsqrt(deg+1) fused.
__global__ __launch_bounds__(1024) void scan1_k(const int* __restrict__ counts,
                                                int* __restrict__ part,
                                                int* __restrict__ bsums,
                                                float* __restrict__ dinv, int n) {
    __shared__ int s[1024];
    int t = threadIdx.x;
    int g = blockIdx.x * 1024 + t;
    int v = (g < n) ? counts[g] : 0;
    if (g < n) dinv[g] = rsqrtf((float)(v + 1));
    s[t] = v;
    __syncthreads();
    for (int off = 1; off < 1024; off <<= 1) {
        int x = (t >= off) ? s[t - off] : 0;
        __syncthreads();
        s[t] += x;
        __syncthreads();
    }
    if (g < n) part[g] = s[t] - v;
    if (t == 1023) bsums[blockIdx.x] = s[1023];
}

__global__ __launch_bounds__(1024) void scan2_k(int* __restrict__ bsums, int nb) {
    __shared__ int s[1024];
    int t = threadIdx.x;
    int v = (t < nb) ? bsums[t] : 0;
    s[t] = v;
    __syncthreads();
    for (int off = 1; off < 1024; off <<= 1) {
        int x = (t >= off) ? s[t - off] : 0;
        __syncthreads();
        s[t] += x;
        __syncthreads();
    }
    if (t < nb) bsums[t] = s[t] - v;
}

__global__ __launch_bounds__(256) void finalize_k(const int* __restrict__ part,
                                                  const int* __restrict__ boffs,
                                                  int* __restrict__ rowptr, int n) {
    int i = blockIdx.x * blockDim.x + threadIdx.x;
    if (i < n) rowptr[i] = part[i] + boffs[i >> 10];
}

// ---- fill body: 4 edges/thread, no atomics, independent gathers/scatters ---
__device__ __forceinline__ void fill_body(const int* __restrict__ ei,
                                          const int* __restrict__ rowptr,
                                          const int* __restrict__ rank,
                                          int* __restrict__ col,
                                          int E, int fb) {
    constexpr int EPT = 4;
    const int t0 = fb * (256 * EPT) + threadIdx.x;
    int s[EPT], d[EPT], r[EPT];
#pragma unroll
    for (int k = 0; k < EPT; ++k) {
        int e = t0 + k * 256;
        if (e < E) { s[k] = ei[e]; d[k] = ei[E + e]; r[k] = rank[e]; }
        else s[k] = -1;
    }
    int b[EPT];
#pragma unroll
    for (int k = 0; k < EPT; ++k)
        if (s[k] >= 0) b[k] = rowptr[d[k]];
#pragma unroll
    for (int k = 0; k < EPT; ++k)
        if (s[k] >= 0) col[b[k] + r[k]] = s[k];
}

// ---- GEMM body: T'[n x OUT] = dinv[r] * (H[n x K] @ W[K x OUT]) ----------
template <int K, int OUT>
__device__ __forceinline__ void gemm_body(const float* __restrict__ H,
                                          const float* __restrict__ W,
                                          const float* __restrict__ dinv,
                                          float* __restrict__ T, int n, int bx) {
    constexpr int TX  = OUT / 4;
    constexpr int TY  = 256 / TX;
    constexpr int BM  = TY * 4;
    constexpr int BK  = 32;
    constexpr int PAD = 4;

    __shared__ float At[BK][BM + PAD];
    __shared__ float Ws[BK][OUT];

    const int t    = threadIdx.x;
    const int cx   = t % TX;
    const int ry   = t / TX;
    const int row0 = bx * BM;

    float acc[4][4] = {{0.f}};
    const int arow = t >> 3;
    const int af4  = t & 7;

    for (int k0 = 0; k0 < K; k0 += BK) {
#pragma unroll
        for (int p = 0; p < BM / 32; ++p) {
            int r  = arow + p * 32;
            int gr = row0 + r;
            int grc = gr < n ? gr : n - 1;
            float4 v = *reinterpret_cast<const float4*>(
                H + (size_t)grc * K + k0 + af4 * 4);
            At[af4 * 4 + 0][r] = v.x;
            At[af4 * 4 + 1][r] = v.y;
            At[af4 * 4 + 2][r] = v.z;
            At[af4 * 4 + 3][r] = v.w;
        }
#pragma unroll
        for (int p = 0; p < (BK * OUT) / 1024; ++p) {
            int idx = t + p * 256;
            int wk  = idx / (OUT / 4);
            int wf  = idx % (OUT / 4);
            float4 v = *reinterpret_cast<const float4*>(
                W + (size_t)(k0 + wk) * OUT + wf * 4);
            *reinterpret_cast<float4*>(&Ws[wk][wf * 4]) = v;
        }
        __syncthreads();
#pragma unroll
        for (int k = 0; k < BK; ++k) {
            float4 a = *reinterpret_cast<const float4*>(&At[k][ry * 4]);
            float4 w = *reinterpret_cast<const float4*>(&Ws[k][cx * 4]);
            acc[0][0] = fmaf(a.x, w.x, acc[0][0]);
            acc[0][1] = fmaf(a.x, w.y, acc[0][1]);
            acc[0][2] = fmaf(a.x, w.z, acc[0][2]);
            acc[0][3] = fmaf(a.x, w.w, acc[0][3]);
            acc[1][0] = fmaf(a.y, w.x, acc[1][0]);
            acc[1][1] = fmaf(a.y, w.y, acc[1][1]);
            acc[1][2] = fmaf(a.y, w.z, acc[1][2]);
            acc[1][3] = fmaf(a.y, w.w, acc[1][3]);
            acc[2][0] = fmaf(a.z, w.x, acc[2][0]);
            acc[2][1] = fmaf(a.z, w.y, acc[2][1]);
            acc[2][2] = fmaf(a.z, w.z, acc[2][2]);
            acc[2][3] = fmaf(a.z, w.w, acc[2][3]);
            acc[3][0] = fmaf(a.w, w.x, acc[3][0]);
            acc[3][1] = fmaf(a.w, w.y, acc[3][1]);
            acc[3][2] = fmaf(a.w, w.z, acc[3][2]);
            acc[3][3] = fmaf(a.w, w.w, acc[3][3]);
        }
        __syncthreads();
    }
#pragma unroll
    for (int i = 0; i < 4; ++i) {
        int gr = row0 + ry * 4 + i;
        if (gr < n) {
            float di = dinv[gr];
            float4 v = make_float4(acc[i][0] * di, acc[i][1] * di,
                                   acc[i][2] * di, acc[i][3] * di);
            *reinterpret_cast<float4*>(T + (size_t)gr * OUT + cx * 4) = v;
        }
    }
}

template <int K, int OUT>
__global__ __launch_bounds__(256) void gemm_tile_k(const float* __restrict__ H,
                                                   const float* __restrict__ W,
                                                   const float* __restrict__ dinv,
                                                   float* __restrict__ T, int n) {
    gemm_body<K, OUT>(H, W, dinv, T, n, blockIdx.x);
}

// Fused layer-1 GEMM + CSR fill (independent work, interleaved blocks).
__global__ __launch_bounds__(256) void gemm1_fill_k(
    const float* __restrict__ x, const float* __restrict__ W1,
    const float* __restrict__ dinv, float* __restrict__ T,
    const int* __restrict__ ei, const int* __restrict__ rowptr,
    const int* __restrict__ rank, int* __restrict__ col,
    int n, int E, int G, int F) {
    const int bx = blockIdx.x;
    const int M  = (G < F) ? G : F;
    bool is_gemm;
    int idx;
    if (bx < 2 * M) { is_gemm = (bx & 1) == 0; idx = bx >> 1; }
    else            { idx = M + (bx - 2 * M); is_gemm = (G > F); }
    if (is_gemm) gemm_body<128, 64>(x, W1, dinv, T, n, idx);
    else         fill_body(ei, rowptr, rank, col, E, idx);
}

// One wave per node; bulk-load 64 cols coalesced, shfl-broadcast, 8-deep
// independent row loads.  T rows pre-scaled by dinv; weight = implicit 1.
// Epilogue: *dinv[i] + bias, relu; optionally fused 32->3 head.
template <int WIDTH, bool FUSE_HEAD>
__global__ __launch_bounds__(256) void agg_k(const float* __restrict__ T,
                                             const int* __restrict__ rowptr,
                                             const int* __restrict__ counts,
                                             const int* __restrict__ col,
                                             const float* __restrict__ dinv,
                                             const float* __restrict__ bias,
                                             float* __restrict__ O, int n,
                                             const float* __restrict__ Wh,
                                             const float* __restrict__ bh) {
    constexpr int NSUB = 64 / WIDTH;  // 1 (64-wide) or 2 (32-wide)
    constexpr int U    = 8;
    const int lane = threadIdx.x & 63;
    const int ch   = lane % WIDTH;
    const int sub  = lane / WIDTH;
    const int i = (blockIdx.x * blockDim.x + threadIdx.x) >> 6;
    if (i >= n) return;

    const int start = rowptr[i];
    const int cnt   = counts[i];
    const float* __restrict__ Tc = T + ch;

    float acc = 0.f;
    for (int base = 0; base < cnt; base += 64) {
        const int m = min(64, cnt - base);
        int c_l = (lane < m) ? col[start + base + lane] : 0;
        int jg = 0;
        for (; jg + U * NSUB <= m; jg += U * NSUB) {
            int c[U]; float v[U];
#pragma unroll
            for (int u = 0; u < U; ++u)
                c[u] = __shfl(c_l, jg + u * NSUB + sub, 64);
#pragma unroll
            for (int u = 0; u < U; ++u) v[u] = Tc[(size_t)c[u] * WIDTH];
#pragma unroll
            for (int u = 0; u < U; ++u) acc += v[u];
        }
        for (; jg < m; jg += NSUB) {
            int j  = jg + sub;
            int jc = j < m ? j : jg;
            int cc = __shfl(c_l, jc, 64);
            float v = Tc[(size_t)cc * WIDTH];
            if (j < m) acc += v;
        }
    }
    if (sub == 0) acc += Tc[(size_t)i * WIDTH];  // self loop (T' = dinv*h)
    if constexpr (NSUB == 2) acc += __shfl_xor(acc, 32, 64);
    // after xor-combine, ALL lanes hold the full sum for their channel
    float h = fmaxf(fmaf(dinv[i], acc, bias[ch]), 0.f);
    if constexpr (!FUSE_HEAD) {
        if (sub == 0) O[(size_t)i * WIDTH + ch] = h;
    } else {
        // WIDTH==32: out[i] = h(32) @ Wh(32x3) + bh; reduce lanes 0..31
        float p0 = h * Wh[ch * 3 + 0];
        float p1 = h * Wh[ch * 3 + 1];
        float p2 = h * Wh[ch * 3 + 2];
#pragma unroll
        for (int off = 1; off < 32; off <<= 1) {
            p0 += __shfl_xor(p0, off, 64);
            p1 += __shfl_xor(p1, off, 64);
            p2 += __shfl_xor(p2, off, 64);
        }
        if (lane == 0) {
            O[(size_t)i * 3 + 0] = p0 + bh[0];
            O[(size_t)i * 3 + 1] = p1 + bh[1];
            O[(size_t)i * 3 + 2] = p2 + bh[2];
        }
    }
}

extern "C" void kernel_launch(void* const* d_in, const int* in_sizes, int n_in,
                              void* d_out, int out_size, void* d_ws, size_t ws_size,
                              hipStream_t stream) {
    const float* x  = (const float*)d_in[0];
    const int*   ei = (const int*)d_in[1];
    const float* W1 = (const float*)d_in[2];
    const float* b1 = (const float*)d_in[3];
    const float* W2 = (const float*)d_in[4];
    const float* b2 = (const float*)d_in[5];
    const float* W3 = (const float*)d_in[6];
    const float* b3 = (const float*)d_in[7];
    const float* W4 = (const float*)d_in[8];
    const float* b4 = (const float*)d_in[9];
    const float* Wh = (const float*)d_in[10];
    const float* bh = (const float*)d_in[11];
    float* out = (float*)d_out;

    const int n = in_sizes[0] / 128;
    const int E = in_sizes[1] / 2;
    const int nb = (n + 1023) / 1024;

    char* ws = (char*)d_ws;
    auto alloc = [&](size_t bytes) {
        char* p = ws;
        ws += (bytes + 255) & ~(size_t)255;
        return p;
    };
    int*   counts = (int*)alloc((size_t)n * 4);
    int*   part   = (int*)alloc((size_t)n * 4);
    int*   rowptr = (int*)alloc((size_t)n * 4);
    float* dinv   = (float*)alloc((size_t)n * 4);
    int*   boffs  = (int*)alloc((size_t)nb * 4);
    int*   rank   = (int*)alloc((size_t)E * 4);
    int*   col    = (int*)alloc((size_t)E * 4);
    float* bufA   = (float*)alloc((size_t)n * 64 * 4);
    float* bufB   = (float*)alloc((size_t)n * 64 * 4);

    const int TB = 256;
    dim3 blk(TB);

    // ---- CSR build prep ----
    init_k<<<dim3((n + TB - 1) / TB), blk, 0, stream>>>(counts, n);
    count_k<<<dim3((E + TB - 1) / TB), blk, 0, stream>>>(ei, counts, rank, E);
    scan1_k<<<dim3(nb), dim3(1024), 0, stream>>>(counts, part, boffs, dinv, n);
    scan2_k<<<dim3(1), dim3(1024), 0, stream>>>(boffs, nb);
    finalize_k<<<dim3((n + TB - 1) / TB), blk, 0, stream>>>(part, boffs, rowptr, n);

    const int agg_blocks = (n + 3) / 4;
    const int G = (n + 63) / 64;            // gemm1 blocks (BM=64)
    const int F = (E + 1023) / 1024;        // fill blocks (4 edges/thread)

    // ---- Layer 1 transform + CSR fill, fused ----
    gemm1_fill_k<<<dim3(G + F), blk, 0, stream>>>(x, W1, dinv, bufA, ei, rowptr,
                                                  rank, col, n, E, G, F);
    agg_k<64, false><<<dim3(agg_blocks), blk, 0, stream>>>(
        bufA, rowptr, counts, col, dinv, b1, bufB, n, nullptr, nullptr);
    // ---- Layer 2 ----
    gemm_tile_k<64, 64><<<dim3((n + 63) / 64), blk, 0, stream>>>(bufB, W2, dinv, bufA, n);
    agg_k<64, false><<<dim3(agg_blocks), blk, 0, stream>>>(
        bufA, rowptr, counts, col, dinv, b2, bufB, n, nullptr, nullptr);
    // ---- Layer 3 ----
    gemm_tile_k<64, 64><<<dim3((n + 63) / 64), blk, 0, stream>>>(bufB, W3, dinv, bufA, n);
    agg_k<64, false><<<dim3(agg_blocks), blk, 0, stream>>>(
        bufA, rowptr, counts, col, dinv, b3, bufB, n, nullptr, nullptr);
    // ---- Layer 4 (+ fused head) ----
    gemm_tile_k<64, 32><<<dim3((n + 127) / 128), blk, 0, stream>>>(bufB, W4, dinv, bufA, n);
    agg_k<32, true><<<dim3(agg_blocks), blk, 0, stream>>>(
        bufA, rowptr, counts, col, dinv, b4, out, n, Wh, bh);
}

// Round 5
// 493.075 us; speedup vs baseline: 2.4586x; 1.0565x over previous
//
#include <hip/hip_runtime.h>
#include <hip/hip_bf16.h>
#include <hip/hip_fp16.h>
#include <cstdint>

// ---------------------------------------------------------------------------
// SPDE GCN: 4x GCNConv + linear head, all fp32 in/out.
// R2: LDS-tiled fp32 GEMM.  R3: MLP agg.  R4: rank-based CSR fill (no atomic
//     in fill), wgt eliminated via dinv pre/post-scaling, gemm1+fill fused,
//     head fused into agg4.
// R5: count_k was atomic-throughput bound (1.6M atomic-with-return at
//     ~24/ns, VALUBusy 0.5%, 67us serial).  Changes:
//       (a) count fused with layer-1 GEMM (raw, unscaled -> dinv not needed).
//       (b) feature table T' stored fp16 (row 128B, table 12.8MB): halves
//           L2-miss bytes for the agg gather.  fp32 accumulate.
//       (c) scale+fp16-convert of layer-1 T fused with CSR fill.
//       (d) layers 2-4 GEMM epilogues write scaled fp16 directly.
// ---------------------------------------------------------------------------

__global__ __launch_bounds__(256) void init_k(int* __restrict__ counts, int n) {
    int i = blockIdx.x * blockDim.x + threadIdx.x;
    if (i < n) counts[i] = 0;
}

// Inclusive LDS scan of 1024 per block -> exclusive prefix + block total;
// dinv = rsqrt(deg+1) fused.
__global__ __launch_bounds__(1024) void scan1_k(const int* __restrict__ counts,
                                                int* __restrict__ part,
                                                int* __restrict__ bsums,
                                                float* __restrict__ dinv, int n) {
    __shared__ int s[1024];
    int t = threadIdx.x;
    int g = blockIdx.x * 1024 + t;
    int v = (g < n) ? counts[g] : 0;
    if (g < n) dinv[g] = rsqrtf((float)(v + 1));
    s[t] = v;
    __syncthreads();
    for (int off = 1; off < 1024; off <<= 1) {
        int x = (t >= off) ? s[t - off] : 0;
        __syncthreads();
        s[t] += x;
        __syncthreads();
    }
    if (g < n) part[g] = s[t] - v;
    if (t == 1023) bsums[blockIdx.x] = s[1023];
}

__global__ __launch_bounds__(1024) void scan2_k(int* __restrict__ bsums, int nb) {
    __shared__ int s[1024];
    int t = threadIdx.x;
    int v = (t < nb) ? bsums[t] : 0;
    s[t] = v;
    __syncthreads();
    for (int off = 1; off < 1024; off <<= 1) {
        int x = (t >= off) ? s[t - off] : 0;
        __syncthreads();
        s[t] += x;
        __syncthreads();
    }
    if (t < nb) bsums[t] = s[t] - v;
}

__global__ __launch_bounds__(256) void finalize_k(const int* __restrict__ part,
                                                  const int* __restrict__ boffs,
                                                  int* __restrict__ rowptr, int n) {
    int i = blockIdx.x * blockDim.x + threadIdx.x;
    if (i < n) rowptr[i] = part[i] + boffs[i >> 10];
}

// ---- count body: 4 edges/thread; histogram + arrival rank ----------------
__device__ __forceinline__ void count_body(const int* __restrict__ ei,
                                           int* __restrict__ counts,
                                           int* __restrict__ rank, int E, int cb) {
    const int t0 = cb * 1024 + threadIdx.x;
    int d[4];
    bool ok[4];
#pragma unroll
    for (int k = 0; k < 4; ++k) {
        int e = t0 + k * 256;
        ok[k] = e < E;
        d[k] = ok[k] ? ei[E + e] : 0;
    }
#pragma unroll
    for (int k = 0; k < 4; ++k)
        if (ok[k]) rank[t0 + k * 256] = atomicAdd(&counts[d[k]], 1);
}

// ---- fill body: 4 edges/thread, no atomics -------------------------------
__device__ __forceinline__ void fill_body(const int* __restrict__ ei,
                                          const int* __restrict__ rowptr,
                                          const int* __restrict__ rank,
                                          int* __restrict__ col, int E, int fb) {
    const int t0 = fb * 1024 + threadIdx.x;
    int s[4], d[4], r[4];
#pragma unroll
    for (int k = 0; k < 4; ++k) {
        int e = t0 + k * 256;
        if (e < E) { s[k] = ei[e]; d[k] = ei[E + e]; r[k] = rank[e]; }
        else s[k] = -1;
    }
    int b[4];
#pragma unroll
    for (int k = 0; k < 4; ++k)
        if (s[k] >= 0) b[k] = rowptr[d[k]];
#pragma unroll
    for (int k = 0; k < 4; ++k)
        if (s[k] >= 0) col[b[k] + r[k]] = s[k];
}

// ---- scale body: Th = fp16(dinv[row] * Traw), 16 elems/thread ------------
__device__ __forceinline__ void scale_body(const float* __restrict__ Traw,
                                           const float* __restrict__ dinv,
                                           __half* __restrict__ Th,
                                           int M4, int sb) {
#pragma unroll
    for (int p = 0; p < 4; ++p) {
        int i4 = sb * 1024 + p * 256 + threadIdx.x;
        if (i4 < M4) {
            float4 v = reinterpret_cast<const float4*>(Traw)[i4];
            float di = dinv[i4 >> 4];  // 16 float4 per 64-ch row
            union { ushort4 u; __half h[4]; } pk;
            pk.h[0] = __float2half_rn(v.x * di);
            pk.h[1] = __float2half_rn(v.y * di);
            pk.h[2] = __float2half_rn(v.z * di);
            pk.h[3] = __float2half_rn(v.w * di);
            reinterpret_cast<ushort4*>(Th)[i4] = pk.u;
        }
    }
}

// ---- GEMM body: T = H @ W; HALF_OUT scales rows by dinv and emits fp16 ----
template <int K, int OUT, bool HALF_OUT>
__device__ __forceinline__ void gemm_body(const float* __restrict__ H,
                                          const float* __restrict__ W,
                                          const float* __restrict__ dinv,
                                          void* __restrict__ Tout, int n, int bx) {
    constexpr int TX  = OUT / 4;
    constexpr int TY  = 256 / TX;
    constexpr int BM  = TY * 4;
    constexpr int BK  = 32;
    constexpr int PAD = 4;

    __shared__ float At[BK][BM + PAD];
    __shared__ float Ws[BK][OUT];

    const int t    = threadIdx.x;
    const int cx   = t % TX;
    const int ry   = t / TX;
    const int row0 = bx * BM;

    float acc[4][4] = {{0.f}};
    const int arow = t >> 3;
    const int af4  = t & 7;

    for (int k0 = 0; k0 < K; k0 += BK) {
#pragma unroll
        for (int p = 0; p < BM / 32; ++p) {
            int r  = arow + p * 32;
            int gr = row0 + r;
            int grc = gr < n ? gr : n - 1;
            float4 v = *reinterpret_cast<const float4*>(
                H + (size_t)grc * K + k0 + af4 * 4);
            At[af4 * 4 + 0][r] = v.x;
            At[af4 * 4 + 1][r] = v.y;
            At[af4 * 4 + 2][r] = v.z;
            At[af4 * 4 + 3][r] = v.w;
        }
#pragma unroll
        for (int p = 0; p < (BK * OUT) / 1024; ++p) {
            int idx = t + p * 256;
            int wk  = idx / (OUT / 4);
            int wf  = idx % (OUT / 4);
            float4 v = *reinterpret_cast<const float4*>(
                W + (size_t)(k0 + wk) * OUT + wf * 4);
            *reinterpret_cast<float4*>(&Ws[wk][wf * 4]) = v;
        }
        __syncthreads();
#pragma unroll
        for (int k = 0; k < BK; ++k) {
            float4 a = *reinterpret_cast<const float4*>(&At[k][ry * 4]);
            float4 w = *reinterpret_cast<const float4*>(&Ws[k][cx * 4]);
            acc[0][0] = fmaf(a.x, w.x, acc[0][0]);
            acc[0][1] = fmaf(a.x, w.y, acc[0][1]);
            acc[0][2] = fmaf(a.x, w.z, acc[0][2]);
            acc[0][3] = fmaf(a.x, w.w, acc[0][3]);
            acc[1][0] = fmaf(a.y, w.x, acc[1][0]);
            acc[1][1] = fmaf(a.y, w.y, acc[1][1]);
            acc[1][2] = fmaf(a.y, w.z, acc[1][2]);
            acc[1][3] = fmaf(a.y, w.w, acc[1][3]);
            acc[2][0] = fmaf(a.z, w.x, acc[2][0]);
            acc[2][1] = fmaf(a.z, w.y, acc[2][1]);
            acc[2][2] = fmaf(a.z, w.z, acc[2][2]);
            acc[2][3] = fmaf(a.z, w.w, acc[2][3]);
            acc[3][0] = fmaf(a.w, w.x, acc[3][0]);
            acc[3][1] = fmaf(a.w, w.y, acc[3][1]);
            acc[3][2] = fmaf(a.w, w.z, acc[3][2]);
            acc[3][3] = fmaf(a.w, w.w, acc[3][3]);
        }
        __syncthreads();
    }
#pragma unroll
    for (int i = 0; i < 4; ++i) {
        int gr = row0 + ry * 4 + i;
        if (gr < n) {
            if constexpr (HALF_OUT) {
                float di = dinv[gr];
                union { ushort4 u; __half h[4]; } pk;
                pk.h[0] = __float2half_rn(acc[i][0] * di);
                pk.h[1] = __float2half_rn(acc[i][1] * di);
                pk.h[2] = __float2half_rn(acc[i][2] * di);
                pk.h[3] = __float2half_rn(acc[i][3] * di);
                *reinterpret_cast<ushort4*>(
                    (__half*)Tout + (size_t)gr * OUT + cx * 4) = pk.u;
            } else {
                float4 v = make_float4(acc[i][0], acc[i][1], acc[i][2], acc[i][3]);
                *reinterpret_cast<float4*>(
                    (float*)Tout + (size_t)gr * OUT + cx * 4) = v;
            }
        }
    }
}

// Fused: layer-1 raw GEMM (x@W1 -> fp32) + degree count/rank (independent).
__global__ __launch_bounds__(256) void gemm1_count_k(
    const float* __restrict__ x, const float* __restrict__ W1,
    float* __restrict__ T1, const int* __restrict__ ei,
    int* __restrict__ counts, int* __restrict__ rank,
    int n, int E, int G, int C) {
    const int bx = blockIdx.x;
    const int M  = (G < C) ? G : C;
    bool is_gemm;
    int idx;
    if (bx < 2 * M) { is_gemm = (bx & 1) == 0; idx = bx >> 1; }
    else            { idx = M + (bx - 2 * M); is_gemm = (G > C); }
    if (is_gemm) gemm_body<128, 64, false>(x, W1, nullptr, T1, n, idx);
    else         count_body(ei, counts, rank, E, idx);
}

// Fused: CSR fill + scale/fp16-convert of layer-1 T (both post-scan).
__global__ __launch_bounds__(256) void fill_scale_k(
    const int* __restrict__ ei, const int* __restrict__ rowptr,
    const int* __restrict__ rank, int* __restrict__ col,
    const float* __restrict__ Traw, const float* __restrict__ dinv,
    __half* __restrict__ Th, int E, int M4, int F, int S) {
    const int bx = blockIdx.x;
    const int M  = (F < S) ? F : S;
    bool is_fill;
    int idx;
    if (bx < 2 * M) { is_fill = (bx & 1) == 0; idx = bx >> 1; }
    else            { idx = M + (bx - 2 * M); is_fill = (F > S); }
    if (is_fill) fill_body(ei, rowptr, rank, col, E, idx);
    else         scale_body(Traw, dinv, Th, M4, idx);
}

template <int K, int OUT>
__global__ __launch_bounds__(256) void gemm_h_k(const float* __restrict__ H,
                                                const float* __restrict__ W,
                                                const float* __restrict__ dinv,
                                                __half* __restrict__ T, int n) {
    gemm_body<K, OUT, true>(H, W, dinv, T, n, blockIdx.x);
}

// One wave per node; bulk-load 64 cols coalesced, shfl-broadcast, 8-deep
// independent fp16 row-element loads.  T' rows pre-scaled by dinv.
// Epilogue: *dinv[i] + bias, relu; optionally fused 32->3 head.
template <int WIDTH, bool FUSE_HEAD>
__global__ __launch_bounds__(256) void agg_k(const __half* __restrict__ T,
                                             const int* __restrict__ rowptr,
                                             const int* __restrict__ counts,
                                             const int* __restrict__ col,
                                             const float* __restrict__ dinv,
                                             const float* __restrict__ bias,
                                             float* __restrict__ O, int n,
                                             const float* __restrict__ Wh,
                                             const float* __restrict__ bh) {
    constexpr int NSUB = 64 / WIDTH;
    constexpr int U    = 8;
    const int lane = threadIdx.x & 63;
    const int ch   = lane % WIDTH;
    const int sub  = lane / WIDTH;
    const int i = (blockIdx.x * blockDim.x + threadIdx.x) >> 6;
    if (i >= n) return;

    const int start = rowptr[i];
    const int cnt   = counts[i];
    const __half* __restrict__ Tc = T + ch;

    float acc = 0.f;
    for (int base = 0; base < cnt; base += 64) {
        const int m = min(64, cnt - base);
        int c_l = (lane < m) ? col[start + base + lane] : 0;
        int jg = 0;
        for (; jg + U * NSUB <= m; jg += U * NSUB) {
            int c[U]; __half v[U];
#pragma unroll
            for (int u = 0; u < U; ++u)
                c[u] = __shfl(c_l, jg + u * NSUB + sub, 64);
#pragma unroll
            for (int u = 0; u < U; ++u) v[u] = Tc[(size_t)c[u] * WIDTH];
#pragma unroll
            for (int u = 0; u < U; ++u) acc += __half2float(v[u]);
        }
        for (; jg < m; jg += NSUB) {
            int j  = jg + sub;
            int jc = j < m ? j : jg;
            int cc = __shfl(c_l, jc, 64);
            float v = __half2float(Tc[(size_t)cc * WIDTH]);
            if (j < m) acc += v;
        }
    }
    if (sub == 0) acc += __half2float(Tc[(size_t)i * WIDTH]);  // self loop
    if constexpr (NSUB == 2) acc += __shfl_xor(acc, 32, 64);
    float h = fmaxf(fmaf(dinv[i], acc, bias[ch]), 0.f);
    if constexpr (!FUSE_HEAD) {
        if (sub == 0) O[(size_t)i * WIDTH + ch] = h;
    } else {
        float p0 = h * Wh[ch * 3 + 0];
        float p1 = h * Wh[ch * 3 + 1];
        float p2 = h * Wh[ch * 3 + 2];
#pragma unroll
        for (int off = 1; off < 32; off <<= 1) {
            p0 += __shfl_xor(p0, off, 64);
            p1 += __shfl_xor(p1, off, 64);
            p2 += __shfl_xor(p2, off, 64);
        }
        if (lane == 0) {
            O[(size_t)i * 3 + 0] = p0 + bh[0];
            O[(size_t)i * 3 + 1] = p1 + bh[1];
            O[(size_t)i * 3 + 2] = p2 + bh[2];
        }
    }
}

extern "C" void kernel_launch(void* const* d_in, const int* in_sizes, int n_in,
                              void* d_out, int out_size, void* d_ws, size_t ws_size,
                              hipStream_t stream) {
    const float* x  = (const float*)d_in[0];
    const int*   ei = (const int*)d_in[1];
    const float* W1 = (const float*)d_in[2];
    const float* b1 = (const float*)d_in[3];
    const float* W2 = (const float*)d_in[4];
    const float* b2 = (const float*)d_in[5];
    const float* W3 = (const float*)d_in[6];
    const float* b3 = (const float*)d_in[7];
    const float* W4 = (const float*)d_in[8];
    const float* b4 = (const float*)d_in[9];
    const float* Wh = (const float*)d_in[10];
    const float* bh = (const float*)d_in[11];
    float* out = (float*)d_out;

    const int n = in_sizes[0] / 128;
    const int E = in_sizes[1] / 2;
    const int nb = (n + 1023) / 1024;

    char* ws = (char*)d_ws;
    auto alloc = [&](size_t bytes) {
        char* p = ws;
        ws += (bytes + 255) & ~(size_t)255;
        return p;
    };
    int*    counts = (int*)alloc((size_t)n * 4);
    int*    part   = (int*)alloc((size_t)n * 4);
    int*    rowptr = (int*)alloc((size_t)n * 4);
    float*  dinv   = (float*)alloc((size_t)n * 4);
    int*    boffs  = (int*)alloc((size_t)nb * 4);
    int*    rank   = (int*)alloc((size_t)E * 4);
    int*    col    = (int*)alloc((size_t)E * 4);
    float*  bufF   = (float*)alloc((size_t)n * 64 * 4);   // fp32 agg outputs / raw T1
    __half* bufH   = (__half*)alloc((size_t)n * 64 * 2);  // fp16 feature table

    const int TB = 256;
    dim3 blk(TB);

    const int G  = (n + 63) / 64;       // gemm blocks (BM=64)
    const int C  = (E + 1023) / 1024;   // count blocks (4 edges/thread)
    const int F  = C;                   // fill blocks
    const int M4 = n * 16;              // float4 count of 64-ch table
    const int S  = (M4 + 1023) / 1024;  // scale blocks (16 elems/thread)
    const int agg_blocks = (n + 3) / 4;

    // ---- CSR prep + layer-1 raw transform (fused) ----
    init_k<<<dim3((n + TB - 1) / TB), blk, 0, stream>>>(counts, n);
    gemm1_count_k<<<dim3(G + C), blk, 0, stream>>>(x, W1, bufF, ei, counts, rank,
                                                   n, E, G, C);
    scan1_k<<<dim3(nb), dim3(1024), 0, stream>>>(counts, part, boffs, dinv, n);
    scan2_k<<<dim3(1), dim3(1024), 0, stream>>>(boffs, nb);
    finalize_k<<<dim3((n + TB - 1) / TB), blk, 0, stream>>>(part, boffs, rowptr, n);
    // ---- CSR fill + layer-1 scale/convert (fused) ----
    fill_scale_k<<<dim3(F + S), blk, 0, stream>>>(ei, rowptr, rank, col,
                                                  bufF, dinv, bufH, E, M4, F, S);
    // ---- Layer 1 agg ----
    agg_k<64, false><<<dim3(agg_blocks), blk, 0, stream>>>(
        bufH, rowptr, counts, col, dinv, b1, bufF, n, nullptr, nullptr);
    // ---- Layer 2 ----
    gemm_h_k<64, 64><<<dim3(G), blk, 0, stream>>>(bufF, W2, dinv, bufH, n);
    agg_k<64, false><<<dim3(agg_blocks), blk, 0, stream>>>(
        bufH, rowptr, counts, col, dinv, b2, bufF, n, nullptr, nullptr);
    // ---- Layer 3 ----
    gemm_h_k<64, 64><<<dim3(G), blk, 0, stream>>>(bufF, W3, dinv, bufH, n);
    agg_k<64, false><<<dim3(agg_blocks), blk, 0, stream>>>(
        bufH, rowptr, counts, col, dinv, b3, bufF, n, nullptr, nullptr);
    // ---- Layer 4 (+ fused head) ----
    gemm_h_k<64, 32><<<dim3((n + 127) / 128), blk, 0, stream>>>(bufF, W4, dinv, bufH, n);
    agg_k<32, true><<<dim3(agg_blocks), blk, 0, stream>>>(
        bufH, rowptr, counts, col, dinv, b4, out, n, Wh, bh);
}

// Round 6
// 440.958 us; speedup vs baseline: 2.7492x; 1.1182x over previous
//
#include <hip/hip_runtime.h>
#include <hip/hip_bf16.h>
#include <hip/hip_fp16.h>
#include <cstdint>

// ---------------------------------------------------------------------------
// SPDE GCN: 4x GCNConv + linear head, fp32 in/out.
// R3: MLP agg.  R4: wgt eliminated (dinv pre/post scaling), head fused.
// R5: fp16 feature table (halved gather bytes).
// R6: CSR build rebuilt as atomic-free MSD bucket sort.  R5 counters: the
//     1.6M global atomicAdd-with-return in count saturated the atomic pipe
//     (~24/ns, 67us serial floor, VALUBusy<1%).  Now:
//       hist(coarse dst>>8, LDS) -> scans -> pack (scatter (src<<8|dlow),
//       fused w/ layer-1 GEMM) -> bucket_k (per-bucket LDS hist of low 8
//       bits: writes deg/dinv/rowptr directly, scatters col, and dinv-scales
//       + fp16-converts layer-1 rows).  Zero global atomics; scan1/scan2/
//       finalize/init kernels deleted.
// ---------------------------------------------------------------------------

#define MAXD 512   // max coarse digits (n <= 131072)
#define EB   8192  // edges per hist/pack block

// ---- A: coarse histogram (block-major matrix histM[b][dg]) ---------------
__global__ __launch_bounds__(256) void hist1_k(const int* __restrict__ ei,
                                               int* __restrict__ histM,
                                               int E, int ND) {
    __shared__ int hist[MAXD];
    const int tid = threadIdx.x, b = blockIdx.x;
    hist[tid] = 0; hist[tid + 256] = 0;
    __syncthreads();
    const int base = b * EB;
#pragma unroll 2
    for (int it = 0; it < EB / 256; it += 4) {
        int d[4]; bool ok[4];
#pragma unroll
        for (int u = 0; u < 4; ++u) {
            int e = base + (it + u) * 256 + tid;
            ok[u] = e < E;
            d[u] = ok[u] ? ei[E + e] : 0;
        }
#pragma unroll
        for (int u = 0; u < 4; ++u)
            if (ok[u]) atomicAdd(&hist[d[u] >> 8], 1);
    }
    __syncthreads();
    histM[(size_t)b * MAXD + tid] = hist[tid];
    histM[(size_t)b * MAXD + tid + 256] = hist[tid + 256];
}

// ---- B1: per-digit exclusive scan over blocks (in place) + digit totals ---
__global__ __launch_bounds__(256) void scan_digits_k(int* __restrict__ histM,
                                                     int* __restrict__ totals,
                                                     int NBLK) {
    __shared__ int s[256];
    const int t = threadIdx.x, dg = blockIdx.x;
    int v = (t < NBLK) ? histM[(size_t)t * MAXD + dg] : 0;
    s[t] = v;
    __syncthreads();
    for (int off = 1; off < 256; off <<= 1) {
        int x = (t >= off) ? s[t - off] : 0;
        __syncthreads();
        s[t] += x;
        __syncthreads();
    }
    if (t < NBLK) histM[(size_t)t * MAXD + dg] = s[t] - v;
    if (t == 255) totals[dg] = s[255];
}

// ---- B2: exclusive scan of digit totals -> coarse bucket bases ------------
__global__ __launch_bounds__(512) void scan_base_k(const int* __restrict__ totals,
                                                   int* __restrict__ cb, int ND) {
    __shared__ int s[512];
    const int t = threadIdx.x;
    int v = (t < ND) ? totals[t] : 0;
    s[t] = v;
    __syncthreads();
    for (int off = 1; off < 512; off <<= 1) {
        int x = (t >= off) ? s[t - off] : 0;
        __syncthreads();
        s[t] += x;
        __syncthreads();
    }
    if (t < ND) cb[t] = s[t] - v;
    if (t == 511) cb[ND] = s[511];  // = E
}

// ---- GEMM body: T = H @ W; HALF_OUT scales rows by dinv, emits fp16 -------
template <int K, int OUT, bool HALF_OUT>
__device__ __forceinline__ void gemm_body(const float* __restrict__ H,
                                          const float* __restrict__ W,
                                          const float* __restrict__ dinv,
                                          void* __restrict__ Tout, int n, int bx) {
    constexpr int TX  = OUT / 4;
    constexpr int TY  = 256 / TX;
    constexpr int BM  = TY * 4;
    constexpr int BK  = 32;
    constexpr int PAD = 4;

    __shared__ float At[BK][BM + PAD];
    __shared__ float Ws[BK][OUT];

    const int t    = threadIdx.x;
    const int cx   = t % TX;
    const int ry   = t / TX;
    const int row0 = bx * BM;

    float acc[4][4] = {{0.f}};
    const int arow = t >> 3;
    const int af4  = t & 7;

    for (int k0 = 0; k0 < K; k0 += BK) {
#pragma unroll
        for (int p = 0; p < BM / 32; ++p) {
            int r  = arow + p * 32;
            int gr = row0 + r;
            int grc = gr < n ? gr : n - 1;
            float4 v = *reinterpret_cast<const float4*>(
                H + (size_t)grc * K + k0 + af4 * 4);
            At[af4 * 4 + 0][r] = v.x;
            At[af4 * 4 + 1][r] = v.y;
            At[af4 * 4 + 2][r] = v.z;
            At[af4 * 4 + 3][r] = v.w;
        }
#pragma unroll
        for (int p = 0; p < (BK * OUT) / 1024; ++p) {
            int idx = t + p * 256;
            int wk  = idx / (OUT / 4);
            int wf  = idx % (OUT / 4);
            float4 v = *reinterpret_cast<const float4*>(
                W + (size_t)(k0 + wk) * OUT + wf * 4);
            *reinterpret_cast<float4*>(&Ws[wk][wf * 4]) = v;
        }
        __syncthreads();
#pragma unroll
        for (int k = 0; k < BK; ++k) {
            float4 a = *reinterpret_cast<const float4*>(&At[k][ry * 4]);
            float4 w = *reinterpret_cast<const float4*>(&Ws[k][cx * 4]);
            acc[0][0] = fmaf(a.x, w.x, acc[0][0]);
            acc[0][1] = fmaf(a.x, w.y, acc[0][1]);
            acc[0][2] = fmaf(a.x, w.z, acc[0][2]);
            acc[0][3] = fmaf(a.x, w.w, acc[0][3]);
            acc[1][0] = fmaf(a.y, w.x, acc[1][0]);
            acc[1][1] = fmaf(a.y, w.y, acc[1][1]);
            acc[1][2] = fmaf(a.y, w.z, acc[1][2]);
            acc[1][3] = fmaf(a.y, w.w, acc[1][3]);
            acc[2][0] = fmaf(a.z, w.x, acc[2][0]);
            acc[2][1] = fmaf(a.z, w.y, acc[2][1]);
            acc[2][2] = fmaf(a.z, w.z, acc[2][2]);
            acc[2][3] = fmaf(a.z, w.w, acc[2][3]);
            acc[3][0] = fmaf(a.w, w.x, acc[3][0]);
            acc[3][1] = fmaf(a.w, w.y, acc[3][1]);
            acc[3][2] = fmaf(a.w, w.z, acc[3][2]);
            acc[3][3] = fmaf(a.w, w.w, acc[3][3]);
        }
        __syncthreads();
    }
#pragma unroll
    for (int i = 0; i < 4; ++i) {
        int gr = row0 + ry * 4 + i;
        if (gr < n) {
            if constexpr (HALF_OUT) {
                float di = dinv[gr];
                union { ushort4 u; __half h[4]; } pk;
                pk.h[0] = __float2half_rn(acc[i][0] * di);
                pk.h[1] = __float2half_rn(acc[i][1] * di);
                pk.h[2] = __float2half_rn(acc[i][2] * di);
                pk.h[3] = __float2half_rn(acc[i][3] * di);
                *reinterpret_cast<ushort4*>(
                    (__half*)Tout + (size_t)gr * OUT + cx * 4) = pk.u;
            } else {
                float4 v = make_float4(acc[i][0], acc[i][1], acc[i][2], acc[i][3]);
                *reinterpret_cast<float4*>(
                    (float*)Tout + (size_t)gr * OUT + cx * 4) = v;
            }
        }
    }
}

// ---- C: pack scatter (LDS cursors, exact offsets, no global atomics) ------
__device__ __forceinline__ void pack_body(const int* __restrict__ ei,
                                          const int* __restrict__ histM,
                                          const int* __restrict__ cb,
                                          int* __restrict__ packed,
                                          int E, int ND, int b) {
    __shared__ int cur[MAXD];
    const int tid = threadIdx.x;
    for (int t = tid; t < ND; t += 256)
        cur[t] = cb[t] + histM[(size_t)b * MAXD + t];
    __syncthreads();
    const int base = b * EB;
#pragma unroll 2
    for (int it = 0; it < EB / 256; it += 4) {
        int s[4], d[4]; bool ok[4];
#pragma unroll
        for (int u = 0; u < 4; ++u) {
            int e = base + (it + u) * 256 + tid;
            ok[u] = e < E;
            if (ok[u]) { s[u] = ei[e]; d[u] = ei[E + e]; }
        }
#pragma unroll
        for (int u = 0; u < 4; ++u) {
            if (ok[u]) {
                int pos = atomicAdd(&cur[d[u] >> 8], 1);
                packed[pos] = (s[u] << 8) | (d[u] & 255);
            }
        }
    }
}

__global__ __launch_bounds__(256) void pack_gemm1_k(
    const int* __restrict__ ei, const int* __restrict__ histM,
    const int* __restrict__ cb, int* __restrict__ packed,
    const float* __restrict__ x, const float* __restrict__ W1,
    float* __restrict__ T1, int n, int E, int ND, int G, int F) {
    const int bx = blockIdx.x;
    const int M  = (G < F) ? G : F;
    bool is_pack;
    int idx;
    if (bx < 2 * M) { is_pack = (bx & 1) == 0; idx = bx >> 1; }
    else            { idx = M + (bx - 2 * M); is_pack = (F > G); }
    if (is_pack) pack_body(ei, histM, cb, packed, E, ND, idx);
    else         gemm_body<128, 64, false>(x, W1, nullptr, T1, n, idx);
}

// ---- D: per-coarse-bucket finalize: low-8 hist -> deg/dinv/rowptr, col
//      scatter, and fused dinv-scale+fp16 of layer-1 rows ------------------
__global__ __launch_bounds__(256) void bucket_k(const int* __restrict__ packed,
                                                const int* __restrict__ cb,
                                                int* __restrict__ col,
                                                int* __restrict__ rowptr,
                                                int* __restrict__ counts,
                                                float* __restrict__ dinv,
                                                const float* __restrict__ Traw,
                                                __half* __restrict__ Th, int n) {
    __shared__ int   hist[256];
    __shared__ int   pref[256];
    __shared__ int   cur[256];
    __shared__ float dinv_l[256];

    const int tid  = threadIdx.x;
    const int dg   = blockIdx.x;
    const int base = cb[dg];
    const int m    = cb[dg + 1] - base;

    hist[tid] = 0;
    __syncthreads();
    // phase 1: low-8 histogram
    for (int k0 = 0; k0 < m; k0 += 1024) {
        int v[4]; bool ok[4];
#pragma unroll
        for (int u = 0; u < 4; ++u) {
            int k = k0 + u * 256 + tid;
            ok[u] = k < m;
            v[u] = ok[u] ? packed[base + k] : 0;
        }
#pragma unroll
        for (int u = 0; u < 4; ++u)
            if (ok[u]) atomicAdd(&hist[v[u] & 255], 1);
    }
    __syncthreads();
    // phase 2: exclusive scan of 256 bins + per-dst outputs
    int deg = hist[tid];
    pref[tid] = deg;
    __syncthreads();
    for (int off = 1; off < 256; off <<= 1) {
        int x = (tid >= off) ? pref[tid - off] : 0;
        __syncthreads();
        pref[tid] += x;
        __syncthreads();
    }
    int excl = pref[tid] - deg;
    float di = rsqrtf((float)(deg + 1));
    dinv_l[tid] = di;
    cur[tid] = base + excl;
    const int d = dg * 256 + tid;
    if (d < n) {
        counts[d] = deg;
        dinv[d]   = di;
        rowptr[d] = base + excl;
    }
    __syncthreads();
    // phase 3: scatter src into col
    for (int k0 = 0; k0 < m; k0 += 1024) {
        int v[4]; bool ok[4];
#pragma unroll
        for (int u = 0; u < 4; ++u) {
            int k = k0 + u * 256 + tid;
            ok[u] = k < m;
            v[u] = ok[u] ? packed[base + k] : 0;
        }
#pragma unroll
        for (int u = 0; u < 4; ++u) {
            if (ok[u]) {
                int pos = atomicAdd(&cur[v[u] & 255], 1);
                col[pos] = v[u] >> 8;
            }
        }
    }
    // phase 4: scale + fp16-convert this bucket's 256 rows of layer-1 T
    const int r0 = dg * 256;
#pragma unroll 4
    for (int it = 0; it < 16; ++it) {
        int idx = it * 256 + tid;        // float4 index within bucket rows
        int rl  = idx >> 4;
        int r   = r0 + rl;
        if (r < n) {
            float4 v = reinterpret_cast<const float4*>(Traw)[(size_t)r * 16 + (idx & 15)];
            float dd = dinv_l[rl];
            union { ushort4 u; __half h[4]; } pk;
            pk.h[0] = __float2half_rn(v.x * dd);
            pk.h[1] = __float2half_rn(v.y * dd);
            pk.h[2] = __float2half_rn(v.z * dd);
            pk.h[3] = __float2half_rn(v.w * dd);
            reinterpret_cast<ushort4*>(Th)[(size_t)r * 16 + (idx & 15)] = pk.u;
        }
    }
}

template <int K, int OUT>
__global__ __launch_bounds__(256) void gemm_h_k(const float* __restrict__ H,
                                                const float* __restrict__ W,
                                                const float* __restrict__ dinv,
                                                __half* __restrict__ T, int n) {
    gemm_body<K, OUT, true>(H, W, dinv, T, n, blockIdx.x);
}

// One wave per node; bulk-load 64 cols coalesced, shfl-broadcast, 8-deep
// independent fp16 row-element loads.  T' rows pre-scaled by dinv.
template <int WIDTH, bool FUSE_HEAD>
__global__ __launch_bounds__(256) void agg_k(const __half* __restrict__ T,
                                             const int* __restrict__ rowptr,
                                             const int* __restrict__ counts,
                                             const int* __restrict__ col,
                                             const float* __restrict__ dinv,
                                             const float* __restrict__ bias,
                                             float* __restrict__ O, int n,
                                             const float* __restrict__ Wh,
                                             const float* __restrict__ bh) {
    constexpr int NSUB = 64 / WIDTH;
    constexpr int U    = 8;
    const int lane = threadIdx.x & 63;
    const int ch   = lane % WIDTH;
    const int sub  = lane / WIDTH;
    const int i = (blockIdx.x * blockDim.x + threadIdx.x) >> 6;
    if (i >= n) return;

    const int start = rowptr[i];
    const int cnt   = counts[i];
    const __half* __restrict__ Tc = T + ch;

    float acc = 0.f;
    for (int base = 0; base < cnt; base += 64) {
        const int m = min(64, cnt - base);
        int c_l = (lane < m) ? col[start + base + lane] : 0;
        int jg = 0;
        for (; jg + U * NSUB <= m; jg += U * NSUB) {
            int c[U]; __half v[U];
#pragma unroll
            for (int u = 0; u < U; ++u)
                c[u] = __shfl(c_l, jg + u * NSUB + sub, 64);
#pragma unroll
            for (int u = 0; u < U; ++u) v[u] = Tc[(size_t)c[u] * WIDTH];
#pragma unroll
            for (int u = 0; u < U; ++u) acc += __half2float(v[u]);
        }
        for (; jg < m; jg += NSUB) {
            int j  = jg + sub;
            int jc = j < m ? j : jg;
            int cc = __shfl(c_l, jc, 64);
            float v = __half2float(Tc[(size_t)cc * WIDTH]);
            if (j < m) acc += v;
        }
    }
    if (sub == 0) acc += __half2float(Tc[(size_t)i * WIDTH]);  // self loop
    if constexpr (NSUB == 2) acc += __shfl_xor(acc, 32, 64);
    float h = fmaxf(fmaf(dinv[i], acc, bias[ch]), 0.f);
    if constexpr (!FUSE_HEAD) {
        if (sub == 0) O[(size_t)i * WIDTH + ch] = h;
    } else {
        float p0 = h * Wh[ch * 3 + 0];
        float p1 = h * Wh[ch * 3 + 1];
        float p2 = h * Wh[ch * 3 + 2];
#pragma unroll
        for (int off = 1; off < 32; off <<= 1) {
            p0 += __shfl_xor(p0, off, 64);
            p1 += __shfl_xor(p1, off, 64);
            p2 += __shfl_xor(p2, off, 64);
        }
        if (lane == 0) {
            O[(size_t)i * 3 + 0] = p0 + bh[0];
            O[(size_t)i * 3 + 1] = p1 + bh[1];
            O[(size_t)i * 3 + 2] = p2 + bh[2];
        }
    }
}

extern "C" void kernel_launch(void* const* d_in, const int* in_sizes, int n_in,
                              void* d_out, int out_size, void* d_ws, size_t ws_size,
                              hipStream_t stream) {
    const float* x  = (const float*)d_in[0];
    const int*   ei = (const int*)d_in[1];
    const float* W1 = (const float*)d_in[2];
    const float* b1 = (const float*)d_in[3];
    const float* W2 = (const float*)d_in[4];
    const float* b2 = (const float*)d_in[5];
    const float* W3 = (const float*)d_in[6];
    const float* b3 = (const float*)d_in[7];
    const float* W4 = (const float*)d_in[8];
    const float* b4 = (const float*)d_in[9];
    const float* Wh = (const float*)d_in[10];
    const float* bh = (const float*)d_in[11];
    float* out = (float*)d_out;

    const int n = in_sizes[0] / 128;
    const int E = in_sizes[1] / 2;
    const int ND   = (n + 255) / 256;   // coarse digits (<= MAXD)
    const int NBLK = (E + EB - 1) / EB; // hist/pack blocks (<= 256)

    char* ws = (char*)d_ws;
    auto alloc = [&](size_t bytes) {
        char* p = ws;
        ws += (bytes + 255) & ~(size_t)255;
        return p;
    };
    int*    histM  = (int*)alloc((size_t)NBLK * MAXD * 4);
    int*    totals = (int*)alloc((size_t)MAXD * 4);
    int*    cbA    = (int*)alloc((size_t)(MAXD + 1) * 4);
    int*    packed = (int*)alloc((size_t)E * 4);
    int*    col    = (int*)alloc((size_t)E * 4);
    int*    rowptr = (int*)alloc((size_t)n * 4);
    int*    counts = (int*)alloc((size_t)n * 4);
    float*  dinv   = (float*)alloc((size_t)n * 4);
    float*  bufF   = (float*)alloc((size_t)n * 64 * 4);   // fp32 agg out / raw T1
    __half* bufH   = (__half*)alloc((size_t)n * 64 * 2);  // fp16 feature table

    dim3 blk(256);
    const int G = (n + 63) / 64;
    const int agg_blocks = (n + 3) / 4;

    // ---- atomic-free CSR build + layer-1 transform ----
    hist1_k<<<dim3(NBLK), blk, 0, stream>>>(ei, histM, E, ND);
    scan_digits_k<<<dim3(ND), blk, 0, stream>>>(histM, totals, NBLK);
    scan_base_k<<<dim3(1), dim3(512), 0, stream>>>(totals, cbA, ND);
    pack_gemm1_k<<<dim3(NBLK + G), blk, 0, stream>>>(ei, histM, cbA, packed,
                                                     x, W1, bufF, n, E, ND, G, NBLK);
    bucket_k<<<dim3(ND), blk, 0, stream>>>(packed, cbA, col, rowptr, counts,
                                           dinv, bufF, bufH, n);
    // ---- Layer 1 agg ----
    agg_k<64, false><<<dim3(agg_blocks), blk, 0, stream>>>(
        bufH, rowptr, counts, col, dinv, b1, bufF, n, nullptr, nullptr);
    // ---- Layer 2 ----
    gemm_h_k<64, 64><<<dim3(G), blk, 0, stream>>>(bufF, W2, dinv, bufH, n);
    agg_k<64, false><<<dim3(agg_blocks), blk, 0, stream>>>(
        bufH, rowptr, counts, col, dinv, b2, bufF, n, nullptr, nullptr);
    // ---- Layer 3 ----
    gemm_h_k<64, 64><<<dim3(G), blk, 0, stream>>>(bufF, W3, dinv, bufH, n);
    agg_k<64, false><<<dim3(agg_blocks), blk, 0, stream>>>(
        bufH, rowptr, counts, col, dinv, b3, bufF, n, nullptr, nullptr);
    // ---- Layer 4 (+ fused head) ----
    gemm_h_k<64, 32><<<dim3((n + 127) / 128), blk, 0, stream>>>(bufF, W4, dinv, bufH, n);
    agg_k<32, true><<<dim3(agg_blocks), blk, 0, stream>>>(
        bufH, rowptr, counts, col, dinv, b4, out, n, Wh, bh);
}

// Round 7
// 402.045 us; speedup vs baseline: 3.0153x; 1.0968x over previous
//
#include <hip/hip_runtime.h>
#include <hip/hip_bf16.h>
#include <hip/hip_fp16.h>
#include <cstdint>

// ---------------------------------------------------------------------------
// SPDE GCN: 4x GCNConv + linear head, fp32 in/out.
// R3-R5: MLP agg, dinv pre/post scaling (no wgt array), fp16 feature table,
//        head fused into agg4.
// R6: atomic-free MSD bucket-sort CSR build (hist/scan/pack/bucket), pack
//     fused with layer-1 GEMM, bucket writes deg/dinv/rowptr + scales T1.
// R7: agg re-layout.  R6 counters: agg 58us each, VALUBusy 42%, ~1TB/s L2
//     side - instruction-issue + serial-tail bound, not BW.  Each lane now
//     loads uint2 (4 fp16 ch); 4 (W64) / 8 (W32) sub-waves process distinct
//     edges per load instr; 16-edge uniform masked steps (= mean degree, so
//     typically ONE step, gathers fully overlapped, no serial tail); float4
//     acc + shfl_xor cross-sub reduce.  ~4x fewer per-edge instructions.
// ---------------------------------------------------------------------------

#define MAXD 512   // max coarse digits (n <= 131072)
#define EB   8192  // edges per hist/pack block

// ---- A: coarse histogram (block-major matrix histM[b][dg]) ---------------
__global__ __launch_bounds__(256) void hist1_k(const int* __restrict__ ei,
                                               int* __restrict__ histM,
                                               int E, int ND) {
    __shared__ int hist[MAXD];
    const int tid = threadIdx.x, b = blockIdx.x;
    hist[tid] = 0; hist[tid + 256] = 0;
    __syncthreads();
    const int base = b * EB;
#pragma unroll 2
    for (int it = 0; it < EB / 256; it += 4) {
        int d[4]; bool ok[4];
#pragma unroll
        for (int u = 0; u < 4; ++u) {
            int e = base + (it + u) * 256 + tid;
            ok[u] = e < E;
            d[u] = ok[u] ? ei[E + e] : 0;
        }
#pragma unroll
        for (int u = 0; u < 4; ++u)
            if (ok[u]) atomicAdd(&hist[d[u] >> 8], 1);
    }
    __syncthreads();
    histM[(size_t)b * MAXD + tid] = hist[tid];
    histM[(size_t)b * MAXD + tid + 256] = hist[tid + 256];
}

// ---- B1: per-digit exclusive scan over blocks (in place) + digit totals ---
__global__ __launch_bounds__(256) void scan_digits_k(int* __restrict__ histM,
                                                     int* __restrict__ totals,
                                                     int NBLK) {
    __shared__ int s[256];
    const int t = threadIdx.x, dg = blockIdx.x;
    int v = (t < NBLK) ? histM[(size_t)t * MAXD + dg] : 0;
    s[t] = v;
    __syncthreads();
    for (int off = 1; off < 256; off <<= 1) {
        int x = (t >= off) ? s[t - off] : 0;
        __syncthreads();
        s[t] += x;
        __syncthreads();
    }
    if (t < NBLK) histM[(size_t)t * MAXD + dg] = s[t] - v;
    if (t == 255) totals[dg] = s[255];
}

// ---- B2: exclusive scan of digit totals -> coarse bucket bases ------------
__global__ __launch_bounds__(512) void scan_base_k(const int* __restrict__ totals,
                                                   int* __restrict__ cb, int ND) {
    __shared__ int s[512];
    const int t = threadIdx.x;
    int v = (t < ND) ? totals[t] : 0;
    s[t] = v;
    __syncthreads();
    for (int off = 1; off < 512; off <<= 1) {
        int x = (t >= off) ? s[t - off] : 0;
        __syncthreads();
        s[t] += x;
        __syncthreads();
    }
    if (t < ND) cb[t] = s[t] - v;
    if (t == 511) cb[ND] = s[511];  // = E
}

// ---- GEMM body: T = H @ W; HALF_OUT scales rows by dinv, emits fp16 -------
template <int K, int OUT, bool HALF_OUT>
__device__ __forceinline__ void gemm_body(const float* __restrict__ H,
                                          const float* __restrict__ W,
                                          const float* __restrict__ dinv,
                                          void* __restrict__ Tout, int n, int bx) {
    constexpr int TX  = OUT / 4;
    constexpr int TY  = 256 / TX;
    constexpr int BM  = TY * 4;
    constexpr int BK  = 32;
    constexpr int PAD = 4;

    __shared__ float At[BK][BM + PAD];
    __shared__ float Ws[BK][OUT];

    const int t    = threadIdx.x;
    const int cx   = t % TX;
    const int ry   = t / TX;
    const int row0 = bx * BM;

    float acc[4][4] = {{0.f}};
    const int arow = t >> 3;
    const int af4  = t & 7;

    for (int k0 = 0; k0 < K; k0 += BK) {
#pragma unroll
        for (int p = 0; p < BM / 32; ++p) {
            int r  = arow + p * 32;
            int gr = row0 + r;
            int grc = gr < n ? gr : n - 1;
            float4 v = *reinterpret_cast<const float4*>(
                H + (size_t)grc * K + k0 + af4 * 4);
            At[af4 * 4 + 0][r] = v.x;
            At[af4 * 4 + 1][r] = v.y;
            At[af4 * 4 + 2][r] = v.z;
            At[af4 * 4 + 3][r] = v.w;
        }
#pragma unroll
        for (int p = 0; p < (BK * OUT) / 1024; ++p) {
            int idx = t + p * 256;
            int wk  = idx / (OUT / 4);
            int wf  = idx % (OUT / 4);
            float4 v = *reinterpret_cast<const float4*>(
                W + (size_t)(k0 + wk) * OUT + wf * 4);
            *reinterpret_cast<float4*>(&Ws[wk][wf * 4]) = v;
        }
        __syncthreads();
#pragma unroll
        for (int k = 0; k < BK; ++k) {
            float4 a = *reinterpret_cast<const float4*>(&At[k][ry * 4]);
            float4 w = *reinterpret_cast<const float4*>(&Ws[k][cx * 4]);
            acc[0][0] = fmaf(a.x, w.x, acc[0][0]);
            acc[0][1] = fmaf(a.x, w.y, acc[0][1]);
            acc[0][2] = fmaf(a.x, w.z, acc[0][2]);
            acc[0][3] = fmaf(a.x, w.w, acc[0][3]);
            acc[1][0] = fmaf(a.y, w.x, acc[1][0]);
            acc[1][1] = fmaf(a.y, w.y, acc[1][1]);
            acc[1][2] = fmaf(a.y, w.z, acc[1][2]);
            acc[1][3] = fmaf(a.y, w.w, acc[1][3]);
            acc[2][0] = fmaf(a.z, w.x, acc[2][0]);
            acc[2][1] = fmaf(a.z, w.y, acc[2][1]);
            acc[2][2] = fmaf(a.z, w.z, acc[2][2]);
            acc[2][3] = fmaf(a.z, w.w, acc[2][3]);
            acc[3][0] = fmaf(a.w, w.x, acc[3][0]);
            acc[3][1] = fmaf(a.w, w.y, acc[3][1]);
            acc[3][2] = fmaf(a.w, w.z, acc[3][2]);
            acc[3][3] = fmaf(a.w, w.w, acc[3][3]);
        }
        __syncthreads();
    }
#pragma unroll
    for (int i = 0; i < 4; ++i) {
        int gr = row0 + ry * 4 + i;
        if (gr < n) {
            if constexpr (HALF_OUT) {
                float di = dinv[gr];
                union { ushort4 u; __half h[4]; } pk;
                pk.h[0] = __float2half_rn(acc[i][0] * di);
                pk.h[1] = __float2half_rn(acc[i][1] * di);
                pk.h[2] = __float2half_rn(acc[i][2] * di);
                pk.h[3] = __float2half_rn(acc[i][3] * di);
                *reinterpret_cast<ushort4*>(
                    (__half*)Tout + (size_t)gr * OUT + cx * 4) = pk.u;
            } else {
                float4 v = make_float4(acc[i][0], acc[i][1], acc[i][2], acc[i][3]);
                *reinterpret_cast<float4*>(
                    (float*)Tout + (size_t)gr * OUT + cx * 4) = v;
            }
        }
    }
}

// ---- C: pack scatter (LDS cursors, exact offsets, no global atomics) ------
__device__ __forceinline__ void pack_body(const int* __restrict__ ei,
                                          const int* __restrict__ histM,
                                          const int* __restrict__ cb,
                                          int* __restrict__ packed,
                                          int E, int ND, int b) {
    __shared__ int cur[MAXD];
    const int tid = threadIdx.x;
    for (int t = tid; t < ND; t += 256)
        cur[t] = cb[t] + histM[(size_t)b * MAXD + t];
    __syncthreads();
    const int base = b * EB;
#pragma unroll 2
    for (int it = 0; it < EB / 256; it += 4) {
        int s[4], d[4]; bool ok[4];
#pragma unroll
        for (int u = 0; u < 4; ++u) {
            int e = base + (it + u) * 256 + tid;
            ok[u] = e < E;
            if (ok[u]) { s[u] = ei[e]; d[u] = ei[E + e]; }
        }
#pragma unroll
        for (int u = 0; u < 4; ++u) {
            if (ok[u]) {
                int pos = atomicAdd(&cur[d[u] >> 8], 1);
                packed[pos] = (s[u] << 8) | (d[u] & 255);
            }
        }
    }
}

__global__ __launch_bounds__(256) void pack_gemm1_k(
    const int* __restrict__ ei, const int* __restrict__ histM,
    const int* __restrict__ cb, int* __restrict__ packed,
    const float* __restrict__ x, const float* __restrict__ W1,
    float* __restrict__ T1, int n, int E, int ND, int G, int F) {
    const int bx = blockIdx.x;
    const int M  = (G < F) ? G : F;
    bool is_pack;
    int idx;
    if (bx < 2 * M) { is_pack = (bx & 1) == 0; idx = bx >> 1; }
    else            { idx = M + (bx - 2 * M); is_pack = (F > G); }
    if (is_pack) pack_body(ei, histM, cb, packed, E, ND, idx);
    else         gemm_body<128, 64, false>(x, W1, nullptr, T1, n, idx);
}

// ---- D: per-coarse-bucket finalize: low-8 hist -> deg/dinv/rowptr, col
//      scatter, and fused dinv-scale+fp16 of layer-1 rows ------------------
__global__ __launch_bounds__(256) void bucket_k(const int* __restrict__ packed,
                                                const int* __restrict__ cb,
                                                int* __restrict__ col,
                                                int* __restrict__ rowptr,
                                                int* __restrict__ counts,
                                                float* __restrict__ dinv,
                                                const float* __restrict__ Traw,
                                                __half* __restrict__ Th, int n) {
    __shared__ int   hist[256];
    __shared__ int   pref[256];
    __shared__ int   cur[256];
    __shared__ float dinv_l[256];

    const int tid  = threadIdx.x;
    const int dg   = blockIdx.x;
    const int base = cb[dg];
    const int m    = cb[dg + 1] - base;

    hist[tid] = 0;
    __syncthreads();
    // phase 1: low-8 histogram
    for (int k0 = 0; k0 < m; k0 += 1024) {
        int v[4]; bool ok[4];
#pragma unroll
        for (int u = 0; u < 4; ++u) {
            int k = k0 + u * 256 + tid;
            ok[u] = k < m;
            v[u] = ok[u] ? packed[base + k] : 0;
        }
#pragma unroll
        for (int u = 0; u < 4; ++u)
            if (ok[u]) atomicAdd(&hist[v[u] & 255], 1);
    }
    __syncthreads();
    // phase 2: exclusive scan of 256 bins + per-dst outputs
    int deg = hist[tid];
    pref[tid] = deg;
    __syncthreads();
    for (int off = 1; off < 256; off <<= 1) {
        int x = (tid >= off) ? pref[tid - off] : 0;
        __syncthreads();
        pref[tid] += x;
        __syncthreads();
    }
    int excl = pref[tid] - deg;
    float di = rsqrtf((float)(deg + 1));
    dinv_l[tid] = di;
    cur[tid] = base + excl;
    const int d = dg * 256 + tid;
    if (d < n) {
        counts[d] = deg;
        dinv[d]   = di;
        rowptr[d] = base + excl;
    }
    __syncthreads();
    // phase 3: scatter src into col
    for (int k0 = 0; k0 < m; k0 += 1024) {
        int v[4]; bool ok[4];
#pragma unroll
        for (int u = 0; u < 4; ++u) {
            int k = k0 + u * 256 + tid;
            ok[u] = k < m;
            v[u] = ok[u] ? packed[base + k] : 0;
        }
#pragma unroll
        for (int u = 0; u < 4; ++u) {
            if (ok[u]) {
                int pos = atomicAdd(&cur[v[u] & 255], 1);
                col[pos] = v[u] >> 8;
            }
        }
    }
    // phase 4: scale + fp16-convert this bucket's 256 rows of layer-1 T
    const int r0 = dg * 256;
#pragma unroll 4
    for (int it = 0; it < 16; ++it) {
        int idx = it * 256 + tid;        // float4 index within bucket rows
        int rl  = idx >> 4;
        int r   = r0 + rl;
        if (r < n) {
            float4 v = reinterpret_cast<const float4*>(Traw)[(size_t)r * 16 + (idx & 15)];
            float dd = dinv_l[rl];
            union { ushort4 u; __half h[4]; } pk;
            pk.h[0] = __float2half_rn(v.x * dd);
            pk.h[1] = __float2half_rn(v.y * dd);
            pk.h[2] = __float2half_rn(v.z * dd);
            pk.h[3] = __float2half_rn(v.w * dd);
            reinterpret_cast<ushort4*>(Th)[(size_t)r * 16 + (idx & 15)] = pk.u;
        }
    }
}

template <int K, int OUT>
__global__ __launch_bounds__(256) void gemm_h_k(const float* __restrict__ H,
                                                const float* __restrict__ W,
                                                const float* __restrict__ dinv,
                                                __half* __restrict__ T, int n) {
    gemm_body<K, OUT, true>(H, W, dinv, T, n, blockIdx.x);
}

// One wave per node.  Lane loads uint2 (4 fp16 channels); LR = WIDTH/4 lanes
// cover a row, NSW = 64/LR sub-waves process DISTINCT edges per load instr.
// 16-edge uniform masked steps (matches mean degree -> usually one step, all
// gathers overlapped, no serial tail).  float4 fp32 acc; shfl_xor cross-sub
// reduce.  T' rows pre-scaled by dinv; epilogue *dinv[i]+bias, relu.
template <int WIDTH, bool FUSE_HEAD>
__global__ __launch_bounds__(256) void agg_k(const __half* __restrict__ T,
                                             const int* __restrict__ rowptr,
                                             const int* __restrict__ counts,
                                             const int* __restrict__ col,
                                             const float* __restrict__ dinv,
                                             const float* __restrict__ bias,
                                             float* __restrict__ O, int n,
                                             const float* __restrict__ Wh,
                                             const float* __restrict__ bh) {
    constexpr int LR  = WIDTH / 4;   // lanes per row (uint2 granules): 16 / 8
    constexpr int NSW = 64 / LR;     // sub-waves: 4 / 8
    constexpr int U   = 16 / NSW;    // edges in flight per sub-wave: 4 / 2
    const int lane = threadIdx.x & 63;
    const int q    = lane % LR;      // uint2 index within row
    const int sw   = lane / LR;
    const int i = (blockIdx.x * blockDim.x + threadIdx.x) >> 6;
    if (i >= n) return;

    const int start = rowptr[i];
    const int cnt   = counts[i];
    const uint2* __restrict__ T2 = reinterpret_cast<const uint2*>(T);

    float4 acc = make_float4(0.f, 0.f, 0.f, 0.f);
    for (int base = 0; base < cnt; base += 64) {
        const int m = min(64, cnt - base);
        int c_l = (lane < m) ? col[start + base + lane] : 0;
        for (int jg = 0; jg < m; jg += 16) {
            int cc[U]; uint2 v[U]; float wm[U];
#pragma unroll
            for (int u = 0; u < U; ++u) {
                int j  = jg + u * NSW + sw;
                int jc = j < m ? j : 0;
                cc[u] = __shfl(c_l, jc, 64);
                wm[u] = (j < m) ? 1.f : 0.f;
            }
#pragma unroll
            for (int u = 0; u < U; ++u) v[u] = T2[(size_t)cc[u] * LR + q];
#pragma unroll
            for (int u = 0; u < U; ++u) {
                const __half2* h2 = reinterpret_cast<const __half2*>(&v[u]);
                float2 f0 = __half22float2(h2[0]);
                float2 f1 = __half22float2(h2[1]);
                acc.x = fmaf(f0.x, wm[u], acc.x);
                acc.y = fmaf(f0.y, wm[u], acc.y);
                acc.z = fmaf(f1.x, wm[u], acc.z);
                acc.w = fmaf(f1.y, wm[u], acc.w);
            }
        }
    }
    if (sw == 0) {  // self loop (rows pre-scaled by dinv)
        uint2 v = T2[(size_t)i * LR + q];
        const __half2* h2 = reinterpret_cast<const __half2*>(&v);
        float2 f0 = __half22float2(h2[0]);
        float2 f1 = __half22float2(h2[1]);
        acc.x += f0.x; acc.y += f0.y; acc.z += f1.x; acc.w += f1.y;
    }
    // cross-sub-wave reduce: lanes with equal q combine
#pragma unroll
    for (int off = LR; off < 64; off <<= 1) {
        acc.x += __shfl_xor(acc.x, off, 64);
        acc.y += __shfl_xor(acc.y, off, 64);
        acc.z += __shfl_xor(acc.z, off, 64);
        acc.w += __shfl_xor(acc.w, off, 64);
    }
    const float di = dinv[i];
    const float4 b4 = reinterpret_cast<const float4*>(bias)[q];
    float4 h;
    h.x = fmaxf(fmaf(di, acc.x, b4.x), 0.f);
    h.y = fmaxf(fmaf(di, acc.y, b4.y), 0.f);
    h.z = fmaxf(fmaf(di, acc.z, b4.z), 0.f);
    h.w = fmaxf(fmaf(di, acc.w, b4.w), 0.f);
    if constexpr (!FUSE_HEAD) {
        if (sw == 0)
            reinterpret_cast<float4*>(O + (size_t)i * WIDTH)[q] = h;
    } else {
        // WIDTH==32 (LR==8): per-lane 4 channels -> 3 partials; reduce over q
        float p0 = h.x * Wh[(4 * q + 0) * 3 + 0];
        float p1 = h.x * Wh[(4 * q + 0) * 3 + 1];
        float p2 = h.x * Wh[(4 * q + 0) * 3 + 2];
        p0 = fmaf(h.y, Wh[(4 * q + 1) * 3 + 0], p0);
        p1 = fmaf(h.y, Wh[(4 * q + 1) * 3 + 1], p1);
        p2 = fmaf(h.y, Wh[(4 * q + 1) * 3 + 2], p2);
        p0 = fmaf(h.z, Wh[(4 * q + 2) * 3 + 0], p0);
        p1 = fmaf(h.z, Wh[(4 * q + 2) * 3 + 1], p1);
        p2 = fmaf(h.z, Wh[(4 * q + 2) * 3 + 2], p2);
        p0 = fmaf(h.w, Wh[(4 * q + 3) * 3 + 0], p0);
        p1 = fmaf(h.w, Wh[(4 * q + 3) * 3 + 1], p1);
        p2 = fmaf(h.w, Wh[(4 * q + 3) * 3 + 2], p2);
#pragma unroll
        for (int off = 1; off < LR; off <<= 1) {
            p0 += __shfl_xor(p0, off, 64);
            p1 += __shfl_xor(p1, off, 64);
            p2 += __shfl_xor(p2, off, 64);
        }
        if (lane == 0) {
            O[(size_t)i * 3 + 0] = p0 + bh[0];
            O[(size_t)i * 3 + 1] = p1 + bh[1];
            O[(size_t)i * 3 + 2] = p2 + bh[2];
        }
    }
}

extern "C" void kernel_launch(void* const* d_in, const int* in_sizes, int n_in,
                              void* d_out, int out_size, void* d_ws, size_t ws_size,
                              hipStream_t stream) {
    const float* x  = (const float*)d_in[0];
    const int*   ei = (const int*)d_in[1];
    const float* W1 = (const float*)d_in[2];
    const float* b1 = (const float*)d_in[3];
    const float* W2 = (const float*)d_in[4];
    const float* b2 = (const float*)d_in[5];
    const float* W3 = (const float*)d_in[6];
    const float* b3 = (const float*)d_in[7];
    const float* W4 = (const float*)d_in[8];
    const float* b4 = (const float*)d_in[9];
    const float* Wh = (const float*)d_in[10];
    const float* bh = (const float*)d_in[11];
    float* out = (float*)d_out;

    const int n = in_sizes[0] / 128;
    const int E = in_sizes[1] / 2;
    const int ND   = (n + 255) / 256;   // coarse digits (<= MAXD)
    const int NBLK = (E + EB - 1) / EB; // hist/pack blocks (<= 256)

    char* ws = (char*)d_ws;
    auto alloc = [&](size_t bytes) {
        char* p = ws;
        ws += (bytes + 255) & ~(size_t)255;
        return p;
    };
    int*    histM  = (int*)alloc((size_t)NBLK * MAXD * 4);
    int*    totals = (int*)alloc((size_t)MAXD * 4);
    int*    cbA    = (int*)alloc((size_t)(MAXD + 1) * 4);
    int*    packed = (int*)alloc((size_t)E * 4);
    int*    col    = (int*)alloc((size_t)E * 4);
    int*    rowptr = (int*)alloc((size_t)n * 4);
    int*    counts = (int*)alloc((size_t)n * 4);
    float*  dinv   = (float*)alloc((size_t)n * 4);
    float*  bufF   = (float*)alloc((size_t)n * 64 * 4);   // fp32 agg out / raw T1
    __half* bufH   = (__half*)alloc((size_t)n * 64 * 2);  // fp16 feature table

    dim3 blk(256);
    const int G = (n + 63) / 64;
    const int agg_blocks = (n + 3) / 4;

    // ---- atomic-free CSR build + layer-1 transform ----
    hist1_k<<<dim3(NBLK), blk, 0, stream>>>(ei, histM, E, ND);
    scan_digits_k<<<dim3(ND), blk, 0, stream>>>(histM, totals, NBLK);
    scan_base_k<<<dim3(1), dim3(512), 0, stream>>>(totals, cbA, ND);
    pack_gemm1_k<<<dim3(NBLK + G), blk, 0, stream>>>(ei, histM, cbA, packed,
                                                     x, W1, bufF, n, E, ND, G, NBLK);
    bucket_k<<<dim3(ND), blk, 0, stream>>>(packed, cbA, col, rowptr, counts,
                                           dinv, bufF, bufH, n);
    // ---- Layer 1 agg ----
    agg_k<64, false><<<dim3(agg_blocks), blk, 0, stream>>>(
        bufH, rowptr, counts, col, dinv, b1, bufF, n, nullptr, nullptr);
    // ---- Layer 2 ----
    gemm_h_k<64, 64><<<dim3(G), blk, 0, stream>>>(bufF, W2, dinv, bufH, n);
    agg_k<64, false><<<dim3(agg_blocks), blk, 0, stream>>>(
        bufH, rowptr, counts, col, dinv, b2, bufF, n, nullptr, nullptr);
    // ---- Layer 3 ----
    gemm_h_k<64, 64><<<dim3(G), blk, 0, stream>>>(bufF, W3, dinv, bufH, n);
    agg_k<64, false><<<dim3(agg_blocks), blk, 0, stream>>>(
        bufH, rowptr, counts, col, dinv, b3, bufF, n, nullptr, nullptr);
    // ---- Layer 4 (+ fused head) ----
    gemm_h_k<64, 32><<<dim3((n + 127) / 128), blk, 0, stream>>>(bufF, W4, dinv, bufH, n);
    agg_k<32, true><<<dim3(agg_blocks), blk, 0, stream>>>(
        bufH, rowptr, counts, col, dinv, b4, out, n, Wh, bh);
}

// Round 8
// 400.320 us; speedup vs baseline: 3.0283x; 1.0043x over previous
//
#include <hip/hip_runtime.h>
#include <hip/hip_bf16.h>
#include <hip/hip_fp16.h>
#include <cstdint>

// ---------------------------------------------------------------------------
// SPDE GCN: 4x GCNConv + linear head, fp32 in/out.
// R3-R7: MLP agg -> uint2 multi-edge agg; fp16 feature table; dinv pre/post
//        scaling; atomic-free MSD bucket-sort CSR; head fused into agg4.
// R8: (a) padded CSR: each node's list padded to x16, slot0 = self, pads ->
//         zeroed sentinel row n => agg inner loop fully maskless, no tail,
//         no self-loop epilogue (R7: ~60% of agg VALU was fixed overhead).
//     (b) pack blocks cover 4 hist chunks (335B digit chunks, was 84B ->
//         3.4x write amp); exact cursors from scanned histM[4b].
//     (c) hist fused with 1/3 of layer-1 GEMM; pack with the rest.
//     (d) fp16 table rows always stride 64 => single sentinel row.
// ---------------------------------------------------------------------------

#define MAXD 512       // max coarse digits (n <= 131072)
#define EB   8192      // edges per hist chunk
#define CH   4         // hist chunks per pack block
#define PADSLACK 4096  // max per-bucket padding (256 nodes * 16)

// ---- hist body: coarse histogram (block-major histM[b][dg]) ---------------
__device__ __forceinline__ void hist_body(const int* __restrict__ ei,
                                          int* __restrict__ histM, int E, int b) {
    __shared__ int hist[MAXD];
    const int tid = threadIdx.x;
    hist[tid] = 0; hist[tid + 256] = 0;
    __syncthreads();
    const int base = b * EB;
#pragma unroll 2
    for (int it = 0; it < EB / 256; it += 4) {
        int d[4]; bool ok[4];
#pragma unroll
        for (int u = 0; u < 4; ++u) {
            int e = base + (it + u) * 256 + tid;
            ok[u] = e < E;
            d[u] = ok[u] ? ei[E + e] : 0;
        }
#pragma unroll
        for (int u = 0; u < 4; ++u)
            if (ok[u]) atomicAdd(&hist[d[u] >> 8], 1);
    }
    __syncthreads();
    histM[(size_t)b * MAXD + tid] = hist[tid];
    histM[(size_t)b * MAXD + tid + 256] = hist[tid + 256];
}

// ---- B1: per-digit exclusive scan over chunks (in place) + digit totals ---
__global__ __launch_bounds__(256) void scan_digits_k(int* __restrict__ histM,
                                                     int* __restrict__ totals,
                                                     int NBLK) {
    __shared__ int s[256];
    const int t = threadIdx.x, dg = blockIdx.x;
    int v = (t < NBLK) ? histM[(size_t)t * MAXD + dg] : 0;
    s[t] = v;
    __syncthreads();
    for (int off = 1; off < 256; off <<= 1) {
        int x = (t >= off) ? s[t - off] : 0;
        __syncthreads();
        s[t] += x;
        __syncthreads();
    }
    if (t < NBLK) histM[(size_t)t * MAXD + dg] = s[t] - v;
    if (t == 255) totals[dg] = s[255];
}

// ---- B2: exclusive scan of digit totals -> coarse bucket bases ------------
__global__ __launch_bounds__(512) void scan_base_k(const int* __restrict__ totals,
                                                   int* __restrict__ cb, int ND) {
    __shared__ int s[512];
    const int t = threadIdx.x;
    int v = (t < ND) ? totals[t] : 0;
    s[t] = v;
    __syncthreads();
    for (int off = 1; off < 512; off <<= 1) {
        int x = (t >= off) ? s[t - off] : 0;
        __syncthreads();
        s[t] += x;
        __syncthreads();
    }
    if (t < ND) cb[t] = s[t] - v;
    if (t == 511) cb[ND] = s[511];  // = E
}

// ---- GEMM body: T = H @ W; HALF_OUT scales rows by dinv, emits fp16 at
//      row stride 64 (single sentinel layout for all layers) ----------------
template <int K, int OUT, bool HALF_OUT>
__device__ __forceinline__ void gemm_body(const float* __restrict__ H,
                                          const float* __restrict__ W,
                                          const float* __restrict__ dinv,
                                          void* __restrict__ Tout, int n, int bx) {
    constexpr int TX  = OUT / 4;
    constexpr int TY  = 256 / TX;
    constexpr int BM  = TY * 4;
    constexpr int BK  = 32;
    constexpr int PAD = 4;

    __shared__ float At[BK][BM + PAD];
    __shared__ float Ws[BK][OUT];

    const int t    = threadIdx.x;
    const int cx   = t % TX;
    const int ry   = t / TX;
    const int row0 = bx * BM;

    float acc[4][4] = {{0.f}};
    const int arow = t >> 3;
    const int af4  = t & 7;

    for (int k0 = 0; k0 < K; k0 += BK) {
#pragma unroll
        for (int p = 0; p < BM / 32; ++p) {
            int r  = arow + p * 32;
            int gr = row0 + r;
            int grc = gr < n ? gr : n - 1;
            float4 v = *reinterpret_cast<const float4*>(
                H + (size_t)grc * K + k0 + af4 * 4);
            At[af4 * 4 + 0][r] = v.x;
            At[af4 * 4 + 1][r] = v.y;
            At[af4 * 4 + 2][r] = v.z;
            At[af4 * 4 + 3][r] = v.w;
        }
#pragma unroll
        for (int p = 0; p < (BK * OUT) / 1024; ++p) {
            int idx = t + p * 256;
            int wk  = idx / (OUT / 4);
            int wf  = idx % (OUT / 4);
            float4 v = *reinterpret_cast<const float4*>(
                W + (size_t)(k0 + wk) * OUT + wf * 4);
            *reinterpret_cast<float4*>(&Ws[wk][wf * 4]) = v;
        }
        __syncthreads();
#pragma unroll
        for (int k = 0; k < BK; ++k) {
            float4 a = *reinterpret_cast<const float4*>(&At[k][ry * 4]);
            float4 w = *reinterpret_cast<const float4*>(&Ws[k][cx * 4]);
            acc[0][0] = fmaf(a.x, w.x, acc[0][0]);
            acc[0][1] = fmaf(a.x, w.y, acc[0][1]);
            acc[0][2] = fmaf(a.x, w.z, acc[0][2]);
            acc[0][3] = fmaf(a.x, w.w, acc[0][3]);
            acc[1][0] = fmaf(a.y, w.x, acc[1][0]);
            acc[1][1] = fmaf(a.y, w.y, acc[1][1]);
            acc[1][2] = fmaf(a.y, w.z, acc[1][2]);
            acc[1][3] = fmaf(a.y, w.w, acc[1][3]);
            acc[2][0] = fmaf(a.z, w.x, acc[2][0]);
            acc[2][1] = fmaf(a.z, w.y, acc[2][1]);
            acc[2][2] = fmaf(a.z, w.z, acc[2][2]);
            acc[2][3] = fmaf(a.z, w.w, acc[2][3]);
            acc[3][0] = fmaf(a.w, w.x, acc[3][0]);
            acc[3][1] = fmaf(a.w, w.y, acc[3][1]);
            acc[3][2] = fmaf(a.w, w.z, acc[3][2]);
            acc[3][3] = fmaf(a.w, w.w, acc[3][3]);
        }
        __syncthreads();
    }
#pragma unroll
    for (int i = 0; i < 4; ++i) {
        int gr = row0 + ry * 4 + i;
        if (gr < n) {
            if constexpr (HALF_OUT) {
                float di = dinv[gr];
                union { ushort4 u; __half h[4]; } pk;
                pk.h[0] = __float2half_rn(acc[i][0] * di);
                pk.h[1] = __float2half_rn(acc[i][1] * di);
                pk.h[2] = __float2half_rn(acc[i][2] * di);
                pk.h[3] = __float2half_rn(acc[i][3] * di);
                *reinterpret_cast<ushort4*>(
                    (__half*)Tout + (size_t)gr * 64 + cx * 4) = pk.u;  // stride 64
            } else {
                float4 v = make_float4(acc[i][0], acc[i][1], acc[i][2], acc[i][3]);
                *reinterpret_cast<float4*>(
                    (float*)Tout + (size_t)gr * OUT + cx * 4) = v;
            }
        }
    }
}

// ---- pack scatter: CH hist chunks per block, exact LDS cursors ------------
__device__ __forceinline__ void pack_body(const int* __restrict__ ei,
                                          const int* __restrict__ histM,
                                          const int* __restrict__ cb,
                                          int* __restrict__ packed,
                                          int E, int ND, int b) {
    __shared__ int cur[MAXD];
    const int tid = threadIdx.x;
    for (int t = tid; t < ND; t += 256)
        cur[t] = cb[t] + histM[(size_t)(b * CH) * MAXD + t];
    __syncthreads();
    const int base = b * (CH * EB);
    for (int it = 0; it < (CH * EB) / 256; it += 4) {
        int s[4], d[4]; bool ok[4];
#pragma unroll
        for (int u = 0; u < 4; ++u) {
            int e = base + (it + u) * 256 + tid;
            ok[u] = e < E;
            if (ok[u]) { s[u] = ei[e]; d[u] = ei[E + e]; }
        }
#pragma unroll
        for (int u = 0; u < 4; ++u) {
            if (ok[u]) {
                int pos = atomicAdd(&cur[d[u] >> 8], 1);
                packed[pos] = (s[u] << 8) | (d[u] & 255);
            }
        }
    }
}

// Fused: hist + first slice of layer-1 GEMM.
__global__ __launch_bounds__(256) void hist_gemm1_k(
    const int* __restrict__ ei, int* __restrict__ histM, int E,
    const float* __restrict__ x, const float* __restrict__ W1,
    float* __restrict__ T1, int n, int NH) {
    const int bx = blockIdx.x;
    if (bx < NH) hist_body(ei, histM, E, bx);
    else         gemm_body<128, 64, false>(x, W1, nullptr, T1, n, bx - NH);
}

// Fused: pack + remaining layer-1 GEMM blocks.
__global__ __launch_bounds__(256) void pack_gemm1_k(
    const int* __restrict__ ei, const int* __restrict__ histM,
    const int* __restrict__ cb, int* __restrict__ packed,
    const float* __restrict__ x, const float* __restrict__ W1,
    float* __restrict__ T1, int n, int E, int ND, int NPB, int G1) {
    const int bx = blockIdx.x;
    if (bx < NPB) pack_body(ei, histM, cb, packed, E, ND, bx);
    else          gemm_body<128, 64, false>(x, W1, nullptr, T1, n, G1 + bx - NPB);
}

// ---- per-coarse-bucket finalize: low-8 hist -> PADDED rowptr/counts (slot0
//      = self, pads -> sentinel row n), dinv, col scatter, layer-1 scale+fp16,
//      sentinel zeroing --------------------------------------------------- --
__global__ __launch_bounds__(256) void bucket_k(const int* __restrict__ packed,
                                                const int* __restrict__ cb,
                                                int* __restrict__ col,
                                                int* __restrict__ rowptr,
                                                int* __restrict__ counts,
                                                float* __restrict__ dinv,
                                                const float* __restrict__ Traw,
                                                __half* __restrict__ Th, int n) {
    __shared__ int   hist[256];
    __shared__ int   pref[256];
    __shared__ int   cur[256];
    __shared__ float dinv_l[256];

    const int tid   = threadIdx.x;
    const int dg    = blockIdx.x;
    const int base  = cb[dg];
    const int m     = cb[dg + 1] - base;
    const int basep = base + dg * PADSLACK;

    hist[tid] = 0;
    __syncthreads();
    // phase 1: low-8 histogram
    for (int k0 = 0; k0 < m; k0 += 1024) {
        int v[4]; bool ok[4];
#pragma unroll
        for (int u = 0; u < 4; ++u) {
            int k = k0 + u * 256 + tid;
            ok[u] = k < m;
            v[u] = ok[u] ? packed[base + k] : 0;
        }
#pragma unroll
        for (int u = 0; u < 4; ++u)
            if (ok[u]) atomicAdd(&hist[v[u] & 255], 1);
    }
    __syncthreads();
    // phase 2: padded sizes (deg+1 self, round to x16), scan, per-dst outputs
    const int deg   = hist[tid];
    const int cnt_p = (deg + 16) & ~15;  // >= deg+1, multiple of 16
    pref[tid] = cnt_p;
    __syncthreads();
    for (int off = 1; off < 256; off <<= 1) {
        int x = (tid >= off) ? pref[tid - off] : 0;
        __syncthreads();
        pref[tid] += x;
        __syncthreads();
    }
    const int rp = basep + pref[tid] - cnt_p;
    const float di = rsqrtf((float)(deg + 1));
    dinv_l[tid] = di;
    cur[tid] = rp + 1;  // edges after the self slot
    const int d = dg * 256 + tid;
    if (d < n) {
        counts[d] = cnt_p;
        dinv[d]   = di;
        rowptr[d] = rp;
        col[rp]   = d;                                   // self slot
        for (int k = deg + 1; k < cnt_p; ++k) col[rp + k] = n;  // sentinel pads
    }
    __syncthreads();
    // phase 3: scatter src into col
    for (int k0 = 0; k0 < m; k0 += 1024) {
        int v[4]; bool ok[4];
#pragma unroll
        for (int u = 0; u < 4; ++u) {
            int k = k0 + u * 256 + tid;
            ok[u] = k < m;
            v[u] = ok[u] ? packed[base + k] : 0;
        }
#pragma unroll
        for (int u = 0; u < 4; ++u) {
            if (ok[u]) {
                int pos = atomicAdd(&cur[v[u] & 255], 1);
                col[pos] = v[u] >> 8;
            }
        }
    }
    // phase 4: scale + fp16-convert this bucket's 256 rows of layer-1 T
    const int r0 = dg * 256;
#pragma unroll 4
    for (int it = 0; it < 16; ++it) {
        int idx = it * 256 + tid;        // float4 index within bucket rows
        int rl  = idx >> 4;
        int r   = r0 + rl;
        if (r < n) {
            float4 v = reinterpret_cast<const float4*>(Traw)[(size_t)r * 16 + (idx & 15)];
            float dd = dinv_l[rl];
            union { ushort4 u; __half h[4]; } pk;
            pk.h[0] = __float2half_rn(v.x * dd);
            pk.h[1] = __float2half_rn(v.y * dd);
            pk.h[2] = __float2half_rn(v.z * dd);
            pk.h[3] = __float2half_rn(v.w * dd);
            reinterpret_cast<ushort4*>(Th)[(size_t)r * 16 + (idx & 15)] = pk.u;
        }
    }
    // sentinel row n (zeros); survives all layers (gemm writes rows < n only)
    if (dg == 0 && tid < 16) {
        uint2 z; z.x = 0u; z.y = 0u;
        reinterpret_cast<uint2*>(Th)[(size_t)n * 16 + tid] = z;
    }
}

template <int K, int OUT>
__global__ __launch_bounds__(256) void gemm_h_k(const float* __restrict__ H,
                                                const float* __restrict__ W,
                                                const float* __restrict__ dinv,
                                                __half* __restrict__ T, int n) {
    gemm_body<K, OUT, true>(H, W, dinv, T, n, blockIdx.x);
}

// One wave per node, MASKLESS: counts padded (incl. self + sentinel pads),
// steps of exactly 16 edges.  Lane loads uint2 (4 fp16 ch); LR lanes/row;
// NSW sub-waves process distinct edges per load instr.  Table rows stride 64.
template <int LR, bool FUSE_HEAD>   // LR=16: 64ch; LR=8: 32ch
__global__ __launch_bounds__(256) void agg_k(const __half* __restrict__ T,
                                             const int* __restrict__ rowptr,
                                             const int* __restrict__ counts,
                                             const int* __restrict__ col,
                                             const float* __restrict__ dinv,
                                             const float* __restrict__ bias,
                                             float* __restrict__ O, int n,
                                             const float* __restrict__ Wh,
                                             const float* __restrict__ bh) {
    constexpr int NSW = 64 / LR;     // 4 / 8
    constexpr int U   = 16 / NSW;    // 4 / 2
    const int lane = threadIdx.x & 63;
    const int q    = lane % LR;
    const int sw   = lane / LR;
    const int i = (blockIdx.x * blockDim.x + threadIdx.x) >> 6;
    if (i >= n) return;

    const int start = rowptr[i];
    const int cnt   = counts[i];     // padded: multiple of 16, includes self
    const uint2* __restrict__ T2 = reinterpret_cast<const uint2*>(T);

    float4 acc = make_float4(0.f, 0.f, 0.f, 0.f);
    for (int base = 0; base < cnt; base += 64) {
        const int m = min(64, cnt - base);       // in {16,32,48,64}
        int c_l = col[start + base + lane];      // unconditional (slack-safe)
        for (int jg = 0; jg < m; jg += 16) {
            int cc[U]; uint2 v[U];
#pragma unroll
            for (int u = 0; u < U; ++u)
                cc[u] = __shfl(c_l, jg + u * NSW + sw, 64);
#pragma unroll
            for (int u = 0; u < U; ++u) v[u] = T2[(size_t)cc[u] * 16 + q];
#pragma unroll
            for (int u = 0; u < U; ++u) {
                const __half2* h2 = reinterpret_cast<const __half2*>(&v[u]);
                float2 f0 = __half22float2(h2[0]);
                float2 f1 = __half22float2(h2[1]);
                acc.x += f0.x; acc.y += f0.y; acc.z += f1.x; acc.w += f1.y;
            }
        }
    }
    // cross-sub-wave reduce: after this, all lanes hold full sums for their q
#pragma unroll
    for (int off = LR; off < 64; off <<= 1) {
        acc.x += __shfl_xor(acc.x, off, 64);
        acc.y += __shfl_xor(acc.y, off, 64);
        acc.z += __shfl_xor(acc.z, off, 64);
        acc.w += __shfl_xor(acc.w, off, 64);
    }
    const float di = dinv[i];
    const float4 b4 = reinterpret_cast<const float4*>(bias)[q];
    float4 h;
    h.x = fmaxf(fmaf(di, acc.x, b4.x), 0.f);
    h.y = fmaxf(fmaf(di, acc.y, b4.y), 0.f);
    h.z = fmaxf(fmaf(di, acc.z, b4.z), 0.f);
    h.w = fmaxf(fmaf(di, acc.w, b4.w), 0.f);
    if constexpr (!FUSE_HEAD) {
        if (sw == 0)
            reinterpret_cast<float4*>(O + (size_t)i * 64)[q] = h;
    } else {
        // LR==8 (32ch): out[i] = h(32) @ Wh(32x3) + bh; reduce over q=0..7
        float p0 = h.x * Wh[(4 * q + 0) * 3 + 0];
        float p1 = h.x * Wh[(4 * q + 0) * 3 + 1];
        float p2 = h.x * Wh[(4 * q + 0) * 3 + 2];
        p0 = fmaf(h.y, Wh[(4 * q + 1) * 3 + 0], p0);
        p1 = fmaf(h.y, Wh[(4 * q + 1) * 3 + 1], p1);
        p2 = fmaf(h.y, Wh[(4 * q + 1) * 3 + 2], p2);
        p0 = fmaf(h.z, Wh[(4 * q + 2) * 3 + 0], p0);
        p1 = fmaf(h.z, Wh[(4 * q + 2) * 3 + 1], p1);
        p2 = fmaf(h.z, Wh[(4 * q + 2) * 3 + 2], p2);
        p0 = fmaf(h.w, Wh[(4 * q + 3) * 3 + 0], p0);
        p1 = fmaf(h.w, Wh[(4 * q + 3) * 3 + 1], p1);
        p2 = fmaf(h.w, Wh[(4 * q + 3) * 3 + 2], p2);
#pragma unroll
        for (int off = 1; off < LR; off <<= 1) {
            p0 += __shfl_xor(p0, off, 64);
            p1 += __shfl_xor(p1, off, 64);
            p2 += __shfl_xor(p2, off, 64);
        }
        if (lane == 0) {
            O[(size_t)i * 3 + 0] = p0 + bh[0];
            O[(size_t)i * 3 + 1] = p1 + bh[1];
            O[(size_t)i * 3 + 2] = p2 + bh[2];
        }
    }
}

extern "C" void kernel_launch(void* const* d_in, const int* in_sizes, int n_in,
                              void* d_out, int out_size, void* d_ws, size_t ws_size,
                              hipStream_t stream) {
    const float* x  = (const float*)d_in[0];
    const int*   ei = (const int*)d_in[1];
    const float* W1 = (const float*)d_in[2];
    const float* b1 = (const float*)d_in[3];
    const float* W2 = (const float*)d_in[4];
    const float* b2 = (const float*)d_in[5];
    const float* W3 = (const float*)d_in[6];
    const float* b3 = (const float*)d_in[7];
    const float* W4 = (const float*)d_in[8];
    const float* b4 = (const float*)d_in[9];
    const float* Wh = (const float*)d_in[10];
    const float* bh = (const float*)d_in[11];
    float* out = (float*)d_out;

    const int n = in_sizes[0] / 128;
    const int E = in_sizes[1] / 2;
    const int ND   = (n + 255) / 256;       // coarse digits (<= MAXD)
    const int NBLK = (E + EB - 1) / EB;     // hist chunks (<= 256)
    const int NPB  = (NBLK + CH - 1) / CH;  // pack blocks

    char* ws = (char*)d_ws;
    auto alloc = [&](size_t bytes) {
        char* p = ws;
        ws += (bytes + 255) & ~(size_t)255;
        return p;
    };
    int*    histM  = (int*)alloc((size_t)NBLK * MAXD * 4);
    int*    totals = (int*)alloc((size_t)MAXD * 4);
    int*    cbA    = (int*)alloc((size_t)(MAXD + 1) * 4);
    int*    packed = (int*)alloc((size_t)E * 4);
    int*    col    = (int*)alloc(((size_t)E + (size_t)ND * PADSLACK + 256) * 4);
    int*    rowptr = (int*)alloc((size_t)n * 4);
    int*    counts = (int*)alloc((size_t)n * 4);
    float*  dinv   = (float*)alloc((size_t)n * 4);
    float*  bufF   = (float*)alloc((size_t)n * 64 * 4);         // fp32 agg out / raw T1
    __half* bufH   = (__half*)alloc(((size_t)n + 1) * 64 * 2);  // fp16 table + sentinel

    dim3 blk(256);
    const int G  = (n + 63) / 64;   // layer-1 gemm blocks
    const int G1 = G / 3;           // slice fused with hist
    const int G2 = G - G1;          // slice fused with pack
    const int agg_blocks = (n + 3) / 4;

    // ---- atomic-free CSR build + layer-1 transform ----
    hist_gemm1_k<<<dim3(NBLK + G1), blk, 0, stream>>>(ei, histM, E, x, W1, bufF, n, NBLK);
    scan_digits_k<<<dim3(ND), blk, 0, stream>>>(histM, totals, NBLK);
    scan_base_k<<<dim3(1), dim3(512), 0, stream>>>(totals, cbA, ND);
    pack_gemm1_k<<<dim3(NPB + G2), blk, 0, stream>>>(ei, histM, cbA, packed,
                                                     x, W1, bufF, n, E, ND, NPB, G1);
    bucket_k<<<dim3(ND), blk, 0, stream>>>(packed, cbA, col, rowptr, counts,
                                           dinv, bufF, bufH, n);
    // ---- Layer 1 agg ----
    agg_k<16, false><<<dim3(agg_blocks), blk, 0, stream>>>(
        bufH, rowptr, counts, col, dinv, b1, bufF, n, nullptr, nullptr);
    // ---- Layer 2 ----
    gemm_h_k<64, 64><<<dim3(G), blk, 0, stream>>>(bufF, W2, dinv, bufH, n);
    agg_k<16, false><<<dim3(agg_blocks), blk, 0, stream>>>(
        bufH, rowptr, counts, col, dinv, b2, bufF, n, nullptr, nullptr);
    // ---- Layer 3 ----
    gemm_h_k<64, 64><<<dim3(G), blk, 0, stream>>>(bufF, W3, dinv, bufH, n);
    agg_k<16, false><<<dim3(agg_blocks), blk, 0, stream>>>(
        bufH, rowptr, counts, col, dinv, b3, bufF, n, nullptr, nullptr);
    // ---- Layer 4 (+ fused head); fp16 table written at stride 64 ----
    gemm_h_k<64, 32><<<dim3((n + 127) / 128), blk, 0, stream>>>(bufF, W4, dinv, bufH, n);
    agg_k<8, true><<<dim3(agg_blocks), blk, 0, stream>>>(
        bufH, rowptr, counts, col, dinv, b4, out, n, Wh, bh);
}

// Round 9
// 383.876 us; speedup vs baseline: 3.1580x; 1.0428x over previous
//
#include <hip/hip_runtime.h>
#include <hip/hip_bf16.h>
#include <hip/hip_fp16.h>
#include <cstdint>

// ---------------------------------------------------------------------------
// SPDE GCN: 4x GCNConv + linear head, fp32 in/out.
// R3-R7: uint2 multi-edge MLP agg; fp16 feature table; dinv pre/post scaling;
//        atomic-free MSD bucket-sort CSR; head fused into agg4.
// R8: padded maskless agg (worked, ~-30us); pack coarsening CH=4 (REGRESSED:
//     49 blocks -> 10% occupancy tail, write-amp was not the limiter).
// R9: (a) pack back to CH=1 (196 blocks) - parallelism over write-amp.
//     (b) pad to x8 (was x16): ~20% fewer agg gathers; agg gets one uniform
//         half-step (8 edges) when cnt&8 - still fully maskless.
// ---------------------------------------------------------------------------

#define MAXD 512       // max coarse digits (n <= 131072)
#define EB   8192      // edges per hist/pack chunk
#define PADSLACK 2048  // max per-bucket padding (256 nodes * 8)

// ---- hist body: coarse histogram (block-major histM[b][dg]) ---------------
__device__ __forceinline__ void hist_body(const int* __restrict__ ei,
                                          int* __restrict__ histM, int E, int b) {
    __shared__ int hist[MAXD];
    const int tid = threadIdx.x;
    hist[tid] = 0; hist[tid + 256] = 0;
    __syncthreads();
    const int base = b * EB;
#pragma unroll 2
    for (int it = 0; it < EB / 256; it += 4) {
        int d[4]; bool ok[4];
#pragma unroll
        for (int u = 0; u < 4; ++u) {
            int e = base + (it + u) * 256 + tid;
            ok[u] = e < E;
            d[u] = ok[u] ? ei[E + e] : 0;
        }
#pragma unroll
        for (int u = 0; u < 4; ++u)
            if (ok[u]) atomicAdd(&hist[d[u] >> 8], 1);
    }
    __syncthreads();
    histM[(size_t)b * MAXD + tid] = hist[tid];
    histM[(size_t)b * MAXD + tid + 256] = hist[tid + 256];
}

// ---- B1: per-digit exclusive scan over chunks (in place) + digit totals ---
__global__ __launch_bounds__(256) void scan_digits_k(int* __restrict__ histM,
                                                     int* __restrict__ totals,
                                                     int NBLK) {
    __shared__ int s[256];
    const int t = threadIdx.x, dg = blockIdx.x;
    int v = (t < NBLK) ? histM[(size_t)t * MAXD + dg] : 0;
    s[t] = v;
    __syncthreads();
    for (int off = 1; off < 256; off <<= 1) {
        int x = (t >= off) ? s[t - off] : 0;
        __syncthreads();
        s[t] += x;
        __syncthreads();
    }
    if (t < NBLK) histM[(size_t)t * MAXD + dg] = s[t] - v;
    if (t == 255) totals[dg] = s[255];
}

// ---- B2: exclusive scan of digit totals -> coarse bucket bases ------------
__global__ __launch_bounds__(512) void scan_base_k(const int* __restrict__ totals,
                                                   int* __restrict__ cb, int ND) {
    __shared__ int s[512];
    const int t = threadIdx.x;
    int v = (t < ND) ? totals[t] : 0;
    s[t] = v;
    __syncthreads();
    for (int off = 1; off < 512; off <<= 1) {
        int x = (t >= off) ? s[t - off] : 0;
        __syncthreads();
        s[t] += x;
        __syncthreads();
    }
    if (t < ND) cb[t] = s[t] - v;
    if (t == 511) cb[ND] = s[511];  // = E
}

// ---- GEMM body: T = H @ W; HALF_OUT scales rows by dinv, emits fp16 at
//      row stride 64 (single sentinel layout for all layers) ----------------
template <int K, int OUT, bool HALF_OUT>
__device__ __forceinline__ void gemm_body(const float* __restrict__ H,
                                          const float* __restrict__ W,
                                          const float* __restrict__ dinv,
                                          void* __restrict__ Tout, int n, int bx) {
    constexpr int TX  = OUT / 4;
    constexpr int TY  = 256 / TX;
    constexpr int BM  = TY * 4;
    constexpr int BK  = 32;
    constexpr int PAD = 4;

    __shared__ float At[BK][BM + PAD];
    __shared__ float Ws[BK][OUT];

    const int t    = threadIdx.x;
    const int cx   = t % TX;
    const int ry   = t / TX;
    const int row0 = bx * BM;

    float acc[4][4] = {{0.f}};
    const int arow = t >> 3;
    const int af4  = t & 7;

    for (int k0 = 0; k0 < K; k0 += BK) {
#pragma unroll
        for (int p = 0; p < BM / 32; ++p) {
            int r  = arow + p * 32;
            int gr = row0 + r;
            int grc = gr < n ? gr : n - 1;
            float4 v = *reinterpret_cast<const float4*>(
                H + (size_t)grc * K + k0 + af4 * 4);
            At[af4 * 4 + 0][r] = v.x;
            At[af4 * 4 + 1][r] = v.y;
            At[af4 * 4 + 2][r] = v.z;
            At[af4 * 4 + 3][r] = v.w;
        }
#pragma unroll
        for (int p = 0; p < (BK * OUT) / 1024; ++p) {
            int idx = t + p * 256;
            int wk  = idx / (OUT / 4);
            int wf  = idx % (OUT / 4);
            float4 v = *reinterpret_cast<const float4*>(
                W + (size_t)(k0 + wk) * OUT + wf * 4);
            *reinterpret_cast<float4*>(&Ws[wk][wf * 4]) = v;
        }
        __syncthreads();
#pragma unroll
        for (int k = 0; k < BK; ++k) {
            float4 a = *reinterpret_cast<const float4*>(&At[k][ry * 4]);
            float4 w = *reinterpret_cast<const float4*>(&Ws[k][cx * 4]);
            acc[0][0] = fmaf(a.x, w.x, acc[0][0]);
            acc[0][1] = fmaf(a.x, w.y, acc[0][1]);
            acc[0][2] = fmaf(a.x, w.z, acc[0][2]);
            acc[0][3] = fmaf(a.x, w.w, acc[0][3]);
            acc[1][0] = fmaf(a.y, w.x, acc[1][0]);
            acc[1][1] = fmaf(a.y, w.y, acc[1][1]);
            acc[1][2] = fmaf(a.y, w.z, acc[1][2]);
            acc[1][3] = fmaf(a.y, w.w, acc[1][3]);
            acc[2][0] = fmaf(a.z, w.x, acc[2][0]);
            acc[2][1] = fmaf(a.z, w.y, acc[2][1]);
            acc[2][2] = fmaf(a.z, w.z, acc[2][2]);
            acc[2][3] = fmaf(a.z, w.w, acc[2][3]);
            acc[3][0] = fmaf(a.w, w.x, acc[3][0]);
            acc[3][1] = fmaf(a.w, w.y, acc[3][1]);
            acc[3][2] = fmaf(a.w, w.z, acc[3][2]);
            acc[3][3] = fmaf(a.w, w.w, acc[3][3]);
        }
        __syncthreads();
    }
#pragma unroll
    for (int i = 0; i < 4; ++i) {
        int gr = row0 + ry * 4 + i;
        if (gr < n) {
            if constexpr (HALF_OUT) {
                float di = dinv[gr];
                union { ushort4 u; __half h[4]; } pk;
                pk.h[0] = __float2half_rn(acc[i][0] * di);
                pk.h[1] = __float2half_rn(acc[i][1] * di);
                pk.h[2] = __float2half_rn(acc[i][2] * di);
                pk.h[3] = __float2half_rn(acc[i][3] * di);
                *reinterpret_cast<ushort4*>(
                    (__half*)Tout + (size_t)gr * 64 + cx * 4) = pk.u;  // stride 64
            } else {
                float4 v = make_float4(acc[i][0], acc[i][1], acc[i][2], acc[i][3]);
                *reinterpret_cast<float4*>(
                    (float*)Tout + (size_t)gr * OUT + cx * 4) = v;
            }
        }
    }
}

// ---- pack scatter: ONE hist chunk per block (parallelism > write-amp) -----
__device__ __forceinline__ void pack_body(const int* __restrict__ ei,
                                          const int* __restrict__ histM,
                                          const int* __restrict__ cb,
                                          int* __restrict__ packed,
                                          int E, int ND, int b) {
    __shared__ int cur[MAXD];
    const int tid = threadIdx.x;
    for (int t = tid; t < ND; t += 256)
        cur[t] = cb[t] + histM[(size_t)b * MAXD + t];
    __syncthreads();
    const int base = b * EB;
    for (int it = 0; it < EB / 256; it += 4) {
        int s[4], d[4]; bool ok[4];
#pragma unroll
        for (int u = 0; u < 4; ++u) {
            int e = base + (it + u) * 256 + tid;
            ok[u] = e < E;
            if (ok[u]) { s[u] = ei[e]; d[u] = ei[E + e]; }
        }
#pragma unroll
        for (int u = 0; u < 4; ++u) {
            if (ok[u]) {
                int pos = atomicAdd(&cur[d[u] >> 8], 1);
                packed[pos] = (s[u] << 8) | (d[u] & 255);
            }
        }
    }
}

// Fused: hist + first slice of layer-1 GEMM.
__global__ __launch_bounds__(256) void hist_gemm1_k(
    const int* __restrict__ ei, int* __restrict__ histM, int E,
    const float* __restrict__ x, const float* __restrict__ W1,
    float* __restrict__ T1, int n, int NH) {
    const int bx = blockIdx.x;
    if (bx < NH) hist_body(ei, histM, E, bx);
    else         gemm_body<128, 64, false>(x, W1, nullptr, T1, n, bx - NH);
}

// Fused: pack + remaining layer-1 GEMM blocks.
__global__ __launch_bounds__(256) void pack_gemm1_k(
    const int* __restrict__ ei, const int* __restrict__ histM,
    const int* __restrict__ cb, int* __restrict__ packed,
    const float* __restrict__ x, const float* __restrict__ W1,
    float* __restrict__ T1, int n, int E, int ND, int NPB, int G1) {
    const int bx = blockIdx.x;
    if (bx < NPB) pack_body(ei, histM, cb, packed, E, ND, bx);
    else          gemm_body<128, 64, false>(x, W1, nullptr, T1, n, G1 + bx - NPB);
}

// ---- per-coarse-bucket finalize: low-8 hist -> PADDED rowptr/counts (x8,
//      slot0 = self, pads -> sentinel row n), dinv, col scatter, layer-1
//      scale+fp16, sentinel zeroing ----------------------------------------
__global__ __launch_bounds__(256) void bucket_k(const int* __restrict__ packed,
                                                const int* __restrict__ cb,
                                                int* __restrict__ col,
                                                int* __restrict__ rowptr,
                                                int* __restrict__ counts,
                                                float* __restrict__ dinv,
                                                const float* __restrict__ Traw,
                                                __half* __restrict__ Th, int n) {
    __shared__ int   hist[256];
    __shared__ int   pref[256];
    __shared__ int   cur[256];
    __shared__ float dinv_l[256];

    const int tid   = threadIdx.x;
    const int dg    = blockIdx.x;
    const int base  = cb[dg];
    const int m     = cb[dg + 1] - base;
    const int basep = base + dg * PADSLACK;

    hist[tid] = 0;
    __syncthreads();
    // phase 1: low-8 histogram
    for (int k0 = 0; k0 < m; k0 += 1024) {
        int v[4]; bool ok[4];
#pragma unroll
        for (int u = 0; u < 4; ++u) {
            int k = k0 + u * 256 + tid;
            ok[u] = k < m;
            v[u] = ok[u] ? packed[base + k] : 0;
        }
#pragma unroll
        for (int u = 0; u < 4; ++u)
            if (ok[u]) atomicAdd(&hist[v[u] & 255], 1);
    }
    __syncthreads();
    // phase 2: padded sizes (deg+1 incl. self, round to x8), scan, outputs
    const int deg   = hist[tid];
    const int cnt_p = (deg + 8) & ~7;  // >= deg+1, multiple of 8
    pref[tid] = cnt_p;
    __syncthreads();
    for (int off = 1; off < 256; off <<= 1) {
        int x = (tid >= off) ? pref[tid - off] : 0;
        __syncthreads();
        pref[tid] += x;
        __syncthreads();
    }
    const int rp = basep + pref[tid] - cnt_p;
    const float di = rsqrtf((float)(deg + 1));
    dinv_l[tid] = di;
    cur[tid] = rp + 1;  // edges after the self slot
    const int d = dg * 256 + tid;
    if (d < n) {
        counts[d] = cnt_p;
        dinv[d]   = di;
        rowptr[d] = rp;
        col[rp]   = d;                                        // self slot
        for (int k = deg + 1; k < cnt_p; ++k) col[rp + k] = n;  // sentinel pads
    }
    __syncthreads();
    // phase 3: scatter src into col
    for (int k0 = 0; k0 < m; k0 += 1024) {
        int v[4]; bool ok[4];
#pragma unroll
        for (int u = 0; u < 4; ++u) {
            int k = k0 + u * 256 + tid;
            ok[u] = k < m;
            v[u] = ok[u] ? packed[base + k] : 0;
        }
#pragma unroll
        for (int u = 0; u < 4; ++u) {
            if (ok[u]) {
                int pos = atomicAdd(&cur[v[u] & 255], 1);
                col[pos] = v[u] >> 8;
            }
        }
    }
    // phase 4: scale + fp16-convert this bucket's 256 rows of layer-1 T
    const int r0 = dg * 256;
#pragma unroll 4
    for (int it = 0; it < 16; ++it) {
        int idx = it * 256 + tid;        // float4 index within bucket rows
        int rl  = idx >> 4;
        int r   = r0 + rl;
        if (r < n) {
            float4 v = reinterpret_cast<const float4*>(Traw)[(size_t)r * 16 + (idx & 15)];
            float dd = dinv_l[rl];
            union { ushort4 u; __half h[4]; } pk;
            pk.h[0] = __float2half_rn(v.x * dd);
            pk.h[1] = __float2half_rn(v.y * dd);
            pk.h[2] = __float2half_rn(v.z * dd);
            pk.h[3] = __float2half_rn(v.w * dd);
            reinterpret_cast<ushort4*>(Th)[(size_t)r * 16 + (idx & 15)] = pk.u;
        }
    }
    // sentinel row n (zeros); survives all layers (gemm writes rows < n only)
    if (dg == 0 && tid < 16) {
        uint2 z; z.x = 0u; z.y = 0u;
        reinterpret_cast<uint2*>(Th)[(size_t)n * 16 + tid] = z;
    }
}

template <int K, int OUT>
__global__ __launch_bounds__(256) void gemm_h_k(const float* __restrict__ H,
                                                const float* __restrict__ W,
                                                const float* __restrict__ dinv,
                                                __half* __restrict__ T, int n) {
    gemm_body<K, OUT, true>(H, W, dinv, T, n, blockIdx.x);
}

// One wave per node, MASKLESS: counts padded to x8 (incl. self + sentinel
// pads).  Full steps of 16 edges + at most one uniform half-step of 8.
// Lane loads uint2 (4 fp16 ch); LR lanes/row; table rows stride 64.
template <int LR, bool FUSE_HEAD>   // LR=16: 64ch; LR=8: 32ch
__global__ __launch_bounds__(256) void agg_k(const __half* __restrict__ T,
                                             const int* __restrict__ rowptr,
                                             const int* __restrict__ counts,
                                             const int* __restrict__ col,
                                             const float* __restrict__ dinv,
                                             const float* __restrict__ bias,
                                             float* __restrict__ O, int n,
                                             const float* __restrict__ Wh,
                                             const float* __restrict__ bh) {
    constexpr int NSW = 64 / LR;     // 4 / 8
    constexpr int U   = 16 / NSW;    // 4 / 2  (full step)
    constexpr int UH  = U / 2;       // 2 / 1  (half step)
    const int lane = threadIdx.x & 63;
    const int q    = lane % LR;
    const int sw   = lane / LR;
    const int i = (blockIdx.x * blockDim.x + threadIdx.x) >> 6;
    if (i >= n) return;

    const int start = rowptr[i];
    const int cnt   = counts[i];     // padded: multiple of 8, includes self
    const uint2* __restrict__ T2 = reinterpret_cast<const uint2*>(T);

    float4 acc = make_float4(0.f, 0.f, 0.f, 0.f);
    for (int base = 0; base < cnt; base += 64) {
        const int m = min(64, cnt - base);       // multiple of 8
        int c_l = col[start + base + lane];      // unconditional (slack-safe)
        int jg = 0;
        for (; jg + 16 <= m; jg += 16) {
            int cc[U]; uint2 v[U];
#pragma unroll
            for (int u = 0; u < U; ++u)
                cc[u] = __shfl(c_l, jg + u * NSW + sw, 64);
#pragma unroll
            for (int u = 0; u < U; ++u) v[u] = T2[(size_t)cc[u] * 16 + q];
#pragma unroll
            for (int u = 0; u < U; ++u) {
                const __half2* h2 = reinterpret_cast<const __half2*>(&v[u]);
                float2 f0 = __half22float2(h2[0]);
                float2 f1 = __half22float2(h2[1]);
                acc.x += f0.x; acc.y += f0.y; acc.z += f1.x; acc.w += f1.y;
            }
        }
        if (jg < m) {  // exactly 8 edges left; uniform across the wave
            int cc[UH]; uint2 v[UH];
#pragma unroll
            for (int u = 0; u < UH; ++u)
                cc[u] = __shfl(c_l, jg + u * NSW + sw, 64);
#pragma unroll
            for (int u = 0; u < UH; ++u) v[u] = T2[(size_t)cc[u] * 16 + q];
#pragma unroll
            for (int u = 0; u < UH; ++u) {
                const __half2* h2 = reinterpret_cast<const __half2*>(&v[u]);
                float2 f0 = __half22float2(h2[0]);
                float2 f1 = __half22float2(h2[1]);
                acc.x += f0.x; acc.y += f0.y; acc.z += f1.x; acc.w += f1.y;
            }
        }
    }
    // cross-sub-wave reduce: after this, all lanes hold full sums for their q
#pragma unroll
    for (int off = LR; off < 64; off <<= 1) {
        acc.x += __shfl_xor(acc.x, off, 64);
        acc.y += __shfl_xor(acc.y, off, 64);
        acc.z += __shfl_xor(acc.z, off, 64);
        acc.w += __shfl_xor(acc.w, off, 64);
    }
    const float di = dinv[i];
    const float4 b4 = reinterpret_cast<const float4*>(bias)[q];
    float4 h;
    h.x = fmaxf(fmaf(di, acc.x, b4.x), 0.f);
    h.y = fmaxf(fmaf(di, acc.y, b4.y), 0.f);
    h.z = fmaxf(fmaf(di, acc.z, b4.z), 0.f);
    h.w = fmaxf(fmaf(di, acc.w, b4.w), 0.f);
    if constexpr (!FUSE_HEAD) {
        if (sw == 0)
            reinterpret_cast<float4*>(O + (size_t)i * 64)[q] = h;
    } else {
        // LR==8 (32ch): out[i] = h(32) @ Wh(32x3) + bh; reduce over q=0..7
        float p0 = h.x * Wh[(4 * q + 0) * 3 + 0];
        float p1 = h.x * Wh[(4 * q + 0) * 3 + 1];
        float p2 = h.x * Wh[(4 * q + 0) * 3 + 2];
        p0 = fmaf(h.y, Wh[(4 * q + 1) * 3 + 0], p0);
        p1 = fmaf(h.y, Wh[(4 * q + 1) * 3 + 1], p1);
        p2 = fmaf(h.y, Wh[(4 * q + 1) * 3 + 2], p2);
        p0 = fmaf(h.z, Wh[(4 * q + 2) * 3 + 0], p0);
        p1 = fmaf(h.z, Wh[(4 * q + 2) * 3 + 1], p1);
        p2 = fmaf(h.z, Wh[(4 * q + 2) * 3 + 2], p2);
        p0 = fmaf(h.w, Wh[(4 * q + 3) * 3 + 0], p0);
        p1 = fmaf(h.w, Wh[(4 * q + 3) * 3 + 1], p1);
        p2 = fmaf(h.w, Wh[(4 * q + 3) * 3 + 2], p2);
#pragma unroll
        for (int off = 1; off < LR; off <<= 1) {
            p0 += __shfl_xor(p0, off, 64);
            p1 += __shfl_xor(p1, off, 64);
            p2 += __shfl_xor(p2, off, 64);
        }
        if (lane == 0) {
            O[(size_t)i * 3 + 0] = p0 + bh[0];
            O[(size_t)i * 3 + 1] = p1 + bh[1];
            O[(size_t)i * 3 + 2] = p2 + bh[2];
        }
    }
}

extern "C" void kernel_launch(void* const* d_in, const int* in_sizes, int n_in,
                              void* d_out, int out_size, void* d_ws, size_t ws_size,
                              hipStream_t stream) {
    const float* x  = (const float*)d_in[0];
    const int*   ei = (const int*)d_in[1];
    const float* W1 = (const float*)d_in[2];
    const float* b1 = (const float*)d_in[3];
    const float* W2 = (const float*)d_in[4];
    const float* b2 = (const float*)d_in[5];
    const float* W3 = (const float*)d_in[6];
    const float* b3 = (const float*)d_in[7];
    const float* W4 = (const float*)d_in[8];
    const float* b4 = (const float*)d_in[9];
    const float* Wh = (const float*)d_in[10];
    const float* bh = (const float*)d_in[11];
    float* out = (float*)d_out;

    const int n = in_sizes[0] / 128;
    const int E = in_sizes[1] / 2;
    const int ND   = (n + 255) / 256;    // coarse digits (<= MAXD)
    const int NBLK = (E + EB - 1) / EB;  // hist/pack blocks (<= 256)

    char* ws = (char*)d_ws;
    auto alloc = [&](size_t bytes) {
        char* p = ws;
        ws += (bytes + 255) & ~(size_t)255;
        return p;
    };
    int*    histM  = (int*)alloc((size_t)NBLK * MAXD * 4);
    int*    totals = (int*)alloc((size_t)MAXD * 4);
    int*    cbA    = (int*)alloc((size_t)(MAXD + 1) * 4);
    int*    packed = (int*)alloc((size_t)E * 4);
    int*    col    = (int*)alloc(((size_t)E + (size_t)ND * PADSLACK + 256) * 4);
    int*    rowptr = (int*)alloc((size_t)n * 4);
    int*    counts = (int*)alloc((size_t)n * 4);
    float*  dinv   = (float*)alloc((size_t)n * 4);
    float*  bufF   = (float*)alloc((size_t)n * 64 * 4);         // fp32 agg out / raw T1
    __half* bufH   = (__half*)alloc(((size_t)n + 1) * 64 * 2);  // fp16 table + sentinel

    dim3 blk(256);
    const int G  = (n + 63) / 64;   // layer-1 gemm blocks
    const int G1 = G / 3;           // slice fused with hist
    const int G2 = G - G1;          // slice fused with pack
    const int agg_blocks = (n + 3) / 4;

    // ---- atomic-free CSR build + layer-1 transform ----
    hist_gemm1_k<<<dim3(NBLK + G1), blk, 0, stream>>>(ei, histM, E, x, W1, bufF, n, NBLK);
    scan_digits_k<<<dim3(ND), blk, 0, stream>>>(histM, totals, NBLK);
    scan_base_k<<<dim3(1), dim3(512), 0, stream>>>(totals, cbA, ND);
    pack_gemm1_k<<<dim3(NBLK + G2), blk, 0, stream>>>(ei, histM, cbA, packed,
                                                      x, W1, bufF, n, E, ND, NBLK, G1);
    bucket_k<<<dim3(ND), blk, 0, stream>>>(packed, cbA, col, rowptr, counts,
                                           dinv, bufF, bufH, n);
    // ---- Layer 1 agg ----
    agg_k<16, false><<<dim3(agg_blocks), blk, 0, stream>>>(
        bufH, rowptr, counts, col, dinv, b1, bufF, n, nullptr, nullptr);
    // ---- Layer 2 ----
    gemm_h_k<64, 64><<<dim3(G), blk, 0, stream>>>(bufF, W2, dinv, bufH, n);
    agg_k<16, false><<<dim3(agg_blocks), blk, 0, stream>>>(
        bufH, rowptr, counts, col, dinv, b2, bufF, n, nullptr, nullptr);
    // ---- Layer 3 ----
    gemm_h_k<64, 64><<<dim3(G), blk, 0, stream>>>(bufF, W3, dinv, bufH, n);
    agg_k<16, false><<<dim3(agg_blocks), blk, 0, stream>>>(
        bufH, rowptr, counts, col, dinv, b3, bufF, n, nullptr, nullptr);
    // ---- Layer 4 (+ fused head); fp16 table written at stride 64 ----
    gemm_h_k<64, 32><<<dim3((n + 127) / 128), blk, 0, stream>>>(bufF, W4, dinv, bufH, n);
    agg_k<8, true><<<dim3(agg_blocks), blk, 0, stream>>>(
        bufH, rowptr, counts, col, dinv, b4, out, n, Wh, bh);
}

// Round 10
// 365.719 us; speedup vs baseline: 3.3148x; 1.0496x over previous
//
#include <hip/hip_runtime.h>
#include <hip/hip_bf16.h>
#include <hip/hip_fp16.h>
#include <cstdint>

// ---------------------------------------------------------------------------
// SPDE GCN: 4x GCNConv + linear head, fp32 in/out.
// R3-R9: uint2 multi-edge MLP agg; fp16 feature table; dinv pre/post scaling;
//        atomic-free MSD bucket-sort CSR (hist/scan/pack/bucket, CSR fused
//        with layer-1 fp32 GEMM); maskless x8-padded CSR w/ sentinel row;
//        head fused into agg4.
// R10: (a) agg inner loop uses v_dot2_f32_f16 with {1,0}/{0,1} selectors:
//          one VOP3P per 2 channels w/ fp32 accumulate (was cvt+add x2).
//      (b) layers 2-4 transform = MFMA fp16 GEMM (16x16x32): aggs 1-3 emit
//          H fp16; W register-cached as B-frags; dinv-scaled fp16 store.
//          Layouts: A[m=lane&15][k=quad*8+j], B[k=quad*8+j][n=lane&15],
//          D row=quad*4+reg, col=lane&15.
//      bufG (fp16 H) aliases bufF (raw T1 fp32, dead after bucket_k).
// ---------------------------------------------------------------------------

#define MAXD 512       // max coarse digits (n <= 131072)
#define EB   8192      // edges per hist/pack chunk
#define PADSLACK 2048  // max per-bucket padding (256 nodes * 8)

typedef _Float16 half8v __attribute__((ext_vector_type(8)));
typedef _Float16 half2v __attribute__((ext_vector_type(2)));
typedef float    float4v __attribute__((ext_vector_type(4)));

#if defined(__has_builtin)
#if __has_builtin(__builtin_amdgcn_fdot2)
#define HAVE_FDOT2 1
#endif
#endif

__device__ __forceinline__ float fdot2f(half2v a, half2v b, float c) {
#ifdef HAVE_FDOT2
    return __builtin_amdgcn_fdot2(a, b, c, false);
#else
    return c + (float)a[0] * (float)b[0] + (float)a[1] * (float)b[1];
#endif
}

// ---- hist body: coarse histogram (block-major histM[b][dg]) ---------------
__device__ __forceinline__ void hist_body(const int* __restrict__ ei,
                                          int* __restrict__ histM, int E, int b) {
    __shared__ int hist[MAXD];
    const int tid = threadIdx.x;
    hist[tid] = 0; hist[tid + 256] = 0;
    __syncthreads();
    const int base = b * EB;
#pragma unroll 2
    for (int it = 0; it < EB / 256; it += 4) {
        int d[4]; bool ok[4];
#pragma unroll
        for (int u = 0; u < 4; ++u) {
            int e = base + (it + u) * 256 + tid;
            ok[u] = e < E;
            d[u] = ok[u] ? ei[E + e] : 0;
        }
#pragma unroll
        for (int u = 0; u < 4; ++u)
            if (ok[u]) atomicAdd(&hist[d[u] >> 8], 1);
    }
    __syncthreads();
    histM[(size_t)b * MAXD + tid] = hist[tid];
    histM[(size_t)b * MAXD + tid + 256] = hist[tid + 256];
}

// ---- B1: per-digit exclusive scan over chunks (in place) + digit totals ---
__global__ __launch_bounds__(256) void scan_digits_k(int* __restrict__ histM,
                                                     int* __restrict__ totals,
                                                     int NBLK) {
    __shared__ int s[256];
    const int t = threadIdx.x, dg = blockIdx.x;
    int v = (t < NBLK) ? histM[(size_t)t * MAXD + dg] : 0;
    s[t] = v;
    __syncthreads();
    for (int off = 1; off < 256; off <<= 1) {
        int x = (t >= off) ? s[t - off] : 0;
        __syncthreads();
        s[t] += x;
        __syncthreads();
    }
    if (t < NBLK) histM[(size_t)t * MAXD + dg] = s[t] - v;
    if (t == 255) totals[dg] = s[255];
}

// ---- B2: exclusive scan of digit totals -> coarse bucket bases ------------
__global__ __launch_bounds__(512) void scan_base_k(const int* __restrict__ totals,
                                                   int* __restrict__ cb, int ND) {
    __shared__ int s[512];
    const int t = threadIdx.x;
    int v = (t < ND) ? totals[t] : 0;
    s[t] = v;
    __syncthreads();
    for (int off = 1; off < 512; off <<= 1) {
        int x = (t >= off) ? s[t - off] : 0;
        __syncthreads();
        s[t] += x;
        __syncthreads();
    }
    if (t < ND) cb[t] = s[t] - v;
    if (t == 511) cb[ND] = s[511];  // = E
}

// ---- fp32 vector GEMM body (layer 1 only, fused with CSR build) -----------
template <int K, int OUT>
__device__ __forceinline__ void gemm_body(const float* __restrict__ H,
                                          const float* __restrict__ W,
                                          float* __restrict__ Tout, int n, int bx) {
    constexpr int TX  = OUT / 4;
    constexpr int TY  = 256 / TX;
    constexpr int BM  = TY * 4;
    constexpr int BK  = 32;
    constexpr int PAD = 4;

    __shared__ float At[BK][BM + PAD];
    __shared__ float Ws[BK][OUT];

    const int t    = threadIdx.x;
    const int cx   = t % TX;
    const int ry   = t / TX;
    const int row0 = bx * BM;

    float acc[4][4] = {{0.f}};
    const int arow = t >> 3;
    const int af4  = t & 7;

    for (int k0 = 0; k0 < K; k0 += BK) {
#pragma unroll
        for (int p = 0; p < BM / 32; ++p) {
            int r  = arow + p * 32;
            int gr = row0 + r;
            int grc = gr < n ? gr : n - 1;
            float4 v = *reinterpret_cast<const float4*>(
                H + (size_t)grc * K + k0 + af4 * 4);
            At[af4 * 4 + 0][r] = v.x;
            At[af4 * 4 + 1][r] = v.y;
            At[af4 * 4 + 2][r] = v.z;
            At[af4 * 4 + 3][r] = v.w;
        }
#pragma unroll
        for (int p = 0; p < (BK * OUT) / 1024; ++p) {
            int idx = t + p * 256;
            int wk  = idx / (OUT / 4);
            int wf  = idx % (OUT / 4);
            float4 v = *reinterpret_cast<const float4*>(
                W + (size_t)(k0 + wk) * OUT + wf * 4);
            *reinterpret_cast<float4*>(&Ws[wk][wf * 4]) = v;
        }
        __syncthreads();
#pragma unroll
        for (int k = 0; k < BK; ++k) {
            float4 a = *reinterpret_cast<const float4*>(&At[k][ry * 4]);
            float4 w = *reinterpret_cast<const float4*>(&Ws[k][cx * 4]);
            acc[0][0] = fmaf(a.x, w.x, acc[0][0]);
            acc[0][1] = fmaf(a.x, w.y, acc[0][1]);
            acc[0][2] = fmaf(a.x, w.z, acc[0][2]);
            acc[0][3] = fmaf(a.x, w.w, acc[0][3]);
            acc[1][0] = fmaf(a.y, w.x, acc[1][0]);
            acc[1][1] = fmaf(a.y, w.y, acc[1][1]);
            acc[1][2] = fmaf(a.y, w.z, acc[1][2]);
            acc[1][3] = fmaf(a.y, w.w, acc[1][3]);
            acc[2][0] = fmaf(a.z, w.x, acc[2][0]);
            acc[2][1] = fmaf(a.z, w.y, acc[2][1]);
            acc[2][2] = fmaf(a.z, w.z, acc[2][2]);
            acc[2][3] = fmaf(a.z, w.w, acc[2][3]);
            acc[3][0] = fmaf(a.w, w.x, acc[3][0]);
            acc[3][1] = fmaf(a.w, w.y, acc[3][1]);
            acc[3][2] = fmaf(a.w, w.z, acc[3][2]);
            acc[3][3] = fmaf(a.w, w.w, acc[3][3]);
        }
        __syncthreads();
    }
#pragma unroll
    for (int i = 0; i < 4; ++i) {
        int gr = row0 + ry * 4 + i;
        if (gr < n) {
            float4 v = make_float4(acc[i][0], acc[i][1], acc[i][2], acc[i][3]);
            *reinterpret_cast<float4*>(Tout + (size_t)gr * OUT + cx * 4) = v;
        }
    }
}

// ---- pack scatter: one hist chunk per block, exact LDS cursors ------------
__device__ __forceinline__ void pack_body(const int* __restrict__ ei,
                                          const int* __restrict__ histM,
                                          const int* __restrict__ cb,
                                          int* __restrict__ packed,
                                          int E, int ND, int b) {
    __shared__ int cur[MAXD];
    const int tid = threadIdx.x;
    for (int t = tid; t < ND; t += 256)
        cur[t] = cb[t] + histM[(size_t)b * MAXD + t];
    __syncthreads();
    const int base = b * EB;
    for (int it = 0; it < EB / 256; it += 4) {
        int s[4], d[4]; bool ok[4];
#pragma unroll
        for (int u = 0; u < 4; ++u) {
            int e = base + (it + u) * 256 + tid;
            ok[u] = e < E;
            if (ok[u]) { s[u] = ei[e]; d[u] = ei[E + e]; }
        }
#pragma unroll
        for (int u = 0; u < 4; ++u) {
            if (ok[u]) {
                int pos = atomicAdd(&cur[d[u] >> 8], 1);
                packed[pos] = (s[u] << 8) | (d[u] & 255);
            }
        }
    }
}

// Fused: hist + first slice of layer-1 GEMM.
__global__ __launch_bounds__(256) void hist_gemm1_k(
    const int* __restrict__ ei, int* __restrict__ histM, int E,
    const float* __restrict__ x, const float* __restrict__ W1,
    float* __restrict__ T1, int n, int NH) {
    const int bx = blockIdx.x;
    if (bx < NH) hist_body(ei, histM, E, bx);
    else         gemm_body<128, 64>(x, W1, T1, n, bx - NH);
}

// Fused: pack + remaining layer-1 GEMM blocks.
__global__ __launch_bounds__(256) void pack_gemm1_k(
    const int* __restrict__ ei, const int* __restrict__ histM,
    const int* __restrict__ cb, int* __restrict__ packed,
    const float* __restrict__ x, const float* __restrict__ W1,
    float* __restrict__ T1, int n, int E, int ND, int NPB, int G1) {
    const int bx = blockIdx.x;
    if (bx < NPB) pack_body(ei, histM, cb, packed, E, ND, bx);
    else          gemm_body<128, 64>(x, W1, T1, n, G1 + bx - NPB);
}

// ---- per-coarse-bucket finalize (padded x8 CSR, dinv, col, T1 scale+fp16) -
__global__ __launch_bounds__(256) void bucket_k(const int* __restrict__ packed,
                                                const int* __restrict__ cb,
                                                int* __restrict__ col,
                                                int* __restrict__ rowptr,
                                                int* __restrict__ counts,
                                                float* __restrict__ dinv,
                                                const float* __restrict__ Traw,
                                                __half* __restrict__ Th, int n) {
    __shared__ int   hist[256];
    __shared__ int   pref[256];
    __shared__ int   cur[256];
    __shared__ float dinv_l[256];

    const int tid   = threadIdx.x;
    const int dg    = blockIdx.x;
    const int base  = cb[dg];
    const int m     = cb[dg + 1] - base;
    const int basep = base + dg * PADSLACK;

    hist[tid] = 0;
    __syncthreads();
    for (int k0 = 0; k0 < m; k0 += 1024) {
        int v[4]; bool ok[4];
#pragma unroll
        for (int u = 0; u < 4; ++u) {
            int k = k0 + u * 256 + tid;
            ok[u] = k < m;
            v[u] = ok[u] ? packed[base + k] : 0;
        }
#pragma unroll
        for (int u = 0; u < 4; ++u)
            if (ok[u]) atomicAdd(&hist[v[u] & 255], 1);
    }
    __syncthreads();
    const int deg   = hist[tid];
    const int cnt_p = (deg + 8) & ~7;  // >= deg+1, multiple of 8
    pref[tid] = cnt_p;
    __syncthreads();
    for (int off = 1; off < 256; off <<= 1) {
        int x = (tid >= off) ? pref[tid - off] : 0;
        __syncthreads();
        pref[tid] += x;
        __syncthreads();
    }
    const int rp = basep + pref[tid] - cnt_p;
    const float di = rsqrtf((float)(deg + 1));
    dinv_l[tid] = di;
    cur[tid] = rp + 1;
    const int d = dg * 256 + tid;
    if (d < n) {
        counts[d] = cnt_p;
        dinv[d]   = di;
        rowptr[d] = rp;
        col[rp]   = d;                                          // self slot
        for (int k = deg + 1; k < cnt_p; ++k) col[rp + k] = n;  // sentinel pads
    }
    __syncthreads();
    for (int k0 = 0; k0 < m; k0 += 1024) {
        int v[4]; bool ok[4];
#pragma unroll
        for (int u = 0; u < 4; ++u) {
            int k = k0 + u * 256 + tid;
            ok[u] = k < m;
            v[u] = ok[u] ? packed[base + k] : 0;
        }
#pragma unroll
        for (int u = 0; u < 4; ++u) {
            if (ok[u]) {
                int pos = atomicAdd(&cur[v[u] & 255], 1);
                col[pos] = v[u] >> 8;
            }
        }
    }
    const int r0 = dg * 256;
#pragma unroll 4
    for (int it = 0; it < 16; ++it) {
        int idx = it * 256 + tid;
        int rl  = idx >> 4;
        int r   = r0 + rl;
        if (r < n) {
            float4 v = reinterpret_cast<const float4*>(Traw)[(size_t)r * 16 + (idx & 15)];
            float dd = dinv_l[rl];
            union { ushort4 u; __half h[4]; } pk;
            pk.h[0] = __float2half_rn(v.x * dd);
            pk.h[1] = __float2half_rn(v.y * dd);
            pk.h[2] = __float2half_rn(v.z * dd);
            pk.h[3] = __float2half_rn(v.w * dd);
            reinterpret_cast<ushort4*>(Th)[(size_t)r * 16 + (idx & 15)] = pk.u;
        }
    }
    if (dg == 0 && tid < 16) {
        uint2 z; z.x = 0u; z.y = 0u;
        reinterpret_cast<uint2*>(Th)[(size_t)n * 16 + tid] = z;
    }
}

// ---- MFMA fp16 GEMM (layers 2-4): T[r] = fp16(dinv[r] * (H[r] @ W)) -------
// H: n x 64 fp16 (stride 64).  W: 64 x OUT fp32 (cvt to fp16 B-frags, held
// in registers for the whole kernel).  T: table, stride 64.
template <int OUT>  // 64 or 32
__global__ __launch_bounds__(256) void gemm_mfma_k(
    const _Float16* __restrict__ H, const float* __restrict__ W,
    const float* __restrict__ dinv, _Float16* __restrict__ T, int n) {
    constexpr int NT = OUT / 16;        // N tiles: 4 or 2
    const int lane = threadIdx.x & 63;
    const int m16  = lane & 15;
    const int quad = lane >> 4;         // 0..3
    const int wid  = (blockIdx.x * blockDim.x + threadIdx.x) >> 6;
    const int nw   = (gridDim.x * blockDim.x) >> 6;

    // B-frags: B[k = h*32 + quad*8 + j][n = t*16 + m16]
    half8v bfrag[NT][2];
#pragma unroll
    for (int t = 0; t < NT; ++t)
#pragma unroll
        for (int h = 0; h < 2; ++h)
#pragma unroll
            for (int j = 0; j < 8; ++j)
                bfrag[t][h][j] = (_Float16)W[(size_t)(h * 32 + quad * 8 + j) * OUT
                                             + t * 16 + m16];

    const int nblk = (n + 15) >> 4;
    for (int rb = wid; rb < nblk; rb += nw) {
        const int r0 = rb * 16;
        int ra = r0 + m16; if (ra >= n) ra = n - 1;
        const half8v* hrow = reinterpret_cast<const half8v*>(H + (size_t)ra * 64);
        half8v a0 = hrow[quad];       // A[m=lane&15][k=quad*8+j]
        half8v a1 = hrow[4 + quad];   // k += 32

        float4v dfr[NT];
#pragma unroll
        for (int t = 0; t < NT; ++t) {
            float4v z = {0.f, 0.f, 0.f, 0.f};
            z = __builtin_amdgcn_mfma_f32_16x16x32_f16(a0, bfrag[t][0], z, 0, 0, 0);
            z = __builtin_amdgcn_mfma_f32_16x16x32_f16(a1, bfrag[t][1], z, 0, 0, 0);
            dfr[t] = z;
        }
        // D: row = r0 + quad*4 + reg, col = t*16 + m16
#pragma unroll
        for (int reg = 0; reg < 4; ++reg) {
            int row = r0 + quad * 4 + reg;
            if (row < n) {
                float di = dinv[row];
#pragma unroll
                for (int t = 0; t < NT; ++t)
                    T[(size_t)row * 64 + t * 16 + m16] =
                        (_Float16)(dfr[t][reg] * di);
            }
        }
    }
}

// One wave per node, maskless padded CSR (x8, slot0=self, pads->sentinel).
// Lane loads uint2 (4 fp16 ch); v_dot2_f32_f16 accumulate.  Non-head layers
// write fp16 H for the MFMA GEMM; head layer writes fp32 out.
template <int LR, bool FUSE_HEAD>   // LR=16: 64ch; LR=8: 32ch
__global__ __launch_bounds__(256) void agg_k(const __half* __restrict__ T,
                                             const int* __restrict__ rowptr,
                                             const int* __restrict__ counts,
                                             const int* __restrict__ col,
                                             const float* __restrict__ dinv,
                                             const float* __restrict__ bias,
                                             void* __restrict__ O, int n,
                                             const float* __restrict__ Wh,
                                             const float* __restrict__ bh) {
    constexpr int NSW = 64 / LR;     // 4 / 8
    constexpr int U   = 16 / NSW;    // 4 / 2  (full step)
    constexpr int UH  = U / 2;       // 2 / 1  (half step)
    const int lane = threadIdx.x & 63;
    const int q    = lane % LR;
    const int sw   = lane / LR;
    const int i = (blockIdx.x * blockDim.x + threadIdx.x) >> 6;
    if (i >= n) return;

    const half2v s10 = {(_Float16)1.f, (_Float16)0.f};
    const half2v s01 = {(_Float16)0.f, (_Float16)1.f};

    const int start = rowptr[i];
    const int cnt   = counts[i];     // padded: multiple of 8, includes self
    const uint2* __restrict__ T2 = reinterpret_cast<const uint2*>(T);

    float4 acc = make_float4(0.f, 0.f, 0.f, 0.f);
    for (int base = 0; base < cnt; base += 64) {
        const int m = min(64, cnt - base);       // multiple of 8
        int c_l = col[start + base + lane];      // unconditional (slack-safe)
        int jg = 0;
        for (; jg + 16 <= m; jg += 16) {
            int cc[U]; uint2 v[U];
#pragma unroll
            for (int u = 0; u < U; ++u)
                cc[u] = __shfl(c_l, jg + u * NSW + sw, 64);
#pragma unroll
            for (int u = 0; u < U; ++u) v[u] = T2[(size_t)cc[u] * 16 + q];
#pragma unroll
            for (int u = 0; u < U; ++u) {
                union { uint2 uu; half2v h[2]; } cv; cv.uu = v[u];
                acc.x = fdot2f(cv.h[0], s10, acc.x);
                acc.y = fdot2f(cv.h[0], s01, acc.y);
                acc.z = fdot2f(cv.h[1], s10, acc.z);
                acc.w = fdot2f(cv.h[1], s01, acc.w);
            }
        }
        if (jg < m) {  // exactly 8 edges left; uniform across the wave
            int cc[UH]; uint2 v[UH];
#pragma unroll
            for (int u = 0; u < UH; ++u)
                cc[u] = __shfl(c_l, jg + u * NSW + sw, 64);
#pragma unroll
            for (int u = 0; u < UH; ++u) v[u] = T2[(size_t)cc[u] * 16 + q];
#pragma unroll
            for (int u = 0; u < UH; ++u) {
                union { uint2 uu; half2v h[2]; } cv; cv.uu = v[u];
                acc.x = fdot2f(cv.h[0], s10, acc.x);
                acc.y = fdot2f(cv.h[0], s01, acc.y);
                acc.z = fdot2f(cv.h[1], s10, acc.z);
                acc.w = fdot2f(cv.h[1], s01, acc.w);
            }
        }
    }
#pragma unroll
    for (int off = LR; off < 64; off <<= 1) {
        acc.x += __shfl_xor(acc.x, off, 64);
        acc.y += __shfl_xor(acc.y, off, 64);
        acc.z += __shfl_xor(acc.z, off, 64);
        acc.w += __shfl_xor(acc.w, off, 64);
    }
    const float di = dinv[i];
    const float4 b4 = reinterpret_cast<const float4*>(bias)[q];
    float4 h;
    h.x = fmaxf(fmaf(di, acc.x, b4.x), 0.f);
    h.y = fmaxf(fmaf(di, acc.y, b4.y), 0.f);
    h.z = fmaxf(fmaf(di, acc.z, b4.z), 0.f);
    h.w = fmaxf(fmaf(di, acc.w, b4.w), 0.f);
    if constexpr (!FUSE_HEAD) {
        if (sw == 0) {  // fp16 H for the MFMA GEMM
            union { ushort4 u; __half hh[4]; } pk;
            pk.hh[0] = __float2half_rn(h.x);
            pk.hh[1] = __float2half_rn(h.y);
            pk.hh[2] = __float2half_rn(h.z);
            pk.hh[3] = __float2half_rn(h.w);
            ushort* base_p = (ushort*)O + (size_t)i * 64;
            *reinterpret_cast<ushort4*>(base_p + 4 * q) = pk.u;
        }
    } else {
        float* Of = (float*)O;
        float p0 = h.x * Wh[(4 * q + 0) * 3 + 0];
        float p1 = h.x * Wh[(4 * q + 0) * 3 + 1];
        float p2 = h.x * Wh[(4 * q + 0) * 3 + 2];
        p0 = fmaf(h.y, Wh[(4 * q + 1) * 3 + 0], p0);
        p1 = fmaf(h.y, Wh[(4 * q + 1) * 3 + 1], p1);
        p2 = fmaf(h.y, Wh[(4 * q + 1) * 3 + 2], p2);
        p0 = fmaf(h.z, Wh[(4 * q + 2) * 3 + 0], p0);
        p1 = fmaf(h.z, Wh[(4 * q + 2) * 3 + 1], p1);
        p2 = fmaf(h.z, Wh[(4 * q + 2) * 3 + 2], p2);
        p0 = fmaf(h.w, Wh[(4 * q + 3) * 3 + 0], p0);
        p1 = fmaf(h.w, Wh[(4 * q + 3) * 3 + 1], p1);
        p2 = fmaf(h.w, Wh[(4 * q + 3) * 3 + 2], p2);
#pragma unroll
        for (int off = 1; off < LR; off <<= 1) {
            p0 += __shfl_xor(p0, off, 64);
            p1 += __shfl_xor(p1, off, 64);
            p2 += __shfl_xor(p2, off, 64);
        }
        if (lane == 0) {
            Of[(size_t)i * 3 + 0] = p0 + bh[0];
            Of[(size_t)i * 3 + 1] = p1 + bh[1];
            Of[(size_t)i * 3 + 2] = p2 + bh[2];
        }
    }
}

extern "C" void kernel_launch(void* const* d_in, const int* in_sizes, int n_in,
                              void* d_out, int out_size, void* d_ws, size_t ws_size,
                              hipStream_t stream) {
    const float* x  = (const float*)d_in[0];
    const int*   ei = (const int*)d_in[1];
    const float* W1 = (const float*)d_in[2];
    const float* b1 = (const float*)d_in[3];
    const float* W2 = (const float*)d_in[4];
    const float* b2 = (const float*)d_in[5];
    const float* W3 = (const float*)d_in[6];
    const float* b3 = (const float*)d_in[7];
    const float* W4 = (const float*)d_in[8];
    const float* b4 = (const float*)d_in[9];
    const float* Wh = (const float*)d_in[10];
    const float* bh = (const float*)d_in[11];
    float* out = (float*)d_out;

    const int n = in_sizes[0] / 128;
    const int E = in_sizes[1] / 2;
    const int ND   = (n + 255) / 256;    // coarse digits (<= MAXD)
    const int NBLK = (E + EB - 1) / EB;  // hist/pack blocks (<= 256)

    char* ws = (char*)d_ws;
    auto alloc = [&](size_t bytes) {
        char* p = ws;
        ws += (bytes + 255) & ~(size_t)255;
        return p;
    };
    int*    histM  = (int*)alloc((size_t)NBLK * MAXD * 4);
    int*    totals = (int*)alloc((size_t)MAXD * 4);
    int*    cbA    = (int*)alloc((size_t)(MAXD + 1) * 4);
    int*    packed = (int*)alloc((size_t)E * 4);
    int*    col    = (int*)alloc(((size_t)E + (size_t)ND * PADSLACK + 256) * 4);
    int*    rowptr = (int*)alloc((size_t)n * 4);
    int*    counts = (int*)alloc((size_t)n * 4);
    float*  dinv   = (float*)alloc((size_t)n * 4);
    float*  bufF   = (float*)alloc((size_t)n * 64 * 4);         // raw T1 fp32
    __half* bufH   = (__half*)alloc(((size_t)n + 1) * 64 * 2);  // fp16 table + sentinel
    __half* bufG   = (__half*)bufF;  // fp16 H (aliases bufF; T1 dead post-bucket)

    dim3 blk(256);
    const int G  = (n + 63) / 64;   // layer-1 gemm blocks
    const int G1 = G / 3;           // slice fused with hist
    const int G2 = G - G1;          // slice fused with pack
    const int agg_blocks = (n + 3) / 4;
    const int mfma_blocks = 640;    // 2560 waves, grid-stride over 16-row blocks

    // ---- atomic-free CSR build + layer-1 transform ----
    hist_gemm1_k<<<dim3(NBLK + G1), blk, 0, stream>>>(ei, histM, E, x, W1, bufF, n, NBLK);
    scan_digits_k<<<dim3(ND), blk, 0, stream>>>(histM, totals, NBLK);
    scan_base_k<<<dim3(1), dim3(512), 0, stream>>>(totals, cbA, ND);
    pack_gemm1_k<<<dim3(NBLK + G2), blk, 0, stream>>>(ei, histM, cbA, packed,
                                                      x, W1, bufF, n, E, ND, NBLK, G1);
    bucket_k<<<dim3(ND), blk, 0, stream>>>(packed, cbA, col, rowptr, counts,
                                           dinv, bufF, bufH, n);
    // ---- Layer 1 agg (writes fp16 H into bufG) ----
    agg_k<16, false><<<dim3(agg_blocks), blk, 0, stream>>>(
        bufH, rowptr, counts, col, dinv, b1, bufG, n, nullptr, nullptr);
    // ---- Layer 2 ----
    gemm_mfma_k<64><<<dim3(mfma_blocks), blk, 0, stream>>>(
        (const _Float16*)bufG, W2, dinv, (_Float16*)bufH, n);
    agg_k<16, false><<<dim3(agg_blocks), blk, 0, stream>>>(
        bufH, rowptr, counts, col, dinv, b2, bufG, n, nullptr, nullptr);
    // ---- Layer 3 ----
    gemm_mfma_k<64><<<dim3(mfma_blocks), blk, 0, stream>>>(
        (const _Float16*)bufG, W3, dinv, (_Float16*)bufH, n);
    agg_k<16, false><<<dim3(agg_blocks), blk, 0, stream>>>(
        bufH, rowptr, counts, col, dinv, b3, bufG, n, nullptr, nullptr);
    // ---- Layer 4 (+ fused head) ----
    gemm_mfma_k<32><<<dim3(mfma_blocks), blk, 0, stream>>>(
        (const _Float16*)bufG, W4, dinv, (_Float16*)bufH, n);
    agg_k<8, true><<<dim3(agg_blocks), blk, 0, stream>>>(
        bufH, rowptr, counts, col, dinv, b4, out, n, Wh, bh);
}

// Round 11
// 363.878 us; speedup vs baseline: 3.3316x; 1.0051x over previous
//
#include <hip/hip_runtime.h>
#include <hip/hip_bf16.h>
#include <hip/hip_fp16.h>
#include <cstdint>

// ---------------------------------------------------------------------------
// SPDE GCN: 4x GCNConv + linear head, fp32 in/out.
// R3-R10: uint2 multi-edge MLP agg; fp16 feature table; dinv pre/post scaling;
//   atomic-free MSD bucket-sort CSR fused with layer-1 fp32 GEMM; maskless
//   x8-padded CSR w/ sentinel row; MFMA fp16 GEMM for layers 2-4; head fused.
// R11: (a) agg gathers fully batched: ONE col load + ALL row gathers issued
//          before any consumption (wave-uniform g<nb guards between loads
//          don't force waits) -> 2 dependent memory rounds/wave, was 3.
//          R10 showed fdot2 neutral => agg is round-latency-bound, not VALU.
//      (b) scan_base_k deleted: pack/bucket compute digit bases locally from
//          totals via LDS scan (one fewer serial launch).
// ---------------------------------------------------------------------------

#define MAXD 512       // max coarse digits (n <= 131072)
#define EB   8192      // edges per hist/pack chunk
#define PADSLACK 2048  // max per-bucket padding (256 nodes * 8)

typedef _Float16 half8v __attribute__((ext_vector_type(8)));
typedef _Float16 half2v __attribute__((ext_vector_type(2)));
typedef float    float4v __attribute__((ext_vector_type(4)));

#if defined(__has_builtin)
#if __has_builtin(__builtin_amdgcn_fdot2)
#define HAVE_FDOT2 1
#endif
#endif

__device__ __forceinline__ float fdot2f(half2v a, half2v b, float c) {
#ifdef HAVE_FDOT2
    return __builtin_amdgcn_fdot2(a, b, c, false);
#else
    return c + (float)a[0] * (float)b[0] + (float)a[1] * (float)b[1];
#endif
}

// ---- LDS exclusive scan of totals[0..MAXD) with 256 threads ---------------
// Writes cbs[0..MAXD) = exclusive prefix.  Caller syncs afterwards implicitly
// (function ends with __syncthreads()).
__device__ __forceinline__ void digit_base_scan(const int* __restrict__ totals,
                                                int ND, int* pairs, int* cbs) {
    const int t = threadIdx.x;
    const int e0 = 2 * t, e1 = 2 * t + 1;
    int v0 = (e0 < ND) ? totals[e0] : 0;
    int v1 = (e1 < ND) ? totals[e1] : 0;
    pairs[t] = v0 + v1;
    __syncthreads();
    for (int off = 1; off < 256; off <<= 1) {
        int x = (t >= off) ? pairs[t - off] : 0;
        __syncthreads();
        pairs[t] += x;
        __syncthreads();
    }
    int ep = pairs[t] - v0 - v1;  // exclusive pair prefix
    cbs[e0] = ep;
    cbs[e1] = ep + v0;
    __syncthreads();
}

// ---- hist body: coarse histogram (block-major histM[b][dg]) ---------------
__device__ __forceinline__ void hist_body(const int* __restrict__ ei,
                                          int* __restrict__ histM, int E, int b) {
    __shared__ int hist[MAXD];
    const int tid = threadIdx.x;
    hist[tid] = 0; hist[tid + 256] = 0;
    __syncthreads();
    const int base = b * EB;
#pragma unroll 2
    for (int it = 0; it < EB / 256; it += 4) {
        int d[4]; bool ok[4];
#pragma unroll
        for (int u = 0; u < 4; ++u) {
            int e = base + (it + u) * 256 + tid;
            ok[u] = e < E;
            d[u] = ok[u] ? ei[E + e] : 0;
        }
#pragma unroll
        for (int u = 0; u < 4; ++u)
            if (ok[u]) atomicAdd(&hist[d[u] >> 8], 1);
    }
    __syncthreads();
    histM[(size_t)b * MAXD + tid] = hist[tid];
    histM[(size_t)b * MAXD + tid + 256] = hist[tid + 256];
}

// ---- per-digit exclusive scan over chunks (in place) + digit totals -------
__global__ __launch_bounds__(256) void scan_digits_k(int* __restrict__ histM,
                                                     int* __restrict__ totals,
                                                     int NBLK) {
    __shared__ int s[256];
    const int t = threadIdx.x, dg = blockIdx.x;
    int v = (t < NBLK) ? histM[(size_t)t * MAXD + dg] : 0;
    s[t] = v;
    __syncthreads();
    for (int off = 1; off < 256; off <<= 1) {
        int x = (t >= off) ? s[t - off] : 0;
        __syncthreads();
        s[t] += x;
        __syncthreads();
    }
    if (t < NBLK) histM[(size_t)t * MAXD + dg] = s[t] - v;
    if (t == 255) totals[dg] = s[255];
}

// ---- fp32 vector GEMM body (layer 1 only, fused with CSR build) -----------
template <int K, int OUT>
__device__ __forceinline__ void gemm_body(const float* __restrict__ H,
                                          const float* __restrict__ W,
                                          float* __restrict__ Tout, int n, int bx) {
    constexpr int TX  = OUT / 4;
    constexpr int TY  = 256 / TX;
    constexpr int BM  = TY * 4;
    constexpr int BK  = 32;
    constexpr int PAD = 4;

    __shared__ float At[BK][BM + PAD];
    __shared__ float Ws[BK][OUT];

    const int t    = threadIdx.x;
    const int cx   = t % TX;
    const int ry   = t / TX;
    const int row0 = bx * BM;

    float acc[4][4] = {{0.f}};
    const int arow = t >> 3;
    const int af4  = t & 7;

    for (int k0 = 0; k0 < K; k0 += BK) {
#pragma unroll
        for (int p = 0; p < BM / 32; ++p) {
            int r  = arow + p * 32;
            int gr = row0 + r;
            int grc = gr < n ? gr : n - 1;
            float4 v = *reinterpret_cast<const float4*>(
                H + (size_t)grc * K + k0 + af4 * 4);
            At[af4 * 4 + 0][r] = v.x;
            At[af4 * 4 + 1][r] = v.y;
            At[af4 * 4 + 2][r] = v.z;
            At[af4 * 4 + 3][r] = v.w;
        }
#pragma unroll
        for (int p = 0; p < (BK * OUT) / 1024; ++p) {
            int idx = t + p * 256;
            int wk  = idx / (OUT / 4);
            int wf  = idx % (OUT / 4);
            float4 v = *reinterpret_cast<const float4*>(
                W + (size_t)(k0 + wk) * OUT + wf * 4);
            *reinterpret_cast<float4*>(&Ws[wk][wf * 4]) = v;
        }
        __syncthreads();
#pragma unroll
        for (int k = 0; k < BK; ++k) {
            float4 a = *reinterpret_cast<const float4*>(&At[k][ry * 4]);
            float4 w = *reinterpret_cast<const float4*>(&Ws[k][cx * 4]);
            acc[0][0] = fmaf(a.x, w.x, acc[0][0]);
            acc[0][1] = fmaf(a.x, w.y, acc[0][1]);
            acc[0][2] = fmaf(a.x, w.z, acc[0][2]);
            acc[0][3] = fmaf(a.x, w.w, acc[0][3]);
            acc[1][0] = fmaf(a.y, w.x, acc[1][0]);
            acc[1][1] = fmaf(a.y, w.y, acc[1][1]);
            acc[1][2] = fmaf(a.y, w.z, acc[1][2]);
            acc[1][3] = fmaf(a.y, w.w, acc[1][3]);
            acc[2][0] = fmaf(a.z, w.x, acc[2][0]);
            acc[2][1] = fmaf(a.z, w.y, acc[2][1]);
            acc[2][2] = fmaf(a.z, w.z, acc[2][2]);
            acc[2][3] = fmaf(a.z, w.w, acc[2][3]);
            acc[3][0] = fmaf(a.w, w.x, acc[3][0]);
            acc[3][1] = fmaf(a.w, w.y, acc[3][1]);
            acc[3][2] = fmaf(a.w, w.z, acc[3][2]);
            acc[3][3] = fmaf(a.w, w.w, acc[3][3]);
        }
        __syncthreads();
    }
#pragma unroll
    for (int i = 0; i < 4; ++i) {
        int gr = row0 + ry * 4 + i;
        if (gr < n) {
            float4 v = make_float4(acc[i][0], acc[i][1], acc[i][2], acc[i][3]);
            *reinterpret_cast<float4*>(Tout + (size_t)gr * OUT + cx * 4) = v;
        }
    }
}

// ---- pack scatter: one hist chunk per block; digit bases from local scan --
__device__ __forceinline__ void pack_body(const int* __restrict__ ei,
                                          const int* __restrict__ histM,
                                          const int* __restrict__ totals,
                                          int* __restrict__ packed,
                                          int E, int ND, int b) {
    __shared__ int pairs[256];
    __shared__ int cbs[MAXD];
    __shared__ int cur[MAXD];
    const int tid = threadIdx.x;
    digit_base_scan(totals, ND, pairs, cbs);
    for (int t = tid; t < ND; t += 256)
        cur[t] = cbs[t] + histM[(size_t)b * MAXD + t];
    __syncthreads();
    const int base = b * EB;
    for (int it = 0; it < EB / 256; it += 4) {
        int s[4], d[4]; bool ok[4];
#pragma unroll
        for (int u = 0; u < 4; ++u) {
            int e = base + (it + u) * 256 + tid;
            ok[u] = e < E;
            if (ok[u]) { s[u] = ei[e]; d[u] = ei[E + e]; }
        }
#pragma unroll
        for (int u = 0; u < 4; ++u) {
            if (ok[u]) {
                int pos = atomicAdd(&cur[d[u] >> 8], 1);
                packed[pos] = (s[u] << 8) | (d[u] & 255);
            }
        }
    }
}

// Fused: hist + first slice of layer-1 GEMM.
__global__ __launch_bounds__(256) void hist_gemm1_k(
    const int* __restrict__ ei, int* __restrict__ histM, int E,
    const float* __restrict__ x, const float* __restrict__ W1,
    float* __restrict__ T1, int n, int NH) {
    const int bx = blockIdx.x;
    if (bx < NH) hist_body(ei, histM, E, bx);
    else         gemm_body<128, 64>(x, W1, T1, n, bx - NH);
}

// Fused: pack + remaining layer-1 GEMM blocks.
__global__ __launch_bounds__(256) void pack_gemm1_k(
    const int* __restrict__ ei, const int* __restrict__ histM,
    const int* __restrict__ totals, int* __restrict__ packed,
    const float* __restrict__ x, const float* __restrict__ W1,
    float* __restrict__ T1, int n, int E, int ND, int NPB, int G1) {
    const int bx = blockIdx.x;
    if (bx < NPB) pack_body(ei, histM, totals, packed, E, ND, bx);
    else          gemm_body<128, 64>(x, W1, T1, n, G1 + bx - NPB);
}

// ---- per-coarse-bucket finalize (padded x8 CSR, dinv, col, T1 scale+fp16) -
__global__ __launch_bounds__(256) void bucket_k(const int* __restrict__ packed,
                                                const int* __restrict__ totals,
                                                int ND,
                                                int* __restrict__ col,
                                                int* __restrict__ rowptr,
                                                int* __restrict__ counts,
                                                float* __restrict__ dinv,
                                                const float* __restrict__ Traw,
                                                __half* __restrict__ Th, int n) {
    __shared__ int   pairs[256];
    __shared__ int   cbs[MAXD];
    __shared__ int   hist[256];
    __shared__ int   pref[256];
    __shared__ int   cur[256];
    __shared__ float dinv_l[256];

    const int tid = threadIdx.x;
    const int dg  = blockIdx.x;
    digit_base_scan(totals, ND, pairs, cbs);
    const int base  = cbs[dg];
    const int m     = totals[dg];
    const int basep = base + dg * PADSLACK;

    hist[tid] = 0;
    __syncthreads();
    for (int k0 = 0; k0 < m; k0 += 1024) {
        int v[4]; bool ok[4];
#pragma unroll
        for (int u = 0; u < 4; ++u) {
            int k = k0 + u * 256 + tid;
            ok[u] = k < m;
            v[u] = ok[u] ? packed[base + k] : 0;
        }
#pragma unroll
        for (int u = 0; u < 4; ++u)
            if (ok[u]) atomicAdd(&hist[v[u] & 255], 1);
    }
    __syncthreads();
    const int deg   = hist[tid];
    const int cnt_p = (deg + 8) & ~7;  // >= deg+1, multiple of 8
    pref[tid] = cnt_p;
    __syncthreads();
    for (int off = 1; off < 256; off <<= 1) {
        int x = (tid >= off) ? pref[tid - off] : 0;
        __syncthreads();
        pref[tid] += x;
        __syncthreads();
    }
    const int rp = basep + pref[tid] - cnt_p;
    const float di = rsqrtf((float)(deg + 1));
    dinv_l[tid] = di;
    cur[tid] = rp + 1;
    const int d = dg * 256 + tid;
    if (d < n) {
        counts[d] = cnt_p;
        dinv[d]   = di;
        rowptr[d] = rp;
        col[rp]   = d;                                          // self slot
        for (int k = deg + 1; k < cnt_p; ++k) col[rp + k] = n;  // sentinel pads
    }
    __syncthreads();
    for (int k0 = 0; k0 < m; k0 += 1024) {
        int v[4]; bool ok[4];
#pragma unroll
        for (int u = 0; u < 4; ++u) {
            int k = k0 + u * 256 + tid;
            ok[u] = k < m;
            v[u] = ok[u] ? packed[base + k] : 0;
        }
#pragma unroll
        for (int u = 0; u < 4; ++u) {
            if (ok[u]) {
                int pos = atomicAdd(&cur[v[u] & 255], 1);
                col[pos] = v[u] >> 8;
            }
        }
    }
    const int r0 = dg * 256;
#pragma unroll 4
    for (int it = 0; it < 16; ++it) {
        int idx = it * 256 + tid;
        int rl  = idx >> 4;
        int r   = r0 + rl;
        if (r < n) {
            float4 v = reinterpret_cast<const float4*>(Traw)[(size_t)r * 16 + (idx & 15)];
            float dd = dinv_l[rl];
            union { ushort4 u; __half h[4]; } pk;
            pk.h[0] = __float2half_rn(v.x * dd);
            pk.h[1] = __float2half_rn(v.y * dd);
            pk.h[2] = __float2half_rn(v.z * dd);
            pk.h[3] = __float2half_rn(v.w * dd);
            reinterpret_cast<ushort4*>(Th)[(size_t)r * 16 + (idx & 15)] = pk.u;
        }
    }
    if (dg == 0 && tid < 16) {
        uint2 z; z.x = 0u; z.y = 0u;
        reinterpret_cast<uint2*>(Th)[(size_t)n * 16 + tid] = z;
    }
}

// ---- MFMA fp16 GEMM (layers 2-4): T[r] = fp16(dinv[r] * (H[r] @ W)) -------
template <int OUT>  // 64 or 32
__global__ __launch_bounds__(256) void gemm_mfma_k(
    const _Float16* __restrict__ H, const float* __restrict__ W,
    const float* __restrict__ dinv, _Float16* __restrict__ T, int n) {
    constexpr int NT = OUT / 16;        // N tiles: 4 or 2
    const int lane = threadIdx.x & 63;
    const int m16  = lane & 15;
    const int quad = lane >> 4;         // 0..3
    const int wid  = (blockIdx.x * blockDim.x + threadIdx.x) >> 6;
    const int nw   = (gridDim.x * blockDim.x) >> 6;

    half8v bfrag[NT][2];
#pragma unroll
    for (int t = 0; t < NT; ++t)
#pragma unroll
        for (int h = 0; h < 2; ++h)
#pragma unroll
            for (int j = 0; j < 8; ++j)
                bfrag[t][h][j] = (_Float16)W[(size_t)(h * 32 + quad * 8 + j) * OUT
                                             + t * 16 + m16];

    const int nblk = (n + 15) >> 4;
    for (int rb = wid; rb < nblk; rb += nw) {
        const int r0 = rb * 16;
        int ra = r0 + m16; if (ra >= n) ra = n - 1;
        const half8v* hrow = reinterpret_cast<const half8v*>(H + (size_t)ra * 64);
        half8v a0 = hrow[quad];       // A[m=lane&15][k=quad*8+j]
        half8v a1 = hrow[4 + quad];   // k += 32

        float4v dfr[NT];
#pragma unroll
        for (int t = 0; t < NT; ++t) {
            float4v z = {0.f, 0.f, 0.f, 0.f};
            z = __builtin_amdgcn_mfma_f32_16x16x32_f16(a0, bfrag[t][0], z, 0, 0, 0);
            z = __builtin_amdgcn_mfma_f32_16x16x32_f16(a1, bfrag[t][1], z, 0, 0, 0);
            dfr[t] = z;
        }
#pragma unroll
        for (int reg = 0; reg < 4; ++reg) {
            int row = r0 + quad * 4 + reg;
            if (row < n) {
                float di = dinv[row];
#pragma unroll
                for (int t = 0; t < NT; ++t)
                    T[(size_t)row * 64 + t * 16 + m16] =
                        (_Float16)(dfr[t][reg] * di);
            }
        }
    }
}

// One wave per node, maskless padded CSR (x8, slot0=self, pads->sentinel).
// R11: ALL gathers for the node issued in one batch (cnt<=64 fast path),
// guarded by wave-uniform g<nb branches -> 2 dependent memory rounds/wave.
template <int LR, bool FUSE_HEAD>   // LR=16: 64ch; LR=8: 32ch
__global__ __launch_bounds__(256) void agg_k(const __half* __restrict__ T,
                                             const int* __restrict__ rowptr,
                                             const int* __restrict__ counts,
                                             const int* __restrict__ col,
                                             const float* __restrict__ dinv,
                                             const float* __restrict__ bias,
                                             void* __restrict__ O, int n,
                                             const float* __restrict__ Wh,
                                             const float* __restrict__ bh) {
    constexpr int NSW = 64 / LR;     // 4 / 8
    constexpr int GPE = 8 / NSW;     // gathers per 8-edge group: 2 / 1
    const int lane = threadIdx.x & 63;
    const int q    = lane % LR;
    const int sw   = lane / LR;
    const int i = (blockIdx.x * blockDim.x + threadIdx.x) >> 6;
    if (i >= n) return;

    const half2v s10 = {(_Float16)1.f, (_Float16)0.f};
    const half2v s01 = {(_Float16)0.f, (_Float16)1.f};

    const int start = rowptr[i];
    const int cnt   = counts[i];     // padded: multiple of 8, includes self
    const uint2* __restrict__ T2 = reinterpret_cast<const uint2*>(T);

    float4 acc = make_float4(0.f, 0.f, 0.f, 0.f);
    if (cnt <= 64) {
        // ---- fast path: one col load, ALL gathers batched ----
        int c_l = col[start + lane];   // slack-safe (col has +256 tail ints)
        const int nb = cnt >> 3;       // 1..8 groups of 8 edges
        uint2 v[8 * GPE];
#pragma unroll
        for (int g = 0; g < 8; ++g) {
            if (g < nb) {
#pragma unroll
                for (int u = 0; u < GPE; ++u) {
                    int cc = __shfl(c_l, g * 8 + u * NSW + sw, 64);
                    v[g * GPE + u] = T2[(size_t)cc * 16 + q];
                }
            }
        }
#pragma unroll
        for (int g = 0; g < 8; ++g) {
            if (g < nb) {
#pragma unroll
                for (int u = 0; u < GPE; ++u) {
                    union { uint2 uu; half2v h[2]; } cv; cv.uu = v[g * GPE + u];
                    acc.x = fdot2f(cv.h[0], s10, acc.x);
                    acc.y = fdot2f(cv.h[0], s01, acc.y);
                    acc.z = fdot2f(cv.h[1], s10, acc.z);
                    acc.w = fdot2f(cv.h[1], s01, acc.w);
                }
            }
        }
    } else {
        // ---- generic fallback (cnt > 64; essentially never taken) ----
        for (int base = 0; base < cnt; base += 64) {
            const int m = min(64, cnt - base);   // multiple of 8
            int c_l = col[start + base + lane];
            for (int jg = 0; jg < m; jg += 8) {
                int cc[GPE]; uint2 v[GPE];
#pragma unroll
                for (int u = 0; u < GPE; ++u)
                    cc[u] = __shfl(c_l, jg + u * NSW + sw, 64);
#pragma unroll
                for (int u = 0; u < GPE; ++u) v[u] = T2[(size_t)cc[u] * 16 + q];
#pragma unroll
                for (int u = 0; u < GPE; ++u) {
                    union { uint2 uu; half2v h[2]; } cv; cv.uu = v[u];
                    acc.x = fdot2f(cv.h[0], s10, acc.x);
                    acc.y = fdot2f(cv.h[0], s01, acc.y);
                    acc.z = fdot2f(cv.h[1], s10, acc.z);
                    acc.w = fdot2f(cv.h[1], s01, acc.w);
                }
            }
        }
    }
#pragma unroll
    for (int off = LR; off < 64; off <<= 1) {
        acc.x += __shfl_xor(acc.x, off, 64);
        acc.y += __shfl_xor(acc.y, off, 64);
        acc.z += __shfl_xor(acc.z, off, 64);
        acc.w += __shfl_xor(acc.w, off, 64);
    }
    const float di = dinv[i];
    const float4 b4 = reinterpret_cast<const float4*>(bias)[q];
    float4 h;
    h.x = fmaxf(fmaf(di, acc.x, b4.x), 0.f);
    h.y = fmaxf(fmaf(di, acc.y, b4.y), 0.f);
    h.z = fmaxf(fmaf(di, acc.z, b4.z), 0.f);
    h.w = fmaxf(fmaf(di, acc.w, b4.w), 0.f);
    if constexpr (!FUSE_HEAD) {
        if (sw == 0) {  // fp16 H for the MFMA GEMM
            union { ushort4 u; __half hh[4]; } pk;
            pk.hh[0] = __float2half_rn(h.x);
            pk.hh[1] = __float2half_rn(h.y);
            pk.hh[2] = __float2half_rn(h.z);
            pk.hh[3] = __float2half_rn(h.w);
            ushort* base_p = (ushort*)O + (size_t)i * 64;
            *reinterpret_cast<ushort4*>(base_p + 4 * q) = pk.u;
        }
    } else {
        float* Of = (float*)O;
        float p0 = h.x * Wh[(4 * q + 0) * 3 + 0];
        float p1 = h.x * Wh[(4 * q + 0) * 3 + 1];
        float p2 = h.x * Wh[(4 * q + 0) * 3 + 2];
        p0 = fmaf(h.y, Wh[(4 * q + 1) * 3 + 0], p0);
        p1 = fmaf(h.y, Wh[(4 * q + 1) * 3 + 1], p1);
        p2 = fmaf(h.y, Wh[(4 * q + 1) * 3 + 2], p2);
        p0 = fmaf(h.z, Wh[(4 * q + 2) * 3 + 0], p0);
        p1 = fmaf(h.z, Wh[(4 * q + 2) * 3 + 1], p1);
        p2 = fmaf(h.z, Wh[(4 * q + 2) * 3 + 2], p2);
        p0 = fmaf(h.w, Wh[(4 * q + 3) * 3 + 0], p0);
        p1 = fmaf(h.w, Wh[(4 * q + 3) * 3 + 1], p1);
        p2 = fmaf(h.w, Wh[(4 * q + 3) * 3 + 2], p2);
#pragma unroll
        for (int off = 1; off < LR; off <<= 1) {
            p0 += __shfl_xor(p0, off, 64);
            p1 += __shfl_xor(p1, off, 64);
            p2 += __shfl_xor(p2, off, 64);
        }
        if (lane == 0) {
            Of[(size_t)i * 3 + 0] = p0 + bh[0];
            Of[(size_t)i * 3 + 1] = p1 + bh[1];
            Of[(size_t)i * 3 + 2] = p2 + bh[2];
        }
    }
}

extern "C" void kernel_launch(void* const* d_in, const int* in_sizes, int n_in,
                              void* d_out, int out_size, void* d_ws, size_t ws_size,
                              hipStream_t stream) {
    const float* x  = (const float*)d_in[0];
    const int*   ei = (const int*)d_in[1];
    const float* W1 = (const float*)d_in[2];
    const float* b1 = (const float*)d_in[3];
    const float* W2 = (const float*)d_in[4];
    const float* b2 = (const float*)d_in[5];
    const float* W3 = (const float*)d_in[6];
    const float* b3 = (const float*)d_in[7];
    const float* W4 = (const float*)d_in[8];
    const float* b4 = (const float*)d_in[9];
    const float* Wh = (const float*)d_in[10];
    const float* bh = (const float*)d_in[11];
    float* out = (float*)d_out;

    const int n = in_sizes[0] / 128;
    const int E = in_sizes[1] / 2;
    const int ND   = (n + 255) / 256;    // coarse digits (<= MAXD)
    const int NBLK = (E + EB - 1) / EB;  // hist/pack blocks (<= 256)

    char* ws = (char*)d_ws;
    auto alloc = [&](size_t bytes) {
        char* p = ws;
        ws += (bytes + 255) & ~(size_t)255;
        return p;
    };
    int*    histM  = (int*)alloc((size_t)NBLK * MAXD * 4);
    int*    totals = (int*)alloc((size_t)MAXD * 4);
    int*    packed = (int*)alloc((size_t)E * 4);
    int*    col    = (int*)alloc(((size_t)E + (size_t)ND * PADSLACK + 256) * 4);
    int*    rowptr = (int*)alloc((size_t)n * 4);
    int*    counts = (int*)alloc((size_t)n * 4);
    float*  dinv   = (float*)alloc((size_t)n * 4);
    float*  bufF   = (float*)alloc((size_t)n * 64 * 4);         // raw T1 fp32
    __half* bufH   = (__half*)alloc(((size_t)n + 1) * 64 * 2);  // fp16 table + sentinel
    __half* bufG   = (__half*)bufF;  // fp16 H (aliases bufF; T1 dead post-bucket)

    dim3 blk(256);
    const int G  = (n + 63) / 64;   // layer-1 gemm blocks
    const int G1 = G / 3;           // slice fused with hist
    const int G2 = G - G1;          // slice fused with pack
    const int agg_blocks = (n + 3) / 4;
    const int mfma_blocks = 640;    // 2560 waves, grid-stride over 16-row blocks

    // ---- atomic-free CSR build + layer-1 transform ----
    hist_gemm1_k<<<dim3(NBLK + G1), blk, 0, stream>>>(ei, histM, E, x, W1, bufF, n, NBLK);
    scan_digits_k<<<dim3(ND), blk, 0, stream>>>(histM, totals, NBLK);
    pack_gemm1_k<<<dim3(NBLK + G2), blk, 0, stream>>>(ei, histM, totals, packed,
                                                      x, W1, bufF, n, E, ND, NBLK, G1);
    bucket_k<<<dim3(ND), blk, 0, stream>>>(packed, totals, ND, col, rowptr, counts,
                                           dinv, bufF, bufH, n);
    // ---- Layer 1 agg (writes fp16 H into bufG) ----
    agg_k<16, false><<<dim3(agg_blocks), blk, 0, stream>>>(
        bufH, rowptr, counts, col, dinv, b1, bufG, n, nullptr, nullptr);
    // ---- Layer 2 ----
    gemm_mfma_k<64><<<dim3(mfma_blocks), blk, 0, stream>>>(
        (const _Float16*)bufG, W2, dinv, (_Float16*)bufH, n);
    agg_k<16, false><<<dim3(agg_blocks), blk, 0, stream>>>(
        bufH, rowptr, counts, col, dinv, b2, bufG, n, nullptr, nullptr);
    // ---- Layer 3 ----
    gemm_mfma_k<64><<<dim3(mfma_blocks), blk, 0, stream>>>(
        (const _Float16*)bufG, W3, dinv, (_Float16*)bufH, n);
    agg_k<16, false><<<dim3(agg_blocks), blk, 0, stream>>>(
        bufH, rowptr, counts, col, dinv, b3, bufG, n, nullptr, nullptr);
    // ---- Layer 4 (+ fused head) ----
    gemm_mfma_k<32><<<dim3(mfma_blocks), blk, 0, stream>>>(
        (const _Float16*)bufG, W4, dinv, (_Float16*)bufH, n);
    agg_k<8, true><<<dim3(agg_blocks), blk, 0, stream>>>(
        bufH, rowptr, counts, col, dinv, b4, out, n, Wh, bh);
}

// Round 12
// 342.888 us; speedup vs baseline: 3.5355x; 1.0612x over previous
//
#include <hip/hip_runtime.h>
#include <hip/hip_bf16.h>
#include <hip/hip_fp16.h>
#include <cstdint>

// ---------------------------------------------------------------------------
// SPDE GCN: 4x GCNConv + linear head, fp32 in/out.
// R3-R10: uint2 multi-edge MLP agg; fp16 feature table; dinv pre/post scaling;
//   atomic-free MSD bucket-sort CSR fused with layer-1 fp32 GEMM; maskless
//   x8-padded CSR w/ sentinel row; MFMA fp16 GEMM for layers 2-4; head fused.
// R11 (neutral): branch-guarded batch -> compiler serialized (VGPR stayed 20,
//   waitcnt per group).
// R12: wave-uniform switch(nb) -> templated straight-line gather_batch<NB>:
//   ALL gathers unconditional + back-to-back, ONE waitcnt, then fdots.
//   True 2-round chain (col -> gathers).  VGPR rise to ~40-56 expected.
// ---------------------------------------------------------------------------

#define MAXD 512       // max coarse digits (n <= 131072)
#define EB   8192      // edges per hist/pack chunk
#define PADSLACK 2048  // max per-bucket padding (256 nodes * 8)

typedef _Float16 half8v __attribute__((ext_vector_type(8)));
typedef _Float16 half2v __attribute__((ext_vector_type(2)));
typedef float    float4v __attribute__((ext_vector_type(4)));

#if defined(__has_builtin)
#if __has_builtin(__builtin_amdgcn_fdot2)
#define HAVE_FDOT2 1
#endif
#endif

__device__ __forceinline__ float fdot2f(half2v a, half2v b, float c) {
#ifdef HAVE_FDOT2
    return __builtin_amdgcn_fdot2(a, b, c, false);
#else
    return c + (float)a[0] * (float)b[0] + (float)a[1] * (float)b[1];
#endif
}

// ---- LDS exclusive scan of totals[0..MAXD) with 256 threads ---------------
__device__ __forceinline__ void digit_base_scan(const int* __restrict__ totals,
                                                int ND, int* pairs, int* cbs) {
    const int t = threadIdx.x;
    const int e0 = 2 * t, e1 = 2 * t + 1;
    int v0 = (e0 < ND) ? totals[e0] : 0;
    int v1 = (e1 < ND) ? totals[e1] : 0;
    pairs[t] = v0 + v1;
    __syncthreads();
    for (int off = 1; off < 256; off <<= 1) {
        int x = (t >= off) ? pairs[t - off] : 0;
        __syncthreads();
        pairs[t] += x;
        __syncthreads();
    }
    int ep = pairs[t] - v0 - v1;  // exclusive pair prefix
    cbs[e0] = ep;
    cbs[e1] = ep + v0;
    __syncthreads();
}

// ---- hist body: coarse histogram (block-major histM[b][dg]) ---------------
__device__ __forceinline__ void hist_body(const int* __restrict__ ei,
                                          int* __restrict__ histM, int E, int b) {
    __shared__ int hist[MAXD];
    const int tid = threadIdx.x;
    hist[tid] = 0; hist[tid + 256] = 0;
    __syncthreads();
    const int base = b * EB;
#pragma unroll 2
    for (int it = 0; it < EB / 256; it += 4) {
        int d[4]; bool ok[4];
#pragma unroll
        for (int u = 0; u < 4; ++u) {
            int e = base + (it + u) * 256 + tid;
            ok[u] = e < E;
            d[u] = ok[u] ? ei[E + e] : 0;
        }
#pragma unroll
        for (int u = 0; u < 4; ++u)
            if (ok[u]) atomicAdd(&hist[d[u] >> 8], 1);
    }
    __syncthreads();
    histM[(size_t)b * MAXD + tid] = hist[tid];
    histM[(size_t)b * MAXD + tid + 256] = hist[tid + 256];
}

// ---- per-digit exclusive scan over chunks (in place) + digit totals -------
__global__ __launch_bounds__(256) void scan_digits_k(int* __restrict__ histM,
                                                     int* __restrict__ totals,
                                                     int NBLK) {
    __shared__ int s[256];
    const int t = threadIdx.x, dg = blockIdx.x;
    int v = (t < NBLK) ? histM[(size_t)t * MAXD + dg] : 0;
    s[t] = v;
    __syncthreads();
    for (int off = 1; off < 256; off <<= 1) {
        int x = (t >= off) ? s[t - off] : 0;
        __syncthreads();
        s[t] += x;
        __syncthreads();
    }
    if (t < NBLK) histM[(size_t)t * MAXD + dg] = s[t] - v;
    if (t == 255) totals[dg] = s[255];
}

// ---- fp32 vector GEMM body (layer 1 only, fused with CSR build) -----------
template <int K, int OUT>
__device__ __forceinline__ void gemm_body(const float* __restrict__ H,
                                          const float* __restrict__ W,
                                          float* __restrict__ Tout, int n, int bx) {
    constexpr int TX  = OUT / 4;
    constexpr int TY  = 256 / TX;
    constexpr int BM  = TY * 4;
    constexpr int BK  = 32;
    constexpr int PAD = 4;

    __shared__ float At[BK][BM + PAD];
    __shared__ float Ws[BK][OUT];

    const int t    = threadIdx.x;
    const int cx   = t % TX;
    const int ry   = t / TX;
    const int row0 = bx * BM;

    float acc[4][4] = {{0.f}};
    const int arow = t >> 3;
    const int af4  = t & 7;

    for (int k0 = 0; k0 < K; k0 += BK) {
#pragma unroll
        for (int p = 0; p < BM / 32; ++p) {
            int r  = arow + p * 32;
            int gr = row0 + r;
            int grc = gr < n ? gr : n - 1;
            float4 v = *reinterpret_cast<const float4*>(
                H + (size_t)grc * K + k0 + af4 * 4);
            At[af4 * 4 + 0][r] = v.x;
            At[af4 * 4 + 1][r] = v.y;
            At[af4 * 4 + 2][r] = v.z;
            At[af4 * 4 + 3][r] = v.w;
        }
#pragma unroll
        for (int p = 0; p < (BK * OUT) / 1024; ++p) {
            int idx = t + p * 256;
            int wk  = idx / (OUT / 4);
            int wf  = idx % (OUT / 4);
            float4 v = *reinterpret_cast<const float4*>(
                W + (size_t)(k0 + wk) * OUT + wf * 4);
            *reinterpret_cast<float4*>(&Ws[wk][wf * 4]) = v;
        }
        __syncthreads();
#pragma unroll
        for (int k = 0; k < BK; ++k) {
            float4 a = *reinterpret_cast<const float4*>(&At[k][ry * 4]);
            float4 w = *reinterpret_cast<const float4*>(&Ws[k][cx * 4]);
            acc[0][0] = fmaf(a.x, w.x, acc[0][0]);
            acc[0][1] = fmaf(a.x, w.y, acc[0][1]);
            acc[0][2] = fmaf(a.x, w.z, acc[0][2]);
            acc[0][3] = fmaf(a.x, w.w, acc[0][3]);
            acc[1][0] = fmaf(a.y, w.x, acc[1][0]);
            acc[1][1] = fmaf(a.y, w.y, acc[1][1]);
            acc[1][2] = fmaf(a.y, w.z, acc[1][2]);
            acc[1][3] = fmaf(a.y, w.w, acc[1][3]);
            acc[2][0] = fmaf(a.z, w.x, acc[2][0]);
            acc[2][1] = fmaf(a.z, w.y, acc[2][1]);
            acc[2][2] = fmaf(a.z, w.z, acc[2][2]);
            acc[2][3] = fmaf(a.z, w.w, acc[2][3]);
            acc[3][0] = fmaf(a.w, w.x, acc[3][0]);
            acc[3][1] = fmaf(a.w, w.y, acc[3][1]);
            acc[3][2] = fmaf(a.w, w.z, acc[3][2]);
            acc[3][3] = fmaf(a.w, w.w, acc[3][3]);
        }
        __syncthreads();
    }
#pragma unroll
    for (int i = 0; i < 4; ++i) {
        int gr = row0 + ry * 4 + i;
        if (gr < n) {
            float4 v = make_float4(acc[i][0], acc[i][1], acc[i][2], acc[i][3]);
            *reinterpret_cast<float4*>(Tout + (size_t)gr * OUT + cx * 4) = v;
        }
    }
}

// ---- pack scatter: one hist chunk per block; digit bases from local scan --
__device__ __forceinline__ void pack_body(const int* __restrict__ ei,
                                          const int* __restrict__ histM,
                                          const int* __restrict__ totals,
                                          int* __restrict__ packed,
                                          int E, int ND, int b) {
    __shared__ int pairs[256];
    __shared__ int cbs[MAXD];
    __shared__ int cur[MAXD];
    const int tid = threadIdx.x;
    digit_base_scan(totals, ND, pairs, cbs);
    for (int t = tid; t < ND; t += 256)
        cur[t] = cbs[t] + histM[(size_t)b * MAXD + t];
    __syncthreads();
    const int base = b * EB;
    for (int it = 0; it < EB / 256; it += 4) {
        int s[4], d[4]; bool ok[4];
#pragma unroll
        for (int u = 0; u < 4; ++u) {
            int e = base + (it + u) * 256 + tid;
            ok[u] = e < E;
            if (ok[u]) { s[u] = ei[e]; d[u] = ei[E + e]; }
        }
#pragma unroll
        for (int u = 0; u < 4; ++u) {
            if (ok[u]) {
                int pos = atomicAdd(&cur[d[u] >> 8], 1);
                packed[pos] = (s[u] << 8) | (d[u] & 255);
            }
        }
    }
}

// Fused: hist + first slice of layer-1 GEMM.
__global__ __launch_bounds__(256) void hist_gemm1_k(
    const int* __restrict__ ei, int* __restrict__ histM, int E,
    const float* __restrict__ x, const float* __restrict__ W1,
    float* __restrict__ T1, int n, int NH) {
    const int bx = blockIdx.x;
    if (bx < NH) hist_body(ei, histM, E, bx);
    else         gemm_body<128, 64>(x, W1, T1, n, bx - NH);
}

// Fused: pack + remaining layer-1 GEMM blocks.
__global__ __launch_bounds__(256) void pack_gemm1_k(
    const int* __restrict__ ei, const int* __restrict__ histM,
    const int* __restrict__ totals, int* __restrict__ packed,
    const float* __restrict__ x, const float* __restrict__ W1,
    float* __restrict__ T1, int n, int E, int ND, int NPB, int G1) {
    const int bx = blockIdx.x;
    if (bx < NPB) pack_body(ei, histM, totals, packed, E, ND, bx);
    else          gemm_body<128, 64>(x, W1, T1, n, G1 + bx - NPB);
}

// ---- per-coarse-bucket finalize (padded x8 CSR, dinv, col, T1 scale+fp16) -
__global__ __launch_bounds__(256) void bucket_k(const int* __restrict__ packed,
                                                const int* __restrict__ totals,
                                                int ND,
                                                int* __restrict__ col,
                                                int* __restrict__ rowptr,
                                                int* __restrict__ counts,
                                                float* __restrict__ dinv,
                                                const float* __restrict__ Traw,
                                                __half* __restrict__ Th, int n) {
    __shared__ int   pairs[256];
    __shared__ int   cbs[MAXD];
    __shared__ int   hist[256];
    __shared__ int   pref[256];
    __shared__ int   cur[256];
    __shared__ float dinv_l[256];

    const int tid = threadIdx.x;
    const int dg  = blockIdx.x;
    digit_base_scan(totals, ND, pairs, cbs);
    const int base  = cbs[dg];
    const int m     = totals[dg];
    const int basep = base + dg * PADSLACK;

    hist[tid] = 0;
    __syncthreads();
    for (int k0 = 0; k0 < m; k0 += 1024) {
        int v[4]; bool ok[4];
#pragma unroll
        for (int u = 0; u < 4; ++u) {
            int k = k0 + u * 256 + tid;
            ok[u] = k < m;
            v[u] = ok[u] ? packed[base + k] : 0;
        }
#pragma unroll
        for (int u = 0; u < 4; ++u)
            if (ok[u]) atomicAdd(&hist[v[u] & 255], 1);
    }
    __syncthreads();
    const int deg   = hist[tid];
    const int cnt_p = (deg + 8) & ~7;  // >= deg+1, multiple of 8
    pref[tid] = cnt_p;
    __syncthreads();
    for (int off = 1; off < 256; off <<= 1) {
        int x = (tid >= off) ? pref[tid - off] : 0;
        __syncthreads();
        pref[tid] += x;
        __syncthreads();
    }
    const int rp = basep + pref[tid] - cnt_p;
    const float di = rsqrtf((float)(deg + 1));
    dinv_l[tid] = di;
    cur[tid] = rp + 1;
    const int d = dg * 256 + tid;
    if (d < n) {
        counts[d] = cnt_p;
        dinv[d]   = di;
        rowptr[d] = rp;
        col[rp]   = d;                                          // self slot
        for (int k = deg + 1; k < cnt_p; ++k) col[rp + k] = n;  // sentinel pads
    }
    __syncthreads();
    for (int k0 = 0; k0 < m; k0 += 1024) {
        int v[4]; bool ok[4];
#pragma unroll
        for (int u = 0; u < 4; ++u) {
            int k = k0 + u * 256 + tid;
            ok[u] = k < m;
            v[u] = ok[u] ? packed[base + k] : 0;
        }
#pragma unroll
        for (int u = 0; u < 4; ++u) {
            if (ok[u]) {
                int pos = atomicAdd(&cur[v[u] & 255], 1);
                col[pos] = v[u] >> 8;
            }
        }
    }
    const int r0 = dg * 256;
#pragma unroll 4
    for (int it = 0; it < 16; ++it) {
        int idx = it * 256 + tid;
        int rl  = idx >> 4;
        int r   = r0 + rl;
        if (r < n) {
            float4 v = reinterpret_cast<const float4*>(Traw)[(size_t)r * 16 + (idx & 15)];
            float dd = dinv_l[rl];
            union { ushort4 u; __half h[4]; } pk;
            pk.h[0] = __float2half_rn(v.x * dd);
            pk.h[1] = __float2half_rn(v.y * dd);
            pk.h[2] = __float2half_rn(v.z * dd);
            pk.h[3] = __float2half_rn(v.w * dd);
            reinterpret_cast<ushort4*>(Th)[(size_t)r * 16 + (idx & 15)] = pk.u;
        }
    }
    if (dg == 0 && tid < 16) {
        uint2 z; z.x = 0u; z.y = 0u;
        reinterpret_cast<uint2*>(Th)[(size_t)n * 16 + tid] = z;
    }
}

// ---- MFMA fp16 GEMM (layers 2-4): T[r] = fp16(dinv[r] * (H[r] @ W)) -------
template <int OUT>  // 64 or 32
__global__ __launch_bounds__(256) void gemm_mfma_k(
    const _Float16* __restrict__ H, const float* __restrict__ W,
    const float* __restrict__ dinv, _Float16* __restrict__ T, int n) {
    constexpr int NT = OUT / 16;        // N tiles: 4 or 2
    const int lane = threadIdx.x & 63;
    const int m16  = lane & 15;
    const int quad = lane >> 4;         // 0..3
    const int wid  = (blockIdx.x * blockDim.x + threadIdx.x) >> 6;
    const int nw   = (gridDim.x * blockDim.x) >> 6;

    half8v bfrag[NT][2];
#pragma unroll
    for (int t = 0; t < NT; ++t)
#pragma unroll
        for (int h = 0; h < 2; ++h)
#pragma unroll
            for (int j = 0; j < 8; ++j)
                bfrag[t][h][j] = (_Float16)W[(size_t)(h * 32 + quad * 8 + j) * OUT
                                             + t * 16 + m16];

    const int nblk = (n + 15) >> 4;
    for (int rb = wid; rb < nblk; rb += nw) {
        const int r0 = rb * 16;
        int ra = r0 + m16; if (ra >= n) ra = n - 1;
        const half8v* hrow = reinterpret_cast<const half8v*>(H + (size_t)ra * 64);
        half8v a0 = hrow[quad];       // A[m=lane&15][k=quad*8+j]
        half8v a1 = hrow[4 + quad];   // k += 32

        float4v dfr[NT];
#pragma unroll
        for (int t = 0; t < NT; ++t) {
            float4v z = {0.f, 0.f, 0.f, 0.f};
            z = __builtin_amdgcn_mfma_f32_16x16x32_f16(a0, bfrag[t][0], z, 0, 0, 0);
            z = __builtin_amdgcn_mfma_f32_16x16x32_f16(a1, bfrag[t][1], z, 0, 0, 0);
            dfr[t] = z;
        }
#pragma unroll
        for (int reg = 0; reg < 4; ++reg) {
            int row = r0 + quad * 4 + reg;
            if (row < n) {
                float di = dinv[row];
#pragma unroll
                for (int t = 0; t < NT; ++t)
                    T[(size_t)row * 64 + t * 16 + m16] =
                        (_Float16)(dfr[t][reg] * di);
            }
        }
    }
}

// ---- straight-line batch: NB groups of 8 edges, all gathers unconditional -
template <int NB, int LR>
__device__ __forceinline__ void gather_batch(int c_l, const uint2* __restrict__ T2,
                                             int q, int sw, float4& acc) {
    constexpr int NSW = 64 / LR;
    constexpr int GPE = 8 / NSW;
    constexpr int NV  = NB * GPE;
    const half2v s10 = {(_Float16)1.f, (_Float16)0.f};
    const half2v s01 = {(_Float16)0.f, (_Float16)1.f};
    uint2 v[NV];
#pragma unroll
    for (int g = 0; g < NB; ++g)
#pragma unroll
        for (int u = 0; u < GPE; ++u) {
            int cc = __shfl(c_l, g * 8 + u * NSW + sw, 64);
            v[g * GPE + u] = T2[(size_t)cc * 16 + q];
        }
#pragma unroll
    for (int k = 0; k < NV; ++k) {
        union { uint2 uu; half2v h[2]; } cv; cv.uu = v[k];
        acc.x = fdot2f(cv.h[0], s10, acc.x);
        acc.y = fdot2f(cv.h[0], s01, acc.y);
        acc.z = fdot2f(cv.h[1], s10, acc.z);
        acc.w = fdot2f(cv.h[1], s01, acc.w);
    }
}

// One wave per node, maskless padded CSR (x8, slot0=self, pads->sentinel).
// R12: switch(nb) -> straight-line batches, 2 dependent memory rounds.
template <int LR, bool FUSE_HEAD>   // LR=16: 64ch; LR=8: 32ch
__global__ __launch_bounds__(256) void agg_k(const __half* __restrict__ T,
                                             const int* __restrict__ rowptr,
                                             const int* __restrict__ counts,
                                             const int* __restrict__ col,
                                             const float* __restrict__ dinv,
                                             const float* __restrict__ bias,
                                             void* __restrict__ O, int n,
                                             const float* __restrict__ Wh,
                                             const float* __restrict__ bh) {
    constexpr int NSW = 64 / LR;     // 4 / 8
    constexpr int GPE = 8 / NSW;     // 2 / 1
    const int lane = threadIdx.x & 63;
    const int q    = lane % LR;
    const int sw   = lane / LR;
    const int i = (blockIdx.x * blockDim.x + threadIdx.x) >> 6;
    if (i >= n) return;

    const int start = rowptr[i];
    const int cnt   = counts[i];     // padded: multiple of 8, includes self
    const uint2* __restrict__ T2 = reinterpret_cast<const uint2*>(T);

    float4 acc = make_float4(0.f, 0.f, 0.f, 0.f);
    if (cnt <= 64) {
        int c_l = col[start + lane];   // slack-safe (col has +256 tail ints)
        switch (cnt >> 3) {            // 1..8 groups of 8
            case 1: gather_batch<1, LR>(c_l, T2, q, sw, acc); break;
            case 2: gather_batch<2, LR>(c_l, T2, q, sw, acc); break;
            case 3: gather_batch<3, LR>(c_l, T2, q, sw, acc); break;
            case 4: gather_batch<4, LR>(c_l, T2, q, sw, acc); break;
            case 5: gather_batch<5, LR>(c_l, T2, q, sw, acc); break;
            case 6: gather_batch<6, LR>(c_l, T2, q, sw, acc); break;
            case 7: gather_batch<7, LR>(c_l, T2, q, sw, acc); break;
            default: gather_batch<8, LR>(c_l, T2, q, sw, acc); break;
        }
    } else {
        // generic fallback (cnt > 64; essentially never taken)
        const half2v s10 = {(_Float16)1.f, (_Float16)0.f};
        const half2v s01 = {(_Float16)0.f, (_Float16)1.f};
        for (int base = 0; base < cnt; base += 64) {
            const int m = min(64, cnt - base);   // multiple of 8
            int c_l = col[start + base + lane];
            for (int jg = 0; jg < m; jg += 8) {
                int cc[GPE]; uint2 v[GPE];
#pragma unroll
                for (int u = 0; u < GPE; ++u)
                    cc[u] = __shfl(c_l, jg + u * NSW + sw, 64);
#pragma unroll
                for (int u = 0; u < GPE; ++u) v[u] = T2[(size_t)cc[u] * 16 + q];
#pragma unroll
                for (int u = 0; u < GPE; ++u) {
                    union { uint2 uu; half2v h[2]; } cv; cv.uu = v[u];
                    acc.x = fdot2f(cv.h[0], s10, acc.x);
                    acc.y = fdot2f(cv.h[0], s01, acc.y);
                    acc.z = fdot2f(cv.h[1], s10, acc.z);
                    acc.w = fdot2f(cv.h[1], s01, acc.w);
                }
            }
        }
    }
#pragma unroll
    for (int off = LR; off < 64; off <<= 1) {
        acc.x += __shfl_xor(acc.x, off, 64);
        acc.y += __shfl_xor(acc.y, off, 64);
        acc.z += __shfl_xor(acc.z, off, 64);
        acc.w += __shfl_xor(acc.w, off, 64);
    }
    const float di = dinv[i];
    const float4 b4 = reinterpret_cast<const float4*>(bias)[q];
    float4 h;
    h.x = fmaxf(fmaf(di, acc.x, b4.x), 0.f);
    h.y = fmaxf(fmaf(di, acc.y, b4.y), 0.f);
    h.z = fmaxf(fmaf(di, acc.z, b4.z), 0.f);
    h.w = fmaxf(fmaf(di, acc.w, b4.w), 0.f);
    if constexpr (!FUSE_HEAD) {
        if (sw == 0) {  // fp16 H for the MFMA GEMM
            union { ushort4 u; __half hh[4]; } pk;
            pk.hh[0] = __float2half_rn(h.x);
            pk.hh[1] = __float2half_rn(h.y);
            pk.hh[2] = __float2half_rn(h.z);
            pk.hh[3] = __float2half_rn(h.w);
            ushort* base_p = (ushort*)O + (size_t)i * 64;
            *reinterpret_cast<ushort4*>(base_p + 4 * q) = pk.u;
        }
    } else {
        float* Of = (float*)O;
        float p0 = h.x * Wh[(4 * q + 0) * 3 + 0];
        float p1 = h.x * Wh[(4 * q + 0) * 3 + 1];
        float p2 = h.x * Wh[(4 * q + 0) * 3 + 2];
        p0 = fmaf(h.y, Wh[(4 * q + 1) * 3 + 0], p0);
        p1 = fmaf(h.y, Wh[(4 * q + 1) * 3 + 1], p1);
        p2 = fmaf(h.y, Wh[(4 * q + 1) * 3 + 2], p2);
        p0 = fmaf(h.z, Wh[(4 * q + 2) * 3 + 0], p0);
        p1 = fmaf(h.z, Wh[(4 * q + 2) * 3 + 1], p1);
        p2 = fmaf(h.z, Wh[(4 * q + 2) * 3 + 2], p2);
        p0 = fmaf(h.w, Wh[(4 * q + 3) * 3 + 0], p0);
        p1 = fmaf(h.w, Wh[(4 * q + 3) * 3 + 1], p1);
        p2 = fmaf(h.w, Wh[(4 * q + 3) * 3 + 2], p2);
#pragma unroll
        for (int off = 1; off < LR; off <<= 1) {
            p0 += __shfl_xor(p0, off, 64);
            p1 += __shfl_xor(p1, off, 64);
            p2 += __shfl_xor(p2, off, 64);
        }
        if (lane == 0) {
            Of[(size_t)i * 3 + 0] = p0 + bh[0];
            Of[(size_t)i * 3 + 1] = p1 + bh[1];
            Of[(size_t)i * 3 + 2] = p2 + bh[2];
        }
    }
}

extern "C" void kernel_launch(void* const* d_in, const int* in_sizes, int n_in,
                              void* d_out, int out_size, void* d_ws, size_t ws_size,
                              hipStream_t stream) {
    const float* x  = (const float*)d_in[0];
    const int*   ei = (const int*)d_in[1];
    const float* W1 = (const float*)d_in[2];
    const float* b1 = (const float*)d_in[3];
    const float* W2 = (const float*)d_in[4];
    const float* b2 = (const float*)d_in[5];
    const float* W3 = (const float*)d_in[6];
    const float* b3 = (const float*)d_in[7];
    const float* W4 = (const float*)d_in[8];
    const float* b4 = (const float*)d_in[9];
    const float* Wh = (const float*)d_in[10];
    const float* bh = (const float*)d_in[11];
    float* out = (float*)d_out;

    const int n = in_sizes[0] / 128;
    const int E = in_sizes[1] / 2;
    const int ND   = (n + 255) / 256;    // coarse digits (<= MAXD)
    const int NBLK = (E + EB - 1) / EB;  // hist/pack blocks (<= 256)

    char* ws = (char*)d_ws;
    auto alloc = [&](size_t bytes) {
        char* p = ws;
        ws += (bytes + 255) & ~(size_t)255;
        return p;
    };
    int*    histM  = (int*)alloc((size_t)NBLK * MAXD * 4);
    int*    totals = (int*)alloc((size_t)MAXD * 4);
    int*    packed = (int*)alloc((size_t)E * 4);
    int*    col    = (int*)alloc(((size_t)E + (size_t)ND * PADSLACK + 256) * 4);
    int*    rowptr = (int*)alloc((size_t)n * 4);
    int*    counts = (int*)alloc((size_t)n * 4);
    float*  dinv   = (float*)alloc((size_t)n * 4);
    float*  bufF   = (float*)alloc((size_t)n * 64 * 4);         // raw T1 fp32
    __half* bufH   = (__half*)alloc(((size_t)n + 1) * 64 * 2);  // fp16 table + sentinel
    __half* bufG   = (__half*)bufF;  // fp16 H (aliases bufF; T1 dead post-bucket)

    dim3 blk(256);
    const int G  = (n + 63) / 64;   // layer-1 gemm blocks
    const int G1 = G / 3;           // slice fused with hist
    const int G2 = G - G1;          // slice fused with pack
    const int agg_blocks = (n + 3) / 4;
    const int mfma_blocks = 640;    // 2560 waves, grid-stride over 16-row blocks

    // ---- atomic-free CSR build + layer-1 transform ----
    hist_gemm1_k<<<dim3(NBLK + G1), blk, 0, stream>>>(ei, histM, E, x, W1, bufF, n, NBLK);
    scan_digits_k<<<dim3(ND), blk, 0, stream>>>(histM, totals, NBLK);
    pack_gemm1_k<<<dim3(NBLK + G2), blk, 0, stream>>>(ei, histM, totals, packed,
                                                      x, W1, bufF, n, E, ND, NBLK, G1);
    bucket_k<<<dim3(ND), blk, 0, stream>>>(packed, totals, ND, col, rowptr, counts,
                                           dinv, bufF, bufH, n);
    // ---- Layer 1 agg (writes fp16 H into bufG) ----
    agg_k<16, false><<<dim3(agg_blocks), blk, 0, stream>>>(
        bufH, rowptr, counts, col, dinv, b1, bufG, n, nullptr, nullptr);
    // ---- Layer 2 ----
    gemm_mfma_k<64><<<dim3(mfma_blocks), blk, 0, stream>>>(
        (const _Float16*)bufG, W2, dinv, (_Float16*)bufH, n);
    agg_k<16, false><<<dim3(agg_blocks), blk, 0, stream>>>(
        bufH, rowptr, counts, col, dinv, b2, bufG, n, nullptr, nullptr);
    // ---- Layer 3 ----
    gemm_mfma_k<64><<<dim3(mfma_blocks), blk, 0, stream>>>(
        (const _Float16*)bufG, W3, dinv, (_Float16*)bufH, n);
    agg_k<16, false><<<dim3(agg_blocks), blk, 0, stream>>>(
        bufH, rowptr, counts, col, dinv, b3, bufG, n, nullptr, nullptr);
    // ---- Layer 4 (+ fused head) ----
    gemm_mfma_k<32><<<dim3(mfma_blocks), blk, 0, stream>>>(
        (const _Float16*)bufG, W4, dinv, (_Float16*)bufH, n);
    agg_k<8, true><<<dim3(agg_blocks), blk, 0, stream>>>(
        bufH, rowptr, counts, col, dinv, b4, out, n, Wh, bh);
}